// Round 14
// baseline (968.664 us; speedup 1.0000x reference)
//
#include <hip/hip_runtime.h>
#include <hip/hip_bf16.h>
#include <math.h>
#include <stdint.h>

#define S_LEN 4096
#define L_LEN 4095
#define DIN   1536
#define DM    768
#define NHEAD 12
#define HDIM  64
#define FFND  3072
#define EPS   1e-5f

typedef unsigned short u16;
typedef unsigned int   u32;
typedef short short8 __attribute__((ext_vector_type(8)));
typedef float f32x4 __attribute__((ext_vector_type(4)));
typedef float f32x16 __attribute__((ext_vector_type(16)));
typedef int i32x2 __attribute__((ext_vector_type(2)));

// ---------------------------------------------------------------- helpers
__device__ __forceinline__ u16 f2b(float f) {
    union { float f; u32 u; } x; x.f = f;
    u32 r = (x.u + 0x7FFF + ((x.u >> 16) & 1)) >> 16;
    return (u16)r;
}
__device__ __forceinline__ float b2f(u16 v) {
    union { u32 u; float f; } x; x.u = ((u32)v) << 16;
    return x.f;
}
__device__ __forceinline__ float gelu_tanh(float x) {
    float x3 = x * x * x;
    return 0.5f * x * (1.f + tanhf(0.7978845608f * (x + 0.044715f * x3)));
}
__device__ __forceinline__ float block_reduce_sum(float v, float* sbuf) {
#pragma unroll
    for (int o = 32; o > 0; o >>= 1) v += __shfl_down(v, o, 64);
    __syncthreads();
    if ((threadIdx.x & 63) == 0) sbuf[threadIdx.x >> 6] = v;
    __syncthreads();
    return sbuf[0] + sbuf[1] + sbuf[2] + sbuf[3];
}
__device__ __forceinline__ void gload16(const void* g, void* l) {
    __builtin_amdgcn_global_load_lds((const __attribute__((address_space(1))) void*)g,
                                     (__attribute__((address_space(3))) void*)l,
                                     16, 0, 0);
}
// barrier draining only LDS ops; global register prefetches stay in flight
__device__ __forceinline__ void lds_barrier() {
    asm volatile("s_waitcnt lgkmcnt(0)" ::: "memory");
    __builtin_amdgcn_s_barrier();
    __builtin_amdgcn_sched_barrier(0);
}

// ---------------------------------------------------------------- GEMM (bf16 MFMA, B^T layout)
template <int BM, int BN>
__device__ __forceinline__ void gemm_bt(
    const u16* __restrict__ A, const u16* __restrict__ Bt,
    const float* __restrict__ bias, const float* __restrict__ res,
    float* __restrict__ outf, u16* __restrict__ outb,
    int M, int N, int K, float scale, int dogelu, int bx, int by)
{
    constexpr int MI = BM / 32;
    constexpr int NI = BN / 32;
    constexpr int AI = BM / 32;
    constexpr int BI = BN / 32;
    __shared__ u16 As[BM * 64];
    __shared__ u16 Bs[BN * 64];
    const int tid = threadIdx.x, wv = tid >> 6, l = tid & 63;
    const int bm = by * BM, bn = bx * BN;
    const int wm = wv >> 1, wn = wv & 1;

    f32x4 acc[MI][NI];
#pragma unroll
    for (int i = 0; i < MI; ++i)
#pragma unroll
        for (int j = 0; j < NI; ++j) acc[i][j] = (f32x4){0.f, 0.f, 0.f, 0.f};

    for (int k0 = 0; k0 < K; k0 += 64) {
#pragma unroll
        for (int i = 0; i < AI; ++i) {
            int row = (wv * AI + i) * 8 + (l >> 3);
            int col = ((l & 7) ^ (row & 7)) * 8;
            int grow = bm + row; if (grow > M - 1) grow = M - 1;
            gload16(A + (size_t)grow * K + k0 + col, &As[(wv * AI + i) * 512]);
        }
#pragma unroll
        for (int i = 0; i < BI; ++i) {
            int row = (wv * BI + i) * 8 + (l >> 3);
            int col = ((l & 7) ^ (row & 7)) * 8;
            gload16(Bt + (size_t)(bn + row) * K + k0 + col, &Bs[(wv * BI + i) * 512]);
        }
        __syncthreads();
#pragma unroll
        for (int kc = 0; kc < 2; ++kc) {
            short8 a[MI], b[NI];
#pragma unroll
            for (int mi = 0; mi < MI; ++mi) {
                int row = wm * (BM / 2) + mi * 16 + (l & 15);
                int off = ((l >> 4) * 16 + kc * 64) ^ ((row & 7) << 4);
                a[mi] = *(const short8*)&As[(row * 128 + off) >> 1];
            }
#pragma unroll
            for (int ni = 0; ni < NI; ++ni) {
                int row = wn * (BN / 2) + ni * 16 + (l & 15);
                int off = ((l >> 4) * 16 + kc * 64) ^ ((row & 7) << 4);
                b[ni] = *(const short8*)&Bs[(row * 128 + off) >> 1];
            }
#pragma unroll
            for (int mi = 0; mi < MI; ++mi)
#pragma unroll
                for (int ni = 0; ni < NI; ++ni)
                    acc[mi][ni] = __builtin_amdgcn_mfma_f32_16x16x32_bf16(
                        a[mi], b[ni], acc[mi][ni], 0, 0, 0);
        }
        __syncthreads();
    }
#pragma unroll
    for (int mi = 0; mi < MI; ++mi) {
#pragma unroll
        for (int rg = 0; rg < 4; ++rg) {
            int row = bm + wm * (BM / 2) + mi * 16 + (l >> 4) * 4 + rg;
            if (row >= M) continue;
#pragma unroll
            for (int ni = 0; ni < NI; ++ni) {
                int col = bn + wn * (BN / 2) + ni * 16 + (l & 15);
                float v = (acc[mi][ni][rg] + bias[col]) * scale;
                if (dogelu) v = gelu_tanh(v);
                if (res) v += res[(size_t)row * N + col];
                if (outf) outf[(size_t)row * N + col] = v;
                if (outb) outb[(size_t)row * N + col] = f2b(v);
            }
        }
    }
}

__global__ __launch_bounds__(256) void gemm128_kernel(
    const u16* __restrict__ A, const u16* __restrict__ Bt,
    const float* __restrict__ bias, const float* __restrict__ res,
    float* __restrict__ outf, u16* __restrict__ outb,
    int M, int N, int K, float scale, int dogelu)
{
    gemm_bt<128, 128>(A, Bt, bias, res, outf, outb, M, N, K, scale, dogelu,
                      blockIdx.x, blockIdx.y);
}
__global__ __launch_bounds__(256) void gemm6464_kernel(
    const u16* __restrict__ A, const u16* __restrict__ Bt,
    const float* __restrict__ bias, const float* __restrict__ res,
    float* __restrict__ outf, u16* __restrict__ outb,
    int M, int N, int K, float scale, int dogelu)
{
    gemm_bt<64, 64>(A, Bt, bias, res, outf, outb, M, N, K, scale, dogelu,
                    blockIdx.x, blockIdx.y);
}
__global__ __launch_bounds__(256) void qkv_kernel(
    const u16* __restrict__ t,
    const u16* __restrict__ wqT, const u16* __restrict__ wkT, const u16* __restrict__ wvT,
    const float* __restrict__ bq, const float* __restrict__ bk, const float* __restrict__ bv,
    u16* __restrict__ q, u16* __restrict__ k, u16* __restrict__ v)
{
    int z = blockIdx.z;
    const u16* B = (z == 0) ? wqT : (z == 1) ? wkT : wvT;
    const float* bias = (z == 0) ? bq : (z == 1) ? bk : bv;
    u16* C = (z == 0) ? q : (z == 1) ? k : v;
    // Q additionally scaled by HD^-0.5 * log2(e) so softmax can use exp2
    float scale = (z == 0) ? 0.125f * 1.4426950408889634f : 1.0f;
    gemm_bt<128, 128>(t, B, bias, nullptr, nullptr, C, S_LEN, DM, DM, scale, 0,
                      blockIdx.x, blockIdx.y);
}

// ---------------------------------------------------------- transpose+convert
__global__ __launch_bounds__(256) void transpose_cvt(
    const float* __restrict__ s0, const float* __restrict__ s1,
    const float* __restrict__ s2, const float* __restrict__ s3,
    u16* __restrict__ dst, int K, int N)
{
    int z = blockIdx.z;
    const float* src = (z == 0) ? s0 : (z == 1) ? s1 : (z == 2) ? s2 : s3;
    u16* d = dst + (size_t)z * K * N;
    __shared__ float tile[64][65];
    const int t = threadIdx.x;
    const int tk = blockIdx.y * 64, tn = blockIdx.x * 64;
    const int r0 = t >> 4, c0 = (t & 15) * 4;
#pragma unroll
    for (int i = 0; i < 4; ++i) {
        const float* sp = &src[(size_t)(tk + r0 + i * 16) * N + tn + c0];
        tile[r0 + i * 16][c0 + 0] = sp[0];
        tile[r0 + i * 16][c0 + 1] = sp[1];
        tile[r0 + i * 16][c0 + 2] = sp[2];
        tile[r0 + i * 16][c0 + 3] = sp[3];
    }
    __syncthreads();
#pragma unroll
    for (int i = 0; i < 4; ++i) {
        int nr = r0 + i * 16;
        u32 lo = (u32)f2b(tile[c0 + 0][nr]) | ((u32)f2b(tile[c0 + 1][nr]) << 16);
        u32 hi = (u32)f2b(tile[c0 + 2][nr]) | ((u32)f2b(tile[c0 + 3][nr]) << 16);
        *(uint2*)&d[(size_t)(tn + nr) * K + tk + c0] = make_uint2(lo, hi);
    }
}

// merged per-layer weight transpose
__global__ __launch_bounds__(256) void prep_weights(
    const float* __restrict__ wq, const float* __restrict__ wk,
    const float* __restrict__ wv, const float* __restrict__ wo,
    const float* __restrict__ w1, const float* __restrict__ w2,
    u16* __restrict__ wTdd, u16* __restrict__ w1T, u16* __restrict__ w2T)
{
    __shared__ float tile[64][65];
    const int id = blockIdx.x;
    const float* src; u16* dst; int K, N, tk64, tn64;
    if (id < 576) {
        int z = id / 144, rm = id % 144;
        src = (z == 0) ? wq : (z == 1) ? wk : (z == 2) ? wv : wo;
        dst = wTdd + (size_t)z * DM * DM;
        K = DM; N = DM; tk64 = rm / 12; tn64 = rm % 12;
    } else if (id < 1152) {
        int rm = id - 576;
        src = w1; dst = w1T; K = DM; N = FFND; tk64 = rm / 48; tn64 = rm % 48;
    } else {
        int rm = id - 1152;
        src = w2; dst = w2T; K = FFND; N = DM; tk64 = rm / 12; tn64 = rm % 12;
    }
    const int t = threadIdx.x;
    const int tk = tk64 * 64, tn = tn64 * 64;
    const int r0 = t >> 4, c0 = (t & 15) * 4;
#pragma unroll
    for (int i = 0; i < 4; ++i) {
        const float* sp = &src[(size_t)(tk + r0 + i * 16) * N + tn + c0];
        tile[r0 + i * 16][c0 + 0] = sp[0];
        tile[r0 + i * 16][c0 + 1] = sp[1];
        tile[r0 + i * 16][c0 + 2] = sp[2];
        tile[r0 + i * 16][c0 + 3] = sp[3];
    }
    __syncthreads();
#pragma unroll
    for (int i = 0; i < 4; ++i) {
        int nr = r0 + i * 16;
        u32 lo = (u32)f2b(tile[c0 + 0][nr]) | ((u32)f2b(tile[c0 + 1][nr]) << 16);
        u32 hi = (u32)f2b(tile[c0 + 2][nr]) | ((u32)f2b(tile[c0 + 3][nr]) << 16);
        *(uint2*)&dst[(size_t)(tn + nr) * K + tk + c0] = make_uint2(lo, hi);
    }
}

__global__ __launch_bounds__(256) void cvt_bf16_kernel(
    const float* __restrict__ x, u16* __restrict__ xb, int n4)
{
    int stride = gridDim.x * 256;
    for (int i = blockIdx.x * 256 + threadIdx.x; i < n4; i += stride) {
        float4 v = ((const float4*)x)[i];
        u32 lo = (u32)f2b(v.x) | ((u32)f2b(v.y) << 16);
        u32 hi = (u32)f2b(v.z) | ((u32)f2b(v.w) << 16);
        ((uint2*)xb)[i] = make_uint2(lo, hi);
    }
}

// ---------------------------------------------------------------- LayerNorm
__global__ __launch_bounds__(192) void ln_kernel(
    const float* __restrict__ in, u16* __restrict__ out,
    const float* __restrict__ g, const float* __restrict__ b)
{
    __shared__ float sA[3], sB[3];
    const int s = blockIdx.x, tid = threadIdx.x;
    float4 x = ((const float4*)(in + (size_t)s * DM))[tid];
    float sum = x.x + x.y + x.z + x.w;
#pragma unroll
    for (int o = 32; o > 0; o >>= 1) sum += __shfl_down(sum, o, 64);
    if ((tid & 63) == 0) sA[tid >> 6] = sum;
    __syncthreads();
    float m = (sA[0] + sA[1] + sA[2]) * (1.f / DM);
    float dx = x.x - m, dy = x.y - m, dz = x.z - m, dw = x.w - m;
    float vs = dx * dx + dy * dy + dz * dz + dw * dw;
#pragma unroll
    for (int o = 32; o > 0; o >>= 1) vs += __shfl_down(vs, o, 64);
    if ((tid & 63) == 0) sB[tid >> 6] = vs;
    __syncthreads();
    float rs = rsqrtf((sB[0] + sB[1] + sB[2]) * (1.f / DM) + EPS);
    float4 gv = ((const float4*)g)[tid];
    float4 bv = ((const float4*)b)[tid];
    u32 lo = (u32)f2b(dx * rs * gv.x + bv.x) | ((u32)f2b(dy * rs * gv.y + bv.y) << 16);
    u32 hi = (u32)f2b(dz * rs * gv.z + bv.z) | ((u32)f2b(dw * rs * gv.w + bv.w) << 16);
    ((uint2*)(out + (size_t)s * DM))[tid] = make_uint2(lo, hi);
}

// ------------------------------------------------- pos-embed add + cls row
__global__ __launch_bounds__(256) void posadd_kernel(
    float* __restrict__ h, const float* __restrict__ coords,
    const float* __restrict__ pe, const float* __restrict__ cls)
{
    const int s = blockIdx.x;
    const int tid = threadIdx.x;
    if (s == 0) {
        for (int c = tid; c < DM; c += 256) h[c] = cls[c] + pe[c];
    } else {
        float c0 = floorf(coords[(size_t)(s - 1) * 2 + 0] * (1.f / 256.f));
        float c1 = floorf(coords[(size_t)(s - 1) * 2 + 1] * (1.f / 256.f));
        int pos = (int)(c0 * 128.f + c1) + 1;
        float* hr = h + (size_t)s * DM;
        const float* pr = pe + (size_t)pos * DM;
        for (int c = tid; c < DM; c += 256) hr[c] += pr[c];
    }
}

// ---------------------------------------------------------------- attention (layers 0..2)
// Swapped-QK flash attention, KEY-SPLIT into 8 partials, NO max tracking
// (scores provably small, p = exp2(s_hat) raw; combine is pure sums).
// XCD-aware block swizzle: grid 1416 = 8*177, logical bid = (hw&7)*177 +
// hw>>3 so blocks sharing one (head,seg) K/V region co-reside on one XCD's
// L2 (consecutive logical bids = same head/seg, different half/qtile).
__global__ __launch_bounds__(256, 4) void attn_kernel(
    const u16* __restrict__ qb, const u16* __restrict__ kbuf, const u16* __restrict__ vb,
    u16* __restrict__ obuf, u16* __restrict__ tp, float* __restrict__ den)
{
    __shared__ u16 Vt[2][64 * 64];   // [buf][hd][key] swizzled

    const int tid = threadIdx.x, wv = tid >> 6, l = tid & 63;
    const int lq = l & 31, lh = l >> 5;
    const int bid = (blockIdx.x & 7) * 177 + (blockIdx.x >> 3);
    int b, half = 0, qtile, head, seg = 0;
    if (bid < 768) {
        b = 0; int i = bid; half = i & 1; qtile = (i >> 1) & 7;
        int rest = i >> 4; head = rest % 12; seg = rest / 12;
    } else if (bid < 1152) {
        b = 1; int i = bid - 768; half = i & 1; qtile = (i >> 1) & 7;
        int rest = i >> 4; head = rest % 12; seg = rest / 12;
    } else if (bid < 1344) {
        b = 2; int i = bid - 1152; half = i & 1; qtile = (i >> 1) & 7;
        head = i >> 4;
    } else if (bid < 1392) {
        b = 3; int i = bid - 1344; qtile = i & 3; head = i >> 2;
    } else {
        b = 4; int i = bid - 1392; qtile = i & 1; head = i >> 1;
    }
    const int slot = (b < 3) ? b * 2 + half : 3 + b;
    const int r = 1 << b;
    const int w = 1024 << b;
    const int keyoff = (b < 3) ? half * 512 : 0;
    const int ntiles = (b == 4) ? 4 : 8;
    const size_t base = (size_t)seg * w + (head & (r - 1));
    const int q0 = qtile * 128 + wv * 32;
    const size_t kstep = (size_t)r * DM;

    const size_t sq_l = base + (size_t)r * (q0 + lq);
    const u16* qp = qb + sq_l * DM + head * 64 + lh * 8;
    short8 qf[4];
#pragma unroll
    for (int s = 0; s < 4; ++s) qf[s] = *(const short8*)(qp + s * 16);

    const u16* kp = kbuf + (base + (size_t)r * (keyoff + lq)) * DM + head * 64 + lh * 8;
    const int c = tid & 7, pp = tid >> 3;
    const u16* vsrc = vb + (base + (size_t)r * (keyoff + 2 * pp)) * DM + head * 64 + c * 8;

#define VPACK(dstbuf, A8, B8) do {                                          \
    _Pragma("unroll") for (int j = 0; j < 8; ++j) {                         \
        int i_ = (j + c) & 7; int hd_ = c * 8 + i_;                         \
        u32 val_ = (u32)(u16)(A8)[i_] | ((u32)(u16)(B8)[i_] << 16);         \
        int byte_ = hd_ * 128 + ((pp * 4) ^ (i_ << 4));                     \
        *(u32*)&Vt[dstbuf][byte_ >> 1] = val_; } } while (0)

    f32x16 oacc0 = {0.f,0.f,0.f,0.f,0.f,0.f,0.f,0.f,0.f,0.f,0.f,0.f,0.f,0.f,0.f,0.f};
    f32x16 oacc1 = oacc0;
    float dl = 0.f;

    short8 van = *(const short8*)vsrc;
    short8 vbn = *(const short8*)(vsrc + kstep);
    VPACK(0, van, vbn);
    van = *(const short8*)(vsrc + 64 * kstep);
    vbn = *(const short8*)(vsrc + 65 * kstep);
    short8 kf[8];
#pragma unroll
    for (int s = 0; s < 4; ++s) {
        kf[s]     = *(const short8*)(kp + s * 16);
        kf[4 + s] = *(const short8*)(kp + 32 * kstep + s * 16);
    }
    lds_barrier();

    for (int t = 0; t < ntiles; ++t) {
        const int curb = t & 1;
        f32x16 s0 = {0.f,0.f,0.f,0.f,0.f,0.f,0.f,0.f,0.f,0.f,0.f,0.f,0.f,0.f,0.f,0.f};
        f32x16 s1 = s0;
#pragma unroll
        for (int s = 0; s < 4; ++s)
            s0 = __builtin_amdgcn_mfma_f32_32x32x16_bf16(kf[s], qf[s], s0, 0, 0, 0);
#pragma unroll
        for (int s = 0; s < 4; ++s)
            s1 = __builtin_amdgcn_mfma_f32_32x32x16_bf16(kf[4 + s], qf[s], s1, 0, 0, 0);

        // ---- prefetch K(t+1): stays in flight across the tile barrier
        if (t + 1 < ntiles) {
            const u16* kn = kp + (size_t)(t + 1) * 64 * kstep;
#pragma unroll
            for (int s = 0; s < 4; ++s) {
                kf[s]     = *(const short8*)(kn + s * 16);
                kf[4 + s] = *(const short8*)(kn + 32 * kstep + s * 16);
            }
        }

        // ---- raw exponentials (no max tracking)
        float ds = 0.f;
#pragma unroll
        for (int i = 0; i < 16; ++i) { s0[i] = exp2f(s0[i]); ds += s0[i]; }
#pragma unroll
        for (int i = 0; i < 16; ++i) { s1[i] = exp2f(s1[i]); ds += s1[i]; }
        ds += __shfl_xor(ds, 32, 64);
        dl += ds;

        if (t + 1 < ntiles) VPACK(curb ^ 1, van, vbn);
        if (t + 2 < ntiles) {
            van = *(const short8*)(vsrc + (size_t)(t + 2) * 64 * kstep);
            vbn = *(const short8*)(vsrc + ((size_t)(t + 2) * 64 + 1) * kstep);
        }

        // ---- P -> bf16 fragments in-register, PV from Vt[curb]
#pragma unroll
        for (int kb2 = 0; kb2 < 2; ++kb2) {
            u32 wd[8];
#pragma unroll
            for (int j = 0; j < 8; ++j) {
                float lo = (kb2 == 0) ? s0[2 * j] : s1[2 * j];
                float hi = (kb2 == 0) ? s0[2 * j + 1] : s1[2 * j + 1];
                asm("v_cvt_pk_bf16_f32 %0, %1, %2" : "=v"(wd[j]) : "v"(lo), "v"(hi));
            }
#pragma unroll
            for (int ks2 = 0; ks2 < 2; ++ks2) {
                i32x2 X = __builtin_amdgcn_permlane32_swap(
                    (int)wd[ks2 * 4 + 0], (int)wd[ks2 * 4 + 2], false, false);
                i32x2 Y = __builtin_amdgcn_permlane32_swap(
                    (int)wd[ks2 * 4 + 1], (int)wd[ks2 * 4 + 3], false, false);
                union { u32 u[4]; short8 s; } pk;
                pk.u[0] = (u32)X[0]; pk.u[1] = (u32)Y[0];
                pk.u[2] = (u32)X[1]; pk.u[3] = (u32)Y[1];
                const int tt = kb2 * 2 + ks2;
#pragma unroll
                for (int hg = 0; hg < 2; ++hg) {
                    int row = hg * 32 + lq;
                    int byteoff = row * 128 + ((lh * 16 + tt * 32) ^ ((row & 7) << 4));
                    short8 vf = *(const short8*)&Vt[curb][byteoff >> 1];
                    if (hg == 0)
                        oacc0 = __builtin_amdgcn_mfma_f32_32x32x16_bf16(pk.s, vf, oacc0, 0, 0, 0);
                    else
                        oacc1 = __builtin_amdgcn_mfma_f32_32x32x16_bf16(pk.s, vf, oacc1, 0, 0, 0);
                }
            }
        }
        lds_barrier();
    }

    // ---- epilogue: unnormalized o (bf16) + denominator (f32)
    u16* ob = (slot == 7) ? tp : obuf + (size_t)slot * S_LEN * DM;
    float* den_b = den + (size_t)slot * S_LEN * NHEAD;
    if (l < 32) den_b[sq_l * NHEAD + head] = dl;
#pragma unroll
    for (int reg = 0; reg < 16; ++reg) {
        int qloc = (reg & 3) + 8 * (reg >> 2) + 4 * lh;
        size_t sq = base + (size_t)r * (q0 + qloc);
        u16* orow = ob + sq * DM + head * 64;
        u32 pk2;
        asm("v_cvt_pk_bf16_f32 %0, %1, %2"
            : "=v"(pk2) : "v"(oacc0[reg]), "v"(oacc1[reg]));
        orow[lq]      = (u16)(pk2 & 0xffff);
        orow[32 + lq] = (u16)(pk2 >> 16);
    }
#undef VPACK
}

// ---- LongNet combine: pure sums (o unnormalized, den linear).
// Structural coverage: slot b valid for (s,head) iff (s^head)&(r-1)==0.
__global__ __launch_bounds__(192) void combine_kernel(
    const u16* __restrict__ obuf, const float* __restrict__ den,
    u16* __restrict__ t)
{
    const int s = blockIdx.x;
    const int tid = threadIdx.x;
    const int c0 = tid * 4, head = c0 >> 6;
    const size_t SD = (size_t)S_LEN * DM;
    const size_t SN = (size_t)S_LEN * NHEAD;
    const int sx = s ^ head;
    bool val[8];
    val[0] = val[1] = true;
    val[2] = val[3] = (sx & 1) == 0;
    val[4] = val[5] = (sx & 3) == 0;
    val[6] = (sx & 7) == 0;
    val[7] = (s & 15) == head;
    float wsum = 0.f, o0 = 0.f, o1 = 0.f, o2 = 0.f, o3 = 0.f;
#pragma unroll
    for (int b = 0; b < 8; ++b) {
        if (val[b]) {
            wsum += den[b * SN + (size_t)s * NHEAD + head];
            const u16* src = (b == 7) ? t : obuf + (size_t)b * SD;
            uint2 u = *(const uint2*)(src + (size_t)s * DM + c0);
            o0 += b2f((u16)(u.x & 0xffff));
            o1 += b2f((u16)(u.x >> 16));
            o2 += b2f((u16)(u.y & 0xffff));
            o3 += b2f((u16)(u.y >> 16));
        }
    }
    float inv = 1.f / wsum;
    u32 lo = (u32)f2b(o0 * inv) | ((u32)f2b(o1 * inv) << 16);
    u32 hi = (u32)f2b(o2 * inv) | ((u32)f2b(o3 * inv) << 16);
    ((uint2*)(t + (size_t)s * DM))[tid] = make_uint2(lo, hi);
}

// ---------------------------------------------------------------- layer-3 cls path
__global__ __launch_bounds__(256) void cls_attn_kernel(
    const u16* __restrict__ qb, const u16* __restrict__ kb,
    const u16* __restrict__ vb, float* __restrict__ cpart,
    float* __restrict__ lsep)
{
    __shared__ float q0[64];
    __shared__ float pbuf[128];
    __shared__ float red[8];
    __shared__ float po[256];
    const int blk = blockIdx.x, tid = threadIdx.x;
    int b, head, chunk;
    if (blk < 96)       { b = 0; head = blk >> 3; chunk = blk & 7; }
    else if (blk < 144) { int i = blk - 96;  b = 1; head = (i >> 3) * 2; chunk = i & 7; }
    else if (blk < 168) { int i = blk - 144; b = 2; head = (i >> 3) * 4; chunk = i & 7; }
    else if (blk < 176) { int i = blk - 168; b = 3; head = (i >> 2) * 8; chunk = i & 3; }
    else                { int i = blk - 176; b = 4; head = 0;            chunk = i; }
    const int r = 1 << b;
    if (tid < 64) q0[tid] = b2f(qb[head * 64 + tid]);  // row 0, pre-scaled log2e/8
    __syncthreads();

    float sc = -1e30f;
    if (tid < 128) {
        const int j = chunk * 128 + tid;
        const u16* kp = kb + (size_t)j * r * DM + head * 64;
        float acc = 0.f;
#pragma unroll
        for (int d8 = 0; d8 < 8; ++d8) {
            short8 kv = *(const short8*)(kp + d8 * 8);
#pragma unroll
            for (int jj = 0; jj < 8; ++jj)
                acc += q0[d8 * 8 + jj] * b2f((u16)kv[jj]);
        }
        sc = acc;
    }
    float mxw = sc;
#pragma unroll
    for (int o = 1; o < 64; o <<= 1) mxw = fmaxf(mxw, __shfl_xor(mxw, o, 64));
    if ((tid & 63) == 0) red[tid >> 6] = mxw;
    __syncthreads();
    const float bm = fmaxf(red[0], red[1]);
    float p = 0.f;
    if (tid < 128) { p = exp2f(sc - bm); pbuf[tid] = p; }
    float sw = p;
#pragma unroll
    for (int o = 1; o < 64; o <<= 1) sw += __shfl_xor(sw, o, 64);
    if ((tid & 63) == 0) red[4 + (tid >> 6)] = sw;
    __syncthreads();
    const float dsum = red[4] + red[5];

    const int hd = tid & 63, ch = tid >> 6;
    const u16* vp = vb + (size_t)(chunk * 128 + ch * 32) * r * DM + head * 64 + hd;
    const size_t vstep = (size_t)r * DM;
    float o = 0.f;
#pragma unroll 8
    for (int j = 0; j < 32; ++j)
        o += pbuf[ch * 32 + j] * b2f(vp[(size_t)j * vstep]);
    po[tid] = o;
    __syncthreads();
    if (tid < 64)
        cpart[(size_t)blk * 64 + tid] =
            (po[tid] + po[tid + 64] + po[tid + 128] + po[tid + 192]) / dsum;
    if (tid == 0) lsep[blk] = bm + log2f(dsum);
}

__global__ __launch_bounds__(64) void cls_combine_kernel(
    const float* __restrict__ cpart, const float* __restrict__ lsep,
    u16* __restrict__ t)
{
    const int head = blockIdx.x, tid = threadIdx.x;
#define FORALL_PARTS(EXPR)                                                    \
    for (int c = 0; c < 8; ++c) { int blk = head * 8 + c; EXPR; }             \
    if (!(head & 1)) for (int c = 0; c < 8; ++c) { int blk = 96 + (head >> 1) * 8 + c; EXPR; } \
    if (!(head & 3)) for (int c = 0; c < 8; ++c) { int blk = 144 + (head >> 2) * 8 + c; EXPR; } \
    if (!(head & 7)) for (int c = 0; c < 4; ++c) { int blk = 168 + (head >> 3) * 4 + c; EXPR; } \
    if (head == 0)  for (int c = 0; c < 2; ++c) { int blk = 176 + c; EXPR; }
    float mx = -1e30f;
    FORALL_PARTS(mx = fmaxf(mx, lsep[blk]))
    float ws = 0.f, ov = 0.f;
    FORALL_PARTS({ float wb = exp2f(lsep[blk] - mx); ws += wb;
                   ov += wb * cpart[(size_t)blk * 64 + tid]; })
    t[head * 64 + tid] = f2b(ov / ws);
#undef FORALL_PARTS
}

// row-0 GEMV, 8 threads per output (width-8 shuffle reduce), 32 outputs/block
__global__ __launch_bounds__(256) void row_gemv_kernel(
    const u16* __restrict__ x, const u16* __restrict__ wT,
    const float* __restrict__ bias, const float* __restrict__ res,
    float* __restrict__ outf, u16* __restrict__ outb, int K, int dogelu)
{
    __shared__ float xs[3072];
    const int tid = threadIdx.x;
    for (int i = tid; i < K; i += 256) xs[i] = b2f(x[i]);
    __syncthreads();
    const int n = blockIdx.x * 32 + (tid >> 3);
    const int kp = tid & 7;
    const u16* wrow = wT + (size_t)n * K;
    float acc = 0.f;
    for (int k = kp * 8; k < K; k += 64) {
        short8 wv = *(const short8*)(wrow + k);
#pragma unroll
        for (int j = 0; j < 8; ++j) acc += xs[k + j] * b2f((u16)wv[j]);
    }
    acc += __shfl_down(acc, 4, 8);
    acc += __shfl_down(acc, 2, 8);
    acc += __shfl_down(acc, 1, 8);
    if (kp == 0) {
        float v = acc + bias[n];
        if (dogelu) v = gelu_tanh(v);
        if (res) v += res[n];
        if (outf) outf[n] = v;
        if (outb) outb[n] = f2b(v);
    }
}

// ---------------------------------------------------- final double-LN, row 0
__global__ __launch_bounds__(256) void final_ln_kernel(
    const float* __restrict__ h,
    const float* __restrict__ g1, const float* __restrict__ b1,
    const float* __restrict__ g2, const float* __restrict__ b2,
    float* __restrict__ out)
{
    __shared__ float sbuf[4];
    const int tid = threadIdx.x;
    float x0 = h[tid], x1 = h[tid + 256], x2 = h[tid + 512];
    float m = block_reduce_sum(x0 + x1 + x2, sbuf) * (1.f / DM);
    float d0 = x0 - m, d1 = x1 - m, d2 = x2 - m;
    float var = block_reduce_sum(d0 * d0 + d1 * d1 + d2 * d2, sbuf) * (1.f / DM);
    float rs = rsqrtf(var + EPS);
    float y0 = d0 * rs * g1[tid]       + b1[tid];
    float y1 = d1 * rs * g1[tid + 256] + b1[tid + 256];
    float y2 = d2 * rs * g1[tid + 512] + b1[tid + 512];
    m = block_reduce_sum(y0 + y1 + y2, sbuf) * (1.f / DM);
    d0 = y0 - m; d1 = y1 - m; d2 = y2 - m;
    var = block_reduce_sum(d0 * d0 + d1 * d1 + d2 * d2, sbuf) * (1.f / DM);
    rs = rsqrtf(var + EPS);
    out[tid]       = d0 * rs * g2[tid]       + b2[tid];
    out[tid + 256] = d1 * rs * g2[tid + 256] + b2[tid + 256];
    out[tid + 512] = d2 * rs * g2[tid + 512] + b2[tid + 512];
}

// ---------------------------------------------------------------- launcher
extern "C" void kernel_launch(void* const* d_in, const int* in_sizes, int n_in,
                              void* d_out, int out_size, void* d_ws, size_t ws_size,
                              hipStream_t stream)
{
    (void)in_sizes; (void)n_in; (void)out_size; (void)ws_size;
    const float* x        = (const float*)d_in[0];
    const float* coords   = (const float*)d_in[1];
    const float* pos_emb  = (const float*)d_in[2];
    const float* cls_tok  = (const float*)d_in[3];
    const float* patch_w  = (const float*)d_in[4];
    const float* patch_b  = (const float*)d_in[5];
    const float* ln1_g    = (const float*)d_in[6];
    const float* ln1_b    = (const float*)d_in[7];
    const float* wq       = (const float*)d_in[8];
    const float* bq       = (const float*)d_in[9];
    const float* wk       = (const float*)d_in[10];
    const float* bk       = (const float*)d_in[11];
    const float* wv       = (const float*)d_in[12];
    const float* bv       = (const float*)d_in[13];
    const float* wo       = (const float*)d_in[14];
    const float* bo       = (const float*)d_in[15];
    const float* ln2_g    = (const float*)d_in[16];
    const float* ln2_b    = (const float*)d_in[17];
    const float* w1       = (const float*)d_in[18];
    const float* b1       = (const float*)d_in[19];
    const float* w2       = (const float*)d_in[20];
    const float* b2       = (const float*)d_in[21];
    const float* enc_g    = (const float*)d_in[22];
    const float* enc_b    = (const float*)d_in[23];
    const float* norm_g   = (const float*)d_in[24];
    const float* norm_b   = (const float*)d_in[25];
    float* out = (float*)d_out;

    const size_t SD = (size_t)S_LEN * DM;
    const size_t DD = (size_t)DM * DM;
    const size_t DF = (size_t)DM * FFND;
    const size_t SN = (size_t)S_LEN * NHEAD;

    char* p = (char*)d_ws;
    float* h   = (float*)p;              p += SD * 4;
    u16* t     = (u16*)p;                p += SD * 2;
    u16* qb    = (u16*)p;                p += SD * 2;
    u16* kb    = (u16*)p;                p += SD * 2;
    u16* vb    = (u16*)p;                p += SD * 2;
    float* den = (float*)p;              p += 8 * SN * 4;
    u16* obuf  = (u16*)p;                p += 7 * SD * 2;  // slot 7 == t
    u16* ffn   = obuf;                   // aliases obuf (dead during FFN)
    u16* xb    = obuf;                   // aliases obuf (used only pre-layer0)
    u16* pwT   = (u16*)p;                p += (size_t)DIN * DM * 2;
    u16* wTdd  = (u16*)p;                p += 4 * DD * 2;
    u16* w1T   = (u16*)p;                p += DF * 2;
    u16* w2T   = (u16*)p;                p += DF * 2;
    // layer-3 cls partials reuse the (then-idle) den buffer
    float* cpart = den;                  // 178*64 floats
    float* lsep  = den + 178 * 64;       // 178 floats

    cvt_bf16_kernel<<<2048, 256, 0, stream>>>(x, xb, (L_LEN * DIN) / 4);
    transpose_cvt<<<dim3(DM / 64, DIN / 64, 1), 256, 0, stream>>>(
        patch_w, patch_w, patch_w, patch_w, pwT, DIN, DM);
    gemm6464_kernel<<<dim3(DM / 64, 64), 256, 0, stream>>>(
        xb, pwT, patch_b, nullptr, h + DM, nullptr, L_LEN, DM, DIN, 1.f, 0);
    posadd_kernel<<<S_LEN, 256, 0, stream>>>(h, coords, pos_emb, cls_tok);

    for (int l = 0; l < 4; ++l) {
        const size_t lDD = (size_t)l * DD;
        const size_t lDF = (size_t)l * DF;
        prep_weights<<<1728, 256, 0, stream>>>(
            wq + lDD, wk + lDD, wv + lDD, wo + lDD, w1 + lDF, w2 + lDF,
            wTdd, w1T, w2T);

        ln_kernel<<<S_LEN, 192, 0, stream>>>(h, t, ln1_g + l * DM, ln1_b + l * DM);
        qkv_kernel<<<dim3(6, 32, 3), 256, 0, stream>>>(
            t, wTdd, wTdd + DD, wTdd + 2 * DD,
            bq + l * DM, bk + l * DM, bv + l * DM, qb, kb, vb);

        if (l < 3) {
            attn_kernel<<<1416, 256, 0, stream>>>(qb, kb, vb, obuf, t, den);
            combine_kernel<<<S_LEN, 192, 0, stream>>>(obuf, den, t);
            gemm6464_kernel<<<dim3(12, 64), 256, 0, stream>>>(
                t, wTdd + 3 * DD, bo + l * DM, h, h, nullptr, S_LEN, DM, DM, 1.f, 0);
            ln_kernel<<<S_LEN, 192, 0, stream>>>(h, t, ln2_g + l * DM, ln2_b + l * DM);
            gemm128_kernel<<<dim3(24, 32), 256, 0, stream>>>(
                t, w1T, b1 + (size_t)l * FFND, nullptr, nullptr, ffn,
                S_LEN, FFND, DM, 1.f, 1);
            gemm6464_kernel<<<dim3(12, 64), 256, 0, stream>>>(
                ffn, w2T, b2 + l * DM, h, h, nullptr, S_LEN, DM, FFND, 1.f, 0);
        } else {
            // Last layer: only the cls row (s=0) is consumed downstream.
            cls_attn_kernel<<<178, 256, 0, stream>>>(qb, kb, vb, cpart, lsep);
            cls_combine_kernel<<<NHEAD, 64, 0, stream>>>(cpart, lsep, t);
            row_gemv_kernel<<<24, 256, 0, stream>>>(
                t, wTdd + 3 * DD, bo + l * DM, h, h, nullptr, DM, 0);
            ln_kernel<<<1, 192, 0, stream>>>(h, t, ln2_g + l * DM, ln2_b + l * DM);
            row_gemv_kernel<<<96, 256, 0, stream>>>(
                t, w1T, b1 + (size_t)l * FFND, nullptr, nullptr, ffn, DM, 1);
            row_gemv_kernel<<<24, 256, 0, stream>>>(
                ffn, w2T, b2 + l * DM, h, h, nullptr, FFND, 0);
        }
    }
    final_ln_kernel<<<1, 256, 0, stream>>>(h, enc_g, enc_b, norm_g, norm_b, out);
}

// Round 15
// 930.692 us; speedup vs baseline: 1.0408x; 1.0408x over previous
//
#include <hip/hip_runtime.h>
#include <hip/hip_bf16.h>
#include <math.h>
#include <stdint.h>

#define S_LEN 4096
#define L_LEN 4095
#define DIN   1536
#define DM    768
#define NHEAD 12
#define HDIM  64
#define FFND  3072
#define NEGV  (-1e9f)
#define EPS   1e-5f

typedef unsigned short u16;
typedef unsigned int   u32;
typedef short short8 __attribute__((ext_vector_type(8)));
typedef float f32x4 __attribute__((ext_vector_type(4)));
typedef float f32x16 __attribute__((ext_vector_type(16)));
typedef int i32x2 __attribute__((ext_vector_type(2)));

// ---------------------------------------------------------------- helpers
__device__ __forceinline__ u16 f2b(float f) {
    union { float f; u32 u; } x; x.f = f;
    u32 r = (x.u + 0x7FFF + ((x.u >> 16) & 1)) >> 16;
    return (u16)r;
}
__device__ __forceinline__ float b2f(u16 v) {
    union { u32 u; float f; } x; x.u = ((u32)v) << 16;
    return x.f;
}
__device__ __forceinline__ float gelu_tanh(float x) {
    float x3 = x * x * x;
    return 0.5f * x * (1.f + tanhf(0.7978845608f * (x + 0.044715f * x3)));
}
__device__ __forceinline__ float block_reduce_sum(float v, float* sbuf) {
#pragma unroll
    for (int o = 32; o > 0; o >>= 1) v += __shfl_down(v, o, 64);
    __syncthreads();
    if ((threadIdx.x & 63) == 0) sbuf[threadIdx.x >> 6] = v;
    __syncthreads();
    return sbuf[0] + sbuf[1] + sbuf[2] + sbuf[3];
}
__device__ __forceinline__ void gload16(const void* g, void* l) {
    __builtin_amdgcn_global_load_lds((const __attribute__((address_space(1))) void*)g,
                                     (__attribute__((address_space(3))) void*)l,
                                     16, 0, 0);
}
// barrier draining only LDS ops; global register prefetches stay in flight
__device__ __forceinline__ void lds_barrier() {
    asm volatile("s_waitcnt lgkmcnt(0)" ::: "memory");
    __builtin_amdgcn_s_barrier();
    __builtin_amdgcn_sched_barrier(0);
}

// ---------------------------------------------------------------- GEMM (bf16 MFMA, B^T layout)
template <int BM, int BN>
__device__ __forceinline__ void gemm_bt(
    const u16* __restrict__ A, const u16* __restrict__ Bt,
    const float* __restrict__ bias, const float* __restrict__ res,
    float* __restrict__ outf, u16* __restrict__ outb,
    int M, int N, int K, float scale, int dogelu, int bx, int by)
{
    constexpr int MI = BM / 32;
    constexpr int NI = BN / 32;
    constexpr int AI = BM / 32;
    constexpr int BI = BN / 32;
    __shared__ u16 As[BM * 64];
    __shared__ u16 Bs[BN * 64];
    const int tid = threadIdx.x, wv = tid >> 6, l = tid & 63;
    const int bm = by * BM, bn = bx * BN;
    const int wm = wv >> 1, wn = wv & 1;

    f32x4 acc[MI][NI];
#pragma unroll
    for (int i = 0; i < MI; ++i)
#pragma unroll
        for (int j = 0; j < NI; ++j) acc[i][j] = (f32x4){0.f, 0.f, 0.f, 0.f};

    for (int k0 = 0; k0 < K; k0 += 64) {
#pragma unroll
        for (int i = 0; i < AI; ++i) {
            int row = (wv * AI + i) * 8 + (l >> 3);
            int col = ((l & 7) ^ (row & 7)) * 8;
            int grow = bm + row; if (grow > M - 1) grow = M - 1;
            gload16(A + (size_t)grow * K + k0 + col, &As[(wv * AI + i) * 512]);
        }
#pragma unroll
        for (int i = 0; i < BI; ++i) {
            int row = (wv * BI + i) * 8 + (l >> 3);
            int col = ((l & 7) ^ (row & 7)) * 8;
            gload16(Bt + (size_t)(bn + row) * K + k0 + col, &Bs[(wv * BI + i) * 512]);
        }
        __syncthreads();
#pragma unroll
        for (int kc = 0; kc < 2; ++kc) {
            short8 a[MI], b[NI];
#pragma unroll
            for (int mi = 0; mi < MI; ++mi) {
                int row = wm * (BM / 2) + mi * 16 + (l & 15);
                int off = ((l >> 4) * 16 + kc * 64) ^ ((row & 7) << 4);
                a[mi] = *(const short8*)&As[(row * 128 + off) >> 1];
            }
#pragma unroll
            for (int ni = 0; ni < NI; ++ni) {
                int row = wn * (BN / 2) + ni * 16 + (l & 15);
                int off = ((l >> 4) * 16 + kc * 64) ^ ((row & 7) << 4);
                b[ni] = *(const short8*)&Bs[(row * 128 + off) >> 1];
            }
#pragma unroll
            for (int mi = 0; mi < MI; ++mi)
#pragma unroll
                for (int ni = 0; ni < NI; ++ni)
                    acc[mi][ni] = __builtin_amdgcn_mfma_f32_16x16x32_bf16(
                        a[mi], b[ni], acc[mi][ni], 0, 0, 0);
        }
        __syncthreads();
    }
#pragma unroll
    for (int mi = 0; mi < MI; ++mi) {
#pragma unroll
        for (int rg = 0; rg < 4; ++rg) {
            int row = bm + wm * (BM / 2) + mi * 16 + (l >> 4) * 4 + rg;
            if (row >= M) continue;
#pragma unroll
            for (int ni = 0; ni < NI; ++ni) {
                int col = bn + wn * (BN / 2) + ni * 16 + (l & 15);
                float v = (acc[mi][ni][rg] + bias[col]) * scale;
                if (dogelu) v = gelu_tanh(v);
                if (res) v += res[(size_t)row * N + col];
                if (outf) outf[(size_t)row * N + col] = v;
                if (outb) outb[(size_t)row * N + col] = f2b(v);
            }
        }
    }
}

__global__ __launch_bounds__(256) void gemm128_kernel(
    const u16* __restrict__ A, const u16* __restrict__ Bt,
    const float* __restrict__ bias, const float* __restrict__ res,
    float* __restrict__ outf, u16* __restrict__ outb,
    int M, int N, int K, float scale, int dogelu)
{
    gemm_bt<128, 128>(A, Bt, bias, res, outf, outb, M, N, K, scale, dogelu,
                      blockIdx.x, blockIdx.y);
}
__global__ __launch_bounds__(256) void gemm6464_kernel(
    const u16* __restrict__ A, const u16* __restrict__ Bt,
    const float* __restrict__ bias, const float* __restrict__ res,
    float* __restrict__ outf, u16* __restrict__ outb,
    int M, int N, int K, float scale, int dogelu)
{
    gemm_bt<64, 64>(A, Bt, bias, res, outf, outb, M, N, K, scale, dogelu,
                    blockIdx.x, blockIdx.y);
}
__global__ __launch_bounds__(256) void qkv_kernel(
    const u16* __restrict__ t,
    const u16* __restrict__ wqT, const u16* __restrict__ wkT, const u16* __restrict__ wvT,
    const float* __restrict__ bq, const float* __restrict__ bk, const float* __restrict__ bv,
    u16* __restrict__ q, u16* __restrict__ k, u16* __restrict__ v)
{
    int z = blockIdx.z;
    const u16* B = (z == 0) ? wqT : (z == 1) ? wkT : wvT;
    const float* bias = (z == 0) ? bq : (z == 1) ? bk : bv;
    u16* C = (z == 0) ? q : (z == 1) ? k : v;
    // Q additionally scaled by HD^-0.5 * log2(e) so softmax can use exp2
    float scale = (z == 0) ? 0.125f * 1.4426950408889634f : 1.0f;
    gemm_bt<128, 128>(t, B, bias, nullptr, nullptr, C, S_LEN, DM, DM, scale, 0,
                      blockIdx.x, blockIdx.y);
}

// ---------------------------------------------------------- transpose+convert
__global__ __launch_bounds__(256) void transpose_cvt(
    const float* __restrict__ s0, const float* __restrict__ s1,
    const float* __restrict__ s2, const float* __restrict__ s3,
    u16* __restrict__ dst, int K, int N)
{
    int z = blockIdx.z;
    const float* src = (z == 0) ? s0 : (z == 1) ? s1 : (z == 2) ? s2 : s3;
    u16* d = dst + (size_t)z * K * N;
    __shared__ float tile[64][65];
    const int t = threadIdx.x;
    const int tk = blockIdx.y * 64, tn = blockIdx.x * 64;
    const int r0 = t >> 4, c0 = (t & 15) * 4;
#pragma unroll
    for (int i = 0; i < 4; ++i) {
        const float* sp = &src[(size_t)(tk + r0 + i * 16) * N + tn + c0];
        tile[r0 + i * 16][c0 + 0] = sp[0];
        tile[r0 + i * 16][c0 + 1] = sp[1];
        tile[r0 + i * 16][c0 + 2] = sp[2];
        tile[r0 + i * 16][c0 + 3] = sp[3];
    }
    __syncthreads();
#pragma unroll
    for (int i = 0; i < 4; ++i) {
        int nr = r0 + i * 16;
        u32 lo = (u32)f2b(tile[c0 + 0][nr]) | ((u32)f2b(tile[c0 + 1][nr]) << 16);
        u32 hi = (u32)f2b(tile[c0 + 2][nr]) | ((u32)f2b(tile[c0 + 3][nr]) << 16);
        *(uint2*)&d[(size_t)(tn + nr) * K + tk + c0] = make_uint2(lo, hi);
    }
}

// merged per-layer weight transpose
__global__ __launch_bounds__(256) void prep_weights(
    const float* __restrict__ wq, const float* __restrict__ wk,
    const float* __restrict__ wv, const float* __restrict__ wo,
    const float* __restrict__ w1, const float* __restrict__ w2,
    u16* __restrict__ wTdd, u16* __restrict__ w1T, u16* __restrict__ w2T)
{
    __shared__ float tile[64][65];
    const int id = blockIdx.x;
    const float* src; u16* dst; int K, N, tk64, tn64;
    if (id < 576) {
        int z = id / 144, rm = id % 144;
        src = (z == 0) ? wq : (z == 1) ? wk : (z == 2) ? wv : wo;
        dst = wTdd + (size_t)z * DM * DM;
        K = DM; N = DM; tk64 = rm / 12; tn64 = rm % 12;
    } else if (id < 1152) {
        int rm = id - 576;
        src = w1; dst = w1T; K = DM; N = FFND; tk64 = rm / 48; tn64 = rm % 48;
    } else {
        int rm = id - 1152;
        src = w2; dst = w2T; K = FFND; N = DM; tk64 = rm / 12; tn64 = rm % 12;
    }
    const int t = threadIdx.x;
    const int tk = tk64 * 64, tn = tn64 * 64;
    const int r0 = t >> 4, c0 = (t & 15) * 4;
#pragma unroll
    for (int i = 0; i < 4; ++i) {
        const float* sp = &src[(size_t)(tk + r0 + i * 16) * N + tn + c0];
        tile[r0 + i * 16][c0 + 0] = sp[0];
        tile[r0 + i * 16][c0 + 1] = sp[1];
        tile[r0 + i * 16][c0 + 2] = sp[2];
        tile[r0 + i * 16][c0 + 3] = sp[3];
    }
    __syncthreads();
#pragma unroll
    for (int i = 0; i < 4; ++i) {
        int nr = r0 + i * 16;
        u32 lo = (u32)f2b(tile[c0 + 0][nr]) | ((u32)f2b(tile[c0 + 1][nr]) << 16);
        u32 hi = (u32)f2b(tile[c0 + 2][nr]) | ((u32)f2b(tile[c0 + 3][nr]) << 16);
        *(uint2*)&dst[(size_t)(tn + nr) * K + tk + c0] = make_uint2(lo, hi);
    }
}

__global__ __launch_bounds__(256) void cvt_bf16_kernel(
    const float* __restrict__ x, u16* __restrict__ xb, int n4)
{
    int stride = gridDim.x * 256;
    for (int i = blockIdx.x * 256 + threadIdx.x; i < n4; i += stride) {
        float4 v = ((const float4*)x)[i];
        u32 lo = (u32)f2b(v.x) | ((u32)f2b(v.y) << 16);
        u32 hi = (u32)f2b(v.z) | ((u32)f2b(v.w) << 16);
        ((uint2*)xb)[i] = make_uint2(lo, hi);
    }
}

// ---------------------------------------------------------------- LayerNorm
__global__ __launch_bounds__(192) void ln_kernel(
    const float* __restrict__ in, u16* __restrict__ out,
    const float* __restrict__ g, const float* __restrict__ b)
{
    __shared__ float sA[3], sB[3];
    const int s = blockIdx.x, tid = threadIdx.x;
    float4 x = ((const float4*)(in + (size_t)s * DM))[tid];
    float sum = x.x + x.y + x.z + x.w;
#pragma unroll
    for (int o = 32; o > 0; o >>= 1) sum += __shfl_down(sum, o, 64);
    if ((tid & 63) == 0) sA[tid >> 6] = sum;
    __syncthreads();
    float m = (sA[0] + sA[1] + sA[2]) * (1.f / DM);
    float dx = x.x - m, dy = x.y - m, dz = x.z - m, dw = x.w - m;
    float vs = dx * dx + dy * dy + dz * dz + dw * dw;
#pragma unroll
    for (int o = 32; o > 0; o >>= 1) vs += __shfl_down(vs, o, 64);
    if ((tid & 63) == 0) sB[tid >> 6] = vs;
    __syncthreads();
    float rs = rsqrtf((sB[0] + sB[1] + sB[2]) * (1.f / DM) + EPS);
    float4 gv = ((const float4*)g)[tid];
    float4 bv = ((const float4*)b)[tid];
    u32 lo = (u32)f2b(dx * rs * gv.x + bv.x) | ((u32)f2b(dy * rs * gv.y + bv.y) << 16);
    u32 hi = (u32)f2b(dz * rs * gv.z + bv.z) | ((u32)f2b(dw * rs * gv.w + bv.w) << 16);
    ((uint2*)(out + (size_t)s * DM))[tid] = make_uint2(lo, hi);
}

// ------------------------------------------------- pos-embed add + cls row
__global__ __launch_bounds__(256) void posadd_kernel(
    float* __restrict__ h, const float* __restrict__ coords,
    const float* __restrict__ pe, const float* __restrict__ cls)
{
    const int s = blockIdx.x;
    const int tid = threadIdx.x;
    if (s == 0) {
        for (int c = tid; c < DM; c += 256) h[c] = cls[c] + pe[c];
    } else {
        float c0 = floorf(coords[(size_t)(s - 1) * 2 + 0] * (1.f / 256.f));
        float c1 = floorf(coords[(size_t)(s - 1) * 2 + 1] * (1.f / 256.f));
        int pos = (int)(c0 * 128.f + c1) + 1;
        float* hr = h + (size_t)s * DM;
        const float* pr = pe + (size_t)pos * DM;
        for (int c = tid; c < DM; c += 256) hr[c] += pr[c];
    }
}

// ---------------------------------------------------------------- attention (layers 0..2)
// Swapped-QK flash attention, pipelined, KEY-SPLIT into 8 partials:
//   slots 0/1 = b0 key-halves, 2/3 = b1, 4/5 = b2, 6 = b3, 7 = b4.
// Max-tracking with defer-THR=8 (R11-proven variant).  XCD-aware block
// swizzle: grid 1416 = 8*177 -> blocks sharing a (head,seg) K/V region
// co-reside on one XCD's L2.
__global__ __launch_bounds__(256, 3) void attn_kernel(
    const u16* __restrict__ qb, const u16* __restrict__ kbuf, const u16* __restrict__ vb,
    u16* __restrict__ obuf, u16* __restrict__ tp, float* __restrict__ lse)
{
    __shared__ u16 Vt[2][64 * 64];   // [buf][hd][key] swizzled
    __shared__ float dbuf[4][32];

    const int tid = threadIdx.x, wv = tid >> 6, l = tid & 63;
    const int lq = l & 31, lh = l >> 5;
    const int bid = (blockIdx.x & 7) * 177 + (blockIdx.x >> 3);
    int b, half = 0, qtile, head, seg = 0;
    if (bid < 768) {
        b = 0; int i = bid; half = i & 1; qtile = (i >> 1) & 7;
        int rest = i >> 4; head = rest % 12; seg = rest / 12;
    } else if (bid < 1152) {
        b = 1; int i = bid - 768; half = i & 1; qtile = (i >> 1) & 7;
        int rest = i >> 4; head = rest % 12; seg = rest / 12;
    } else if (bid < 1344) {
        b = 2; int i = bid - 1152; half = i & 1; qtile = (i >> 1) & 7;
        head = i >> 4;
    } else if (bid < 1392) {
        b = 3; int i = bid - 1344; qtile = i & 3; head = i >> 2;
    } else {
        b = 4; int i = bid - 1392; qtile = i & 1; head = i >> 1;
    }
    const int slot = (b < 3) ? b * 2 + half : 3 + b;
    const int r = 1 << b;
    const int w = 1024 << b;
    const int keyoff = (b < 3) ? half * 512 : 0;
    const int ntiles = (b == 4) ? 4 : 8;
    const size_t base = (size_t)seg * w + (head & (r - 1));
    const int q0 = qtile * 128 + wv * 32;
    const size_t kstep = (size_t)r * DM;

    const size_t sq_l = base + (size_t)r * (q0 + lq);
    const u16* qp = qb + sq_l * DM + head * 64 + lh * 8;
    short8 qf[4];
#pragma unroll
    for (int s = 0; s < 4; ++s) qf[s] = *(const short8*)(qp + s * 16);

    const u16* kp = kbuf + (base + (size_t)r * (keyoff + lq)) * DM + head * 64 + lh * 8;
    const int c = tid & 7, pp = tid >> 3;
    const u16* vsrc = vb + (base + (size_t)r * (keyoff + 2 * pp)) * DM + head * 64 + c * 8;

#define VPACK(dstbuf, A8, B8) do {                                          \
    _Pragma("unroll") for (int j = 0; j < 8; ++j) {                         \
        int i_ = (j + c) & 7; int hd_ = c * 8 + i_;                         \
        u32 val_ = (u32)(u16)(A8)[i_] | ((u32)(u16)(B8)[i_] << 16);         \
        int byte_ = hd_ * 128 + ((pp * 4) ^ (i_ << 4));                     \
        *(u32*)&Vt[dstbuf][byte_ >> 1] = val_; } } while (0)

    f32x16 oacc0 = {0.f,0.f,0.f,0.f,0.f,0.f,0.f,0.f,0.f,0.f,0.f,0.f,0.f,0.f,0.f,0.f};
    f32x16 oacc1 = oacc0;
    float mw = -INFINITY, dl = 0.f;

    short8 van = *(const short8*)vsrc;
    short8 vbn = *(const short8*)(vsrc + kstep);
    VPACK(0, van, vbn);
    van = *(const short8*)(vsrc + 64 * kstep);
    vbn = *(const short8*)(vsrc + 65 * kstep);
    short8 kf[8];
#pragma unroll
    for (int s = 0; s < 4; ++s) {
        kf[s]     = *(const short8*)(kp + s * 16);
        kf[4 + s] = *(const short8*)(kp + 32 * kstep + s * 16);
    }
    lds_barrier();

    for (int t = 0; t < ntiles; ++t) {
        const int curb = t & 1;
        f32x16 s0 = {0.f,0.f,0.f,0.f,0.f,0.f,0.f,0.f,0.f,0.f,0.f,0.f,0.f,0.f,0.f,0.f};
        f32x16 s1 = s0;
#pragma unroll
        for (int s = 0; s < 4; ++s)
            s0 = __builtin_amdgcn_mfma_f32_32x32x16_bf16(kf[s], qf[s], s0, 0, 0, 0);
#pragma unroll
        for (int s = 0; s < 4; ++s)
            s1 = __builtin_amdgcn_mfma_f32_32x32x16_bf16(kf[4 + s], qf[s], s1, 0, 0, 0);

        if (t + 1 < ntiles) {
            const u16* kn = kp + (size_t)(t + 1) * 64 * kstep;
#pragma unroll
            for (int s = 0; s < 4; ++s) {
                kf[s]     = *(const short8*)(kn + s * 16);
                kf[4 + s] = *(const short8*)(kn + 32 * kstep + s * 16);
            }
        }

        float pm[16];
#pragma unroll
        for (int i = 0; i < 16; ++i) pm[i] = fmaxf(s0[i], s1[i]);
#pragma unroll
        for (int i = 0; i < 8; ++i) pm[i] = fmaxf(pm[i], pm[i + 8]);
#pragma unroll
        for (int i = 0; i < 4; ++i) pm[i] = fmaxf(pm[i], pm[i + 4]);
        float mloc = fmaxf(fmaxf(pm[0], pm[1]), fmaxf(pm[2], pm[3]));
        if (__any(mloc > mw + 8.f)) {
            float mn = mloc;
#pragma unroll
            for (int o = 1; o < 64; o <<= 1) mn = fmaxf(mn, __shfl_xor(mn, o, 64));
            float al = exp2f(mw - mn);
            mw = mn;
            dl *= al;
#pragma unroll
            for (int i = 0; i < 16; ++i) { oacc0[i] *= al; oacc1[i] *= al; }
        }
        float ds = 0.f;
#pragma unroll
        for (int i = 0; i < 16; ++i) { s0[i] = exp2f(s0[i] - mw); ds += s0[i]; }
#pragma unroll
        for (int i = 0; i < 16; ++i) { s1[i] = exp2f(s1[i] - mw); ds += s1[i]; }
        ds += __shfl_xor(ds, 32, 64);
        dl += ds;

        if (t + 1 < ntiles) VPACK(curb ^ 1, van, vbn);
        if (t + 2 < ntiles) {
            van = *(const short8*)(vsrc + (size_t)(t + 2) * 64 * kstep);
            vbn = *(const short8*)(vsrc + ((size_t)(t + 2) * 64 + 1) * kstep);
        }

#pragma unroll
        for (int kb2 = 0; kb2 < 2; ++kb2) {
            u32 wd[8];
#pragma unroll
            for (int j = 0; j < 8; ++j) {
                float lo = (kb2 == 0) ? s0[2 * j] : s1[2 * j];
                float hi = (kb2 == 0) ? s0[2 * j + 1] : s1[2 * j + 1];
                asm("v_cvt_pk_bf16_f32 %0, %1, %2" : "=v"(wd[j]) : "v"(lo), "v"(hi));
            }
#pragma unroll
            for (int ks2 = 0; ks2 < 2; ++ks2) {
                i32x2 X = __builtin_amdgcn_permlane32_swap(
                    (int)wd[ks2 * 4 + 0], (int)wd[ks2 * 4 + 2], false, false);
                i32x2 Y = __builtin_amdgcn_permlane32_swap(
                    (int)wd[ks2 * 4 + 1], (int)wd[ks2 * 4 + 3], false, false);
                union { u32 u[4]; short8 s; } pk;
                pk.u[0] = (u32)X[0]; pk.u[1] = (u32)Y[0];
                pk.u[2] = (u32)X[1]; pk.u[3] = (u32)Y[1];
                const int tt = kb2 * 2 + ks2;
#pragma unroll
                for (int hg = 0; hg < 2; ++hg) {
                    int row = hg * 32 + lq;
                    int byteoff = row * 128 + ((lh * 16 + tt * 32) ^ ((row & 7) << 4));
                    short8 vf = *(const short8*)&Vt[curb][byteoff >> 1];
                    if (hg == 0)
                        oacc0 = __builtin_amdgcn_mfma_f32_32x32x16_bf16(pk.s, vf, oacc0, 0, 0, 0);
                    else
                        oacc1 = __builtin_amdgcn_mfma_f32_32x32x16_bf16(pk.s, vf, oacc1, 0, 0, 0);
                }
            }
        }
        lds_barrier();
    }

    if (l < 32) dbuf[wv][lq] = dl;
    u16* ob = (slot == 7) ? tp : obuf + (size_t)slot * S_LEN * DM;
    float* lse_b = lse + (size_t)slot * S_LEN * NHEAD;
    if (l < 32) lse_b[sq_l * NHEAD + head] = mw + log2f(dl);
#pragma unroll
    for (int reg = 0; reg < 16; ++reg) {
        int qloc = (reg & 3) + 8 * (reg >> 2) + 4 * lh;
        float invd = 1.f / dbuf[wv][qloc];
        size_t sq = base + (size_t)r * (q0 + qloc);
        u16* orow = ob + sq * DM + head * 64;
        u32 pk2;
        float v0 = oacc0[reg] * invd, v1 = oacc1[reg] * invd;
        asm("v_cvt_pk_bf16_f32 %0, %1, %2" : "=v"(pk2) : "v"(v0), "v"(v1));
        orow[lq]      = (u16)(pk2 & 0xffff);
        orow[32 + lq] = (u16)(pk2 >> 16);
    }
#undef VPACK
}

// ---- LongNet combine over 8 partials (normalized o, weight exp2(lse-mx)).
// Structural coverage: slot b (branch br) valid for (s,head) iff
// (s^head)&(r-1)==0; slot7 iff (s&15)==head.  Invalid slots fully skipped.
__global__ __launch_bounds__(192) void combine_kernel(
    const u16* __restrict__ obuf, const float* __restrict__ lse,
    u16* __restrict__ t)
{
    const int s = blockIdx.x;
    const int tid = threadIdx.x;
    const int c0 = tid * 4, head = c0 >> 6;
    const size_t SD = (size_t)S_LEN * DM;
    const size_t SN = (size_t)S_LEN * NHEAD;
    const int sx = s ^ head;
    bool val[8];
    val[0] = val[1] = true;
    val[2] = val[3] = (sx & 1) == 0;
    val[4] = val[5] = (sx & 3) == 0;
    val[6] = (sx & 7) == 0;
    val[7] = (s & 15) == head;
    float lv[8];
#pragma unroll
    for (int b = 0; b < 8; ++b)
        lv[b] = val[b] ? lse[b * SN + (size_t)s * NHEAD + head] : NEGV;
    float mx = lv[0];
#pragma unroll
    for (int b = 1; b < 8; ++b) mx = fmaxf(mx, lv[b]);
    float wsum = 0.f, o0 = 0.f, o1 = 0.f, o2 = 0.f, o3 = 0.f;
#pragma unroll
    for (int b = 0; b < 8; ++b) {
        if (val[b]) {
            float wb = exp2f(lv[b] - mx);
            wsum += wb;
            const u16* src = (b == 7) ? t : obuf + (size_t)b * SD;
            uint2 u = *(const uint2*)(src + (size_t)s * DM + c0);
            o0 += wb * b2f((u16)(u.x & 0xffff));
            o1 += wb * b2f((u16)(u.x >> 16));
            o2 += wb * b2f((u16)(u.y & 0xffff));
            o3 += wb * b2f((u16)(u.y >> 16));
        }
    }
    float inv = 1.f / wsum;
    u32 lo = (u32)f2b(o0 * inv) | ((u32)f2b(o1 * inv) << 16);
    u32 hi = (u32)f2b(o2 * inv) | ((u32)f2b(o3 * inv) << 16);
    ((uint2*)(t + (size_t)s * DM))[tid] = make_uint2(lo, hi);
}

// ---------------------------------------------------------------- layer-3 cls path
__global__ __launch_bounds__(256) void cls_attn_kernel(
    const u16* __restrict__ qb, const u16* __restrict__ kb,
    const u16* __restrict__ vb, float* __restrict__ cpart,
    float* __restrict__ lsep)
{
    __shared__ float q0[64];
    __shared__ float pbuf[128];
    __shared__ float red[8];
    __shared__ float po[256];
    const int blk = blockIdx.x, tid = threadIdx.x;
    int b, head, chunk;
    if (blk < 96)       { b = 0; head = blk >> 3; chunk = blk & 7; }
    else if (blk < 144) { int i = blk - 96;  b = 1; head = (i >> 3) * 2; chunk = i & 7; }
    else if (blk < 168) { int i = blk - 144; b = 2; head = (i >> 3) * 4; chunk = i & 7; }
    else if (blk < 176) { int i = blk - 168; b = 3; head = (i >> 2) * 8; chunk = i & 3; }
    else                { int i = blk - 176; b = 4; head = 0;            chunk = i; }
    const int r = 1 << b;
    if (tid < 64) q0[tid] = b2f(qb[head * 64 + tid]);  // row 0, pre-scaled log2e/8
    __syncthreads();

    float sc = -1e30f;
    if (tid < 128) {
        const int j = chunk * 128 + tid;
        const u16* kp = kb + (size_t)j * r * DM + head * 64;
        float acc = 0.f;
#pragma unroll
        for (int d8 = 0; d8 < 8; ++d8) {
            short8 kv = *(const short8*)(kp + d8 * 8);
#pragma unroll
            for (int jj = 0; jj < 8; ++jj)
                acc += q0[d8 * 8 + jj] * b2f((u16)kv[jj]);
        }
        sc = acc;
    }
    float mxw = sc;
#pragma unroll
    for (int o = 1; o < 64; o <<= 1) mxw = fmaxf(mxw, __shfl_xor(mxw, o, 64));
    if ((tid & 63) == 0) red[tid >> 6] = mxw;
    __syncthreads();
    const float bm = fmaxf(red[0], red[1]);
    float p = 0.f;
    if (tid < 128) { p = exp2f(sc - bm); pbuf[tid] = p; }
    float sw = p;
#pragma unroll
    for (int o = 1; o < 64; o <<= 1) sw += __shfl_xor(sw, o, 64);
    if ((tid & 63) == 0) red[4 + (tid >> 6)] = sw;
    __syncthreads();
    const float dsum = red[4] + red[5];

    const int hd = tid & 63, ch = tid >> 6;
    const u16* vp = vb + (size_t)(chunk * 128 + ch * 32) * r * DM + head * 64 + hd;
    const size_t vstep = (size_t)r * DM;
    float o = 0.f;
#pragma unroll 8
    for (int j = 0; j < 32; ++j)
        o += pbuf[ch * 32 + j] * b2f(vp[(size_t)j * vstep]);
    po[tid] = o;
    __syncthreads();
    if (tid < 64)
        cpart[(size_t)blk * 64 + tid] =
            (po[tid] + po[tid + 64] + po[tid + 128] + po[tid + 192]) / dsum;
    if (tid == 0) lsep[blk] = bm + log2f(dsum);
}

__global__ __launch_bounds__(64) void cls_combine_kernel(
    const float* __restrict__ cpart, const float* __restrict__ lsep,
    u16* __restrict__ t)
{
    const int head = blockIdx.x, tid = threadIdx.x;
#define FORALL_PARTS(EXPR)                                                    \
    for (int c = 0; c < 8; ++c) { int blk = head * 8 + c; EXPR; }             \
    if (!(head & 1)) for (int c = 0; c < 8; ++c) { int blk = 96 + (head >> 1) * 8 + c; EXPR; } \
    if (!(head & 3)) for (int c = 0; c < 8; ++c) { int blk = 144 + (head >> 2) * 8 + c; EXPR; } \
    if (!(head & 7)) for (int c = 0; c < 4; ++c) { int blk = 168 + (head >> 3) * 4 + c; EXPR; } \
    if (head == 0)  for (int c = 0; c < 2; ++c) { int blk = 176 + c; EXPR; }
    float mx = -1e30f;
    FORALL_PARTS(mx = fmaxf(mx, lsep[blk]))
    float ws = 0.f, ov = 0.f;
    FORALL_PARTS({ float wb = exp2f(lsep[blk] - mx); ws += wb;
                   ov += wb * cpart[(size_t)blk * 64 + tid]; })
    t[head * 64 + tid] = f2b(ov / ws);
#undef FORALL_PARTS
}

// row-0 GEMV, 8 threads per output (width-8 shuffle reduce), 32 outputs/block
__global__ __launch_bounds__(256) void row_gemv_kernel(
    const u16* __restrict__ x, const u16* __restrict__ wT,
    const float* __restrict__ bias, const float* __restrict__ res,
    float* __restrict__ outf, u16* __restrict__ outb, int K, int dogelu)
{
    __shared__ float xs[3072];
    const int tid = threadIdx.x;
    for (int i = tid; i < K; i += 256) xs[i] = b2f(x[i]);
    __syncthreads();
    const int n = blockIdx.x * 32 + (tid >> 3);
    const int kp = tid & 7;
    const u16* wrow = wT + (size_t)n * K;
    float acc = 0.f;
    for (int k = kp * 8; k < K; k += 64) {
        short8 wv = *(const short8*)(wrow + k);
#pragma unroll
        for (int j = 0; j < 8; ++j) acc += xs[k + j] * b2f((u16)wv[j]);
    }
    acc += __shfl_down(acc, 4, 8);
    acc += __shfl_down(acc, 2, 8);
    acc += __shfl_down(acc, 1, 8);
    if (kp == 0) {
        float v = acc + bias[n];
        if (dogelu) v = gelu_tanh(v);
        if (res) v += res[n];
        if (outf) outf[n] = v;
        if (outb) outb[n] = f2b(v);
    }
}

// ---------------------------------------------------- final double-LN, row 0
__global__ __launch_bounds__(256) void final_ln_kernel(
    const float* __restrict__ h,
    const float* __restrict__ g1, const float* __restrict__ b1,
    const float* __restrict__ g2, const float* __restrict__ b2,
    float* __restrict__ out)
{
    __shared__ float sbuf[4];
    const int tid = threadIdx.x;
    float x0 = h[tid], x1 = h[tid + 256], x2 = h[tid + 512];
    float m = block_reduce_sum(x0 + x1 + x2, sbuf) * (1.f / DM);
    float d0 = x0 - m, d1 = x1 - m, d2 = x2 - m;
    float var = block_reduce_sum(d0 * d0 + d1 * d1 + d2 * d2, sbuf) * (1.f / DM);
    float rs = rsqrtf(var + EPS);
    float y0 = d0 * rs * g1[tid]       + b1[tid];
    float y1 = d1 * rs * g1[tid + 256] + b1[tid + 256];
    float y2 = d2 * rs * g1[tid + 512] + b1[tid + 512];
    m = block_reduce_sum(y0 + y1 + y2, sbuf) * (1.f / DM);
    d0 = y0 - m; d1 = y1 - m; d2 = y2 - m;
    var = block_reduce_sum(d0 * d0 + d1 * d1 + d2 * d2, sbuf) * (1.f / DM);
    rs = rsqrtf(var + EPS);
    out[tid]       = d0 * rs * g2[tid]       + b2[tid];
    out[tid + 256] = d1 * rs * g2[tid + 256] + b2[tid + 256];
    out[tid + 512] = d2 * rs * g2[tid + 512] + b2[tid + 512];
}

// ---------------------------------------------------------------- launcher
extern "C" void kernel_launch(void* const* d_in, const int* in_sizes, int n_in,
                              void* d_out, int out_size, void* d_ws, size_t ws_size,
                              hipStream_t stream)
{
    (void)in_sizes; (void)n_in; (void)out_size; (void)ws_size;
    const float* x        = (const float*)d_in[0];
    const float* coords   = (const float*)d_in[1];
    const float* pos_emb  = (const float*)d_in[2];
    const float* cls_tok  = (const float*)d_in[3];
    const float* patch_w  = (const float*)d_in[4];
    const float* patch_b  = (const float*)d_in[5];
    const float* ln1_g    = (const float*)d_in[6];
    const float* ln1_b    = (const float*)d_in[7];
    const float* wq       = (const float*)d_in[8];
    const float* bq       = (const float*)d_in[9];
    const float* wk       = (const float*)d_in[10];
    const float* bk       = (const float*)d_in[11];
    const float* wv       = (const float*)d_in[12];
    const float* bv       = (const float*)d_in[13];
    const float* wo       = (const float*)d_in[14];
    const float* bo       = (const float*)d_in[15];
    const float* ln2_g    = (const float*)d_in[16];
    const float* ln2_b    = (const float*)d_in[17];
    const float* w1       = (const float*)d_in[18];
    const float* b1       = (const float*)d_in[19];
    const float* w2       = (const float*)d_in[20];
    const float* b2       = (const float*)d_in[21];
    const float* enc_g    = (const float*)d_in[22];
    const float* enc_b    = (const float*)d_in[23];
    const float* norm_g   = (const float*)d_in[24];
    const float* norm_b   = (const float*)d_in[25];
    float* out = (float*)d_out;

    const size_t SD = (size_t)S_LEN * DM;
    const size_t DD = (size_t)DM * DM;
    const size_t DF = (size_t)DM * FFND;
    const size_t SN = (size_t)S_LEN * NHEAD;

    char* p = (char*)d_ws;
    float* h   = (float*)p;              p += SD * 4;
    u16* t     = (u16*)p;                p += SD * 2;
    u16* qb    = (u16*)p;                p += SD * 2;
    u16* kb    = (u16*)p;                p += SD * 2;
    u16* vb    = (u16*)p;                p += SD * 2;
    float* lse = (float*)p;              p += 8 * SN * 4;
    u16* obuf  = (u16*)p;                p += 7 * SD * 2;  // slot 7 == t
    u16* ffn   = obuf;                   // aliases obuf (dead during FFN)
    u16* xb    = obuf;                   // aliases obuf (used only pre-layer0)
    u16* pwT   = (u16*)p;                p += (size_t)DIN * DM * 2;
    u16* wTdd  = (u16*)p;                p += 4 * DD * 2;
    u16* w1T   = (u16*)p;                p += DF * 2;
    u16* w2T   = (u16*)p;                p += DF * 2;
    // layer-3 cls partials reuse the (then-idle) lse buffer
    float* cpart = lse;                  // 178*64 floats
    float* lsep  = lse + 178 * 64;       // 178 floats

    cvt_bf16_kernel<<<2048, 256, 0, stream>>>(x, xb, (L_LEN * DIN) / 4);
    transpose_cvt<<<dim3(DM / 64, DIN / 64, 1), 256, 0, stream>>>(
        patch_w, patch_w, patch_w, patch_w, pwT, DIN, DM);
    gemm6464_kernel<<<dim3(DM / 64, 64), 256, 0, stream>>>(
        xb, pwT, patch_b, nullptr, h + DM, nullptr, L_LEN, DM, DIN, 1.f, 0);
    posadd_kernel<<<S_LEN, 256, 0, stream>>>(h, coords, pos_emb, cls_tok);

    for (int l = 0; l < 4; ++l) {
        const size_t lDD = (size_t)l * DD;
        const size_t lDF = (size_t)l * DF;
        prep_weights<<<1728, 256, 0, stream>>>(
            wq + lDD, wk + lDD, wv + lDD, wo + lDD, w1 + lDF, w2 + lDF,
            wTdd, w1T, w2T);

        ln_kernel<<<S_LEN, 192, 0, stream>>>(h, t, ln1_g + l * DM, ln1_b + l * DM);
        qkv_kernel<<<dim3(6, 32, 3), 256, 0, stream>>>(
            t, wTdd, wTdd + DD, wTdd + 2 * DD,
            bq + l * DM, bk + l * DM, bv + l * DM, qb, kb, vb);

        if (l < 3) {
            attn_kernel<<<1416, 256, 0, stream>>>(qb, kb, vb, obuf, t, lse);
            combine_kernel<<<S_LEN, 192, 0, stream>>>(obuf, lse, t);
            gemm6464_kernel<<<dim3(12, 64), 256, 0, stream>>>(
                t, wTdd + 3 * DD, bo + l * DM, h, h, nullptr, S_LEN, DM, DM, 1.f, 0);
            ln_kernel<<<S_LEN, 192, 0, stream>>>(h, t, ln2_g + l * DM, ln2_b + l * DM);
            gemm128_kernel<<<dim3(24, 32), 256, 0, stream>>>(
                t, w1T, b1 + (size_t)l * FFND, nullptr, nullptr, ffn,
                S_LEN, FFND, DM, 1.f, 1);
            gemm6464_kernel<<<dim3(12, 64), 256, 0, stream>>>(
                ffn, w2T, b2 + l * DM, h, h, nullptr, S_LEN, DM, FFND, 1.f, 0);
        } else {
            // Last layer: only the cls row (s=0) is consumed downstream.
            cls_attn_kernel<<<178, 256, 0, stream>>>(qb, kb, vb, cpart, lsep);
            cls_combine_kernel<<<NHEAD, 64, 0, stream>>>(cpart, lsep, t);
            row_gemv_kernel<<<24, 256, 0, stream>>>(
                t, wTdd + 3 * DD, bo + l * DM, h, h, nullptr, DM, 0);
            ln_kernel<<<1, 192, 0, stream>>>(h, t, ln2_g + l * DM, ln2_b + l * DM);
            row_gemv_kernel<<<96, 256, 0, stream>>>(
                t, w1T, b1 + (size_t)l * FFND, nullptr, nullptr, ffn, DM, 1);
            row_gemv_kernel<<<24, 256, 0, stream>>>(
                ffn, w2T, b2 + l * DM, h, h, nullptr, FFND, 0);
        }
    }
    final_ln_kernel<<<1, 256, 0, stream>>>(h, enc_g, enc_b, norm_g, norm_b, out);
}

// Round 16
// 920.831 us; speedup vs baseline: 1.0519x; 1.0107x over previous
//
#include <hip/hip_runtime.h>
#include <hip/hip_bf16.h>
#include <math.h>
#include <stdint.h>

#define S_LEN 4096
#define L_LEN 4095
#define DIN   1536
#define DM    768
#define NHEAD 12
#define HDIM  64
#define FFND  3072
#define NEGV  (-1e9f)
#define EPS   1e-5f

typedef unsigned short u16;
typedef unsigned int   u32;
typedef short short8 __attribute__((ext_vector_type(8)));
typedef float f32x4 __attribute__((ext_vector_type(4)));
typedef float f32x16 __attribute__((ext_vector_type(16)));
typedef int i32x2 __attribute__((ext_vector_type(2)));

// ---------------------------------------------------------------- helpers
__device__ __forceinline__ u16 f2b(float f) {
    union { float f; u32 u; } x; x.f = f;
    u32 r = (x.u + 0x7FFF + ((x.u >> 16) & 1)) >> 16;
    return (u16)r;
}
__device__ __forceinline__ float b2f(u16 v) {
    union { u32 u; float f; } x; x.u = ((u32)v) << 16;
    return x.f;
}
__device__ __forceinline__ float gelu_tanh(float x) {
    float x3 = x * x * x;
    return 0.5f * x * (1.f + tanhf(0.7978845608f * (x + 0.044715f * x3)));
}
__device__ __forceinline__ float block_reduce_sum(float v, float* sbuf) {
#pragma unroll
    for (int o = 32; o > 0; o >>= 1) v += __shfl_down(v, o, 64);
    __syncthreads();
    if ((threadIdx.x & 63) == 0) sbuf[threadIdx.x >> 6] = v;
    __syncthreads();
    return sbuf[0] + sbuf[1] + sbuf[2] + sbuf[3];
}
__device__ __forceinline__ void gload16(const void* g, void* l) {
    __builtin_amdgcn_global_load_lds((const __attribute__((address_space(1))) void*)g,
                                     (__attribute__((address_space(3))) void*)l,
                                     16, 0, 0);
}
// barrier draining only LDS ops; global register prefetches stay in flight
__device__ __forceinline__ void lds_barrier() {
    asm volatile("s_waitcnt lgkmcnt(0)" ::: "memory");
    __builtin_amdgcn_s_barrier();
    __builtin_amdgcn_sched_barrier(0);
}

// ---------------------------------------------------------------- GEMM (bf16 MFMA, B^T layout)
// POS=1: add pos_embed[pos(coords[row])] in the epilogue (patch embed fusion)
template <int BM, int BN, int POS = 0>
__device__ __forceinline__ void gemm_bt(
    const u16* __restrict__ A, const u16* __restrict__ Bt,
    const float* __restrict__ bias, const float* __restrict__ res,
    float* __restrict__ outf, u16* __restrict__ outb,
    int M, int N, int K, float scale, int dogelu, int bx, int by,
    const float* __restrict__ coords = nullptr,
    const float* __restrict__ pe = nullptr)
{
    constexpr int MI = BM / 32;
    constexpr int NI = BN / 32;
    constexpr int AI = BM / 32;
    constexpr int BI = BN / 32;
    __shared__ u16 As[BM * 64];
    __shared__ u16 Bs[BN * 64];
    const int tid = threadIdx.x, wv = tid >> 6, l = tid & 63;
    const int bm = by * BM, bn = bx * BN;
    const int wm = wv >> 1, wn = wv & 1;

    f32x4 acc[MI][NI];
#pragma unroll
    for (int i = 0; i < MI; ++i)
#pragma unroll
        for (int j = 0; j < NI; ++j) acc[i][j] = (f32x4){0.f, 0.f, 0.f, 0.f};

    for (int k0 = 0; k0 < K; k0 += 64) {
#pragma unroll
        for (int i = 0; i < AI; ++i) {
            int row = (wv * AI + i) * 8 + (l >> 3);
            int col = ((l & 7) ^ (row & 7)) * 8;
            int grow = bm + row; if (grow > M - 1) grow = M - 1;
            gload16(A + (size_t)grow * K + k0 + col, &As[(wv * AI + i) * 512]);
        }
#pragma unroll
        for (int i = 0; i < BI; ++i) {
            int row = (wv * BI + i) * 8 + (l >> 3);
            int col = ((l & 7) ^ (row & 7)) * 8;
            gload16(Bt + (size_t)(bn + row) * K + k0 + col, &Bs[(wv * BI + i) * 512]);
        }
        __syncthreads();
#pragma unroll
        for (int kc = 0; kc < 2; ++kc) {
            short8 a[MI], b[NI];
#pragma unroll
            for (int mi = 0; mi < MI; ++mi) {
                int row = wm * (BM / 2) + mi * 16 + (l & 15);
                int off = ((l >> 4) * 16 + kc * 64) ^ ((row & 7) << 4);
                a[mi] = *(const short8*)&As[(row * 128 + off) >> 1];
            }
#pragma unroll
            for (int ni = 0; ni < NI; ++ni) {
                int row = wn * (BN / 2) + ni * 16 + (l & 15);
                int off = ((l >> 4) * 16 + kc * 64) ^ ((row & 7) << 4);
                b[ni] = *(const short8*)&Bs[(row * 128 + off) >> 1];
            }
#pragma unroll
            for (int mi = 0; mi < MI; ++mi)
#pragma unroll
                for (int ni = 0; ni < NI; ++ni)
                    acc[mi][ni] = __builtin_amdgcn_mfma_f32_16x16x32_bf16(
                        a[mi], b[ni], acc[mi][ni], 0, 0, 0);
        }
        __syncthreads();
    }
#pragma unroll
    for (int mi = 0; mi < MI; ++mi) {
#pragma unroll
        for (int rg = 0; rg < 4; ++rg) {
            int row = bm + wm * (BM / 2) + mi * 16 + (l >> 4) * 4 + rg;
            if (row >= M) continue;
            int posidx = 0;
            if constexpr (POS) {
                float c0 = floorf(coords[(size_t)row * 2 + 0] * (1.f / 256.f));
                float c1 = floorf(coords[(size_t)row * 2 + 1] * (1.f / 256.f));
                posidx = (int)(c0 * 128.f + c1) + 1;
            }
#pragma unroll
            for (int ni = 0; ni < NI; ++ni) {
                int col = bn + wn * (BN / 2) + ni * 16 + (l & 15);
                float v = (acc[mi][ni][rg] + bias[col]) * scale;
                if (dogelu) v = gelu_tanh(v);
                if (res) v += res[(size_t)row * N + col];
                if constexpr (POS) v += pe[(size_t)posidx * N + col];
                if (outf) outf[(size_t)row * N + col] = v;
                if (outb) outb[(size_t)row * N + col] = f2b(v);
            }
        }
    }
}

__global__ __launch_bounds__(256) void gemm128_kernel(
    const u16* __restrict__ A, const u16* __restrict__ Bt,
    const float* __restrict__ bias, const float* __restrict__ res,
    float* __restrict__ outf, u16* __restrict__ outb,
    int M, int N, int K, float scale, int dogelu)
{
    gemm_bt<128, 128>(A, Bt, bias, res, outf, outb, M, N, K, scale, dogelu,
                      blockIdx.x, blockIdx.y);
}
__global__ __launch_bounds__(256) void gemm6464_kernel(
    const u16* __restrict__ A, const u16* __restrict__ Bt,
    const float* __restrict__ bias, const float* __restrict__ res,
    float* __restrict__ outf, u16* __restrict__ outb,
    int M, int N, int K, float scale, int dogelu)
{
    gemm_bt<64, 64>(A, Bt, bias, res, outf, outb, M, N, K, scale, dogelu,
                    blockIdx.x, blockIdx.y);
}
// patch embed GEMM with fused pos-embed add (rows 1..4095 of h)
__global__ __launch_bounds__(256) void gemm_patch_kernel(
    const u16* __restrict__ A, const u16* __restrict__ Bt,
    const float* __restrict__ bias, const float* __restrict__ coords,
    const float* __restrict__ pe, float* __restrict__ outf,
    int M, int N, int K)
{
    gemm_bt<64, 64, 1>(A, Bt, bias, nullptr, outf, nullptr, M, N, K, 1.f, 0,
                       blockIdx.x, blockIdx.y, coords, pe);
}
__global__ __launch_bounds__(256) void qkv_kernel(
    const u16* __restrict__ t,
    const u16* __restrict__ wqT, const u16* __restrict__ wkT, const u16* __restrict__ wvT,
    const float* __restrict__ bq, const float* __restrict__ bk, const float* __restrict__ bv,
    u16* __restrict__ q, u16* __restrict__ k, u16* __restrict__ v, int zbase)
{
    int z = blockIdx.z + zbase;
    const u16* B = (z == 0) ? wqT : (z == 1) ? wkT : wvT;
    const float* bias = (z == 0) ? bq : (z == 1) ? bk : bv;
    u16* C = (z == 0) ? q : (z == 1) ? k : v;
    // Q additionally scaled by HD^-0.5 * log2(e) so softmax can use exp2
    float scale = (z == 0) ? 0.125f * 1.4426950408889634f : 1.0f;
    gemm_bt<128, 128>(t, B, bias, nullptr, nullptr, C, S_LEN, DM, DM, scale, 0,
                      blockIdx.x, blockIdx.y);
}

// ---------------------------------------------------------- transpose+convert
__global__ __launch_bounds__(256) void transpose_cvt(
    const float* __restrict__ s0, const float* __restrict__ s1,
    const float* __restrict__ s2, const float* __restrict__ s3,
    u16* __restrict__ dst, int K, int N)
{
    int z = blockIdx.z;
    const float* src = (z == 0) ? s0 : (z == 1) ? s1 : (z == 2) ? s2 : s3;
    u16* d = dst + (size_t)z * K * N;
    __shared__ float tile[64][65];
    const int t = threadIdx.x;
    const int tk = blockIdx.y * 64, tn = blockIdx.x * 64;
    const int r0 = t >> 4, c0 = (t & 15) * 4;
#pragma unroll
    for (int i = 0; i < 4; ++i) {
        const float* sp = &src[(size_t)(tk + r0 + i * 16) * N + tn + c0];
        tile[r0 + i * 16][c0 + 0] = sp[0];
        tile[r0 + i * 16][c0 + 1] = sp[1];
        tile[r0 + i * 16][c0 + 2] = sp[2];
        tile[r0 + i * 16][c0 + 3] = sp[3];
    }
    __syncthreads();
#pragma unroll
    for (int i = 0; i < 4; ++i) {
        int nr = r0 + i * 16;
        u32 lo = (u32)f2b(tile[c0 + 0][nr]) | ((u32)f2b(tile[c0 + 1][nr]) << 16);
        u32 hi = (u32)f2b(tile[c0 + 2][nr]) | ((u32)f2b(tile[c0 + 3][nr]) << 16);
        *(uint2*)&d[(size_t)(tn + nr) * K + tk + c0] = make_uint2(lo, hi);
    }
}

// merged per-layer weight transpose
__global__ __launch_bounds__(256) void prep_weights(
    const float* __restrict__ wq, const float* __restrict__ wk,
    const float* __restrict__ wv, const float* __restrict__ wo,
    const float* __restrict__ w1, const float* __restrict__ w2,
    u16* __restrict__ wTdd, u16* __restrict__ w1T, u16* __restrict__ w2T)
{
    __shared__ float tile[64][65];
    const int id = blockIdx.x;
    const float* src; u16* dst; int K, N, tk64, tn64;
    if (id < 576) {
        int z = id / 144, rm = id % 144;
        src = (z == 0) ? wq : (z == 1) ? wk : (z == 2) ? wv : wo;
        dst = wTdd + (size_t)z * DM * DM;
        K = DM; N = DM; tk64 = rm / 12; tn64 = rm % 12;
    } else if (id < 1152) {
        int rm = id - 576;
        src = w1; dst = w1T; K = DM; N = FFND; tk64 = rm / 48; tn64 = rm % 48;
    } else {
        int rm = id - 1152;
        src = w2; dst = w2T; K = FFND; N = DM; tk64 = rm / 12; tn64 = rm % 12;
    }
    const int t = threadIdx.x;
    const int tk = tk64 * 64, tn = tn64 * 64;
    const int r0 = t >> 4, c0 = (t & 15) * 4;
#pragma unroll
    for (int i = 0; i < 4; ++i) {
        const float* sp = &src[(size_t)(tk + r0 + i * 16) * N + tn + c0];
        tile[r0 + i * 16][c0 + 0] = sp[0];
        tile[r0 + i * 16][c0 + 1] = sp[1];
        tile[r0 + i * 16][c0 + 2] = sp[2];
        tile[r0 + i * 16][c0 + 3] = sp[3];
    }
    __syncthreads();
#pragma unroll
    for (int i = 0; i < 4; ++i) {
        int nr = r0 + i * 16;
        u32 lo = (u32)f2b(tile[c0 + 0][nr]) | ((u32)f2b(tile[c0 + 1][nr]) << 16);
        u32 hi = (u32)f2b(tile[c0 + 2][nr]) | ((u32)f2b(tile[c0 + 3][nr]) << 16);
        *(uint2*)&dst[(size_t)(tn + nr) * K + tk + c0] = make_uint2(lo, hi);
    }
}

__global__ __launch_bounds__(256) void cvt_bf16_kernel(
    const float* __restrict__ x, u16* __restrict__ xb, int n4)
{
    int stride = gridDim.x * 256;
    for (int i = blockIdx.x * 256 + threadIdx.x; i < n4; i += stride) {
        float4 v = ((const float4*)x)[i];
        u32 lo = (u32)f2b(v.x) | ((u32)f2b(v.y) << 16);
        u32 hi = (u32)f2b(v.z) | ((u32)f2b(v.w) << 16);
        ((uint2*)xb)[i] = make_uint2(lo, hi);
    }
}

// ---------------------------------------------------------------- LayerNorm
__global__ __launch_bounds__(192) void ln_kernel(
    const float* __restrict__ in, u16* __restrict__ out,
    const float* __restrict__ g, const float* __restrict__ b)
{
    __shared__ float sA[3], sB[3];
    const int s = blockIdx.x, tid = threadIdx.x;
    float4 x = ((const float4*)(in + (size_t)s * DM))[tid];
    float sum = x.x + x.y + x.z + x.w;
#pragma unroll
    for (int o = 32; o > 0; o >>= 1) sum += __shfl_down(sum, o, 64);
    if ((tid & 63) == 0) sA[tid >> 6] = sum;
    __syncthreads();
    float m = (sA[0] + sA[1] + sA[2]) * (1.f / DM);
    float dx = x.x - m, dy = x.y - m, dz = x.z - m, dw = x.w - m;
    float vs = dx * dx + dy * dy + dz * dz + dw * dw;
#pragma unroll
    for (int o = 32; o > 0; o >>= 1) vs += __shfl_down(vs, o, 64);
    if ((tid & 63) == 0) sB[tid >> 6] = vs;
    __syncthreads();
    float rs = rsqrtf((sB[0] + sB[1] + sB[2]) * (1.f / DM) + EPS);
    float4 gv = ((const float4*)g)[tid];
    float4 bv = ((const float4*)b)[tid];
    u32 lo = (u32)f2b(dx * rs * gv.x + bv.x) | ((u32)f2b(dy * rs * gv.y + bv.y) << 16);
    u32 hi = (u32)f2b(dz * rs * gv.z + bv.z) | ((u32)f2b(dw * rs * gv.w + bv.w) << 16);
    ((uint2*)(out + (size_t)s * DM))[tid] = make_uint2(lo, hi);
}

// ------------------------------------------------- cls row: h[0] = cls + pe[0]
__global__ __launch_bounds__(256) void posadd_cls_kernel(
    float* __restrict__ h, const float* __restrict__ pe,
    const float* __restrict__ cls)
{
    const int tid = threadIdx.x;
    for (int c = tid; c < DM; c += 256) h[c] = cls[c] + pe[c];
}

// ---------------------------------------------------------------- attention (layers 0..2)
// Swapped-QK flash attention, pipelined, KEY-SPLIT into 8 partials:
//   slots 0/1 = b0 key-halves, 2/3 = b1, 4/5 = b2, 6 = b3, 7 = b4.
// Max-tracking with defer-THR=8 (R11-proven variant).  XCD-aware block
// swizzle: grid 1416 = 8*177 -> blocks sharing a (head,seg) K/V region
// co-reside on one XCD's L2.
__global__ __launch_bounds__(256, 3) void attn_kernel(
    const u16* __restrict__ qb, const u16* __restrict__ kbuf, const u16* __restrict__ vb,
    u16* __restrict__ obuf, u16* __restrict__ tp, float* __restrict__ lse)
{
    __shared__ u16 Vt[2][64 * 64];   // [buf][hd][key] swizzled
    __shared__ float dbuf[4][32];

    const int tid = threadIdx.x, wv = tid >> 6, l = tid & 63;
    const int lq = l & 31, lh = l >> 5;
    const int bid = (blockIdx.x & 7) * 177 + (blockIdx.x >> 3);
    int b, half = 0, qtile, head, seg = 0;
    if (bid < 768) {
        b = 0; int i = bid; half = i & 1; qtile = (i >> 1) & 7;
        int rest = i >> 4; head = rest % 12; seg = rest / 12;
    } else if (bid < 1152) {
        b = 1; int i = bid - 768; half = i & 1; qtile = (i >> 1) & 7;
        int rest = i >> 4; head = rest % 12; seg = rest / 12;
    } else if (bid < 1344) {
        b = 2; int i = bid - 1152; half = i & 1; qtile = (i >> 1) & 7;
        head = i >> 4;
    } else if (bid < 1392) {
        b = 3; int i = bid - 1344; qtile = i & 3; head = i >> 2;
    } else {
        b = 4; int i = bid - 1392; qtile = i & 1; head = i >> 1;
    }
    const int slot = (b < 3) ? b * 2 + half : 3 + b;
    const int r = 1 << b;
    const int w = 1024 << b;
    const int keyoff = (b < 3) ? half * 512 : 0;
    const int ntiles = (b == 4) ? 4 : 8;
    const size_t base = (size_t)seg * w + (head & (r - 1));
    const int q0 = qtile * 128 + wv * 32;
    const size_t kstep = (size_t)r * DM;

    const size_t sq_l = base + (size_t)r * (q0 + lq);
    const u16* qp = qb + sq_l * DM + head * 64 + lh * 8;
    short8 qf[4];
#pragma unroll
    for (int s = 0; s < 4; ++s) qf[s] = *(const short8*)(qp + s * 16);

    const u16* kp = kbuf + (base + (size_t)r * (keyoff + lq)) * DM + head * 64 + lh * 8;
    const int c = tid & 7, pp = tid >> 3;
    const u16* vsrc = vb + (base + (size_t)r * (keyoff + 2 * pp)) * DM + head * 64 + c * 8;

#define VPACK(dstbuf, A8, B8) do {                                          \
    _Pragma("unroll") for (int j = 0; j < 8; ++j) {                         \
        int i_ = (j + c) & 7; int hd_ = c * 8 + i_;                         \
        u32 val_ = (u32)(u16)(A8)[i_] | ((u32)(u16)(B8)[i_] << 16);         \
        int byte_ = hd_ * 128 + ((pp * 4) ^ (i_ << 4));                     \
        *(u32*)&Vt[dstbuf][byte_ >> 1] = val_; } } while (0)

    f32x16 oacc0 = {0.f,0.f,0.f,0.f,0.f,0.f,0.f,0.f,0.f,0.f,0.f,0.f,0.f,0.f,0.f,0.f};
    f32x16 oacc1 = oacc0;
    float mw = -INFINITY, dl = 0.f;

    short8 van = *(const short8*)vsrc;
    short8 vbn = *(const short8*)(vsrc + kstep);
    VPACK(0, van, vbn);
    van = *(const short8*)(vsrc + 64 * kstep);
    vbn = *(const short8*)(vsrc + 65 * kstep);
    short8 kf[8];
#pragma unroll
    for (int s = 0; s < 4; ++s) {
        kf[s]     = *(const short8*)(kp + s * 16);
        kf[4 + s] = *(const short8*)(kp + 32 * kstep + s * 16);
    }
    lds_barrier();

    for (int t = 0; t < ntiles; ++t) {
        const int curb = t & 1;
        f32x16 s0 = {0.f,0.f,0.f,0.f,0.f,0.f,0.f,0.f,0.f,0.f,0.f,0.f,0.f,0.f,0.f,0.f};
        f32x16 s1 = s0;
#pragma unroll
        for (int s = 0; s < 4; ++s)
            s0 = __builtin_amdgcn_mfma_f32_32x32x16_bf16(kf[s], qf[s], s0, 0, 0, 0);
#pragma unroll
        for (int s = 0; s < 4; ++s)
            s1 = __builtin_amdgcn_mfma_f32_32x32x16_bf16(kf[4 + s], qf[s], s1, 0, 0, 0);

        if (t + 1 < ntiles) {
            const u16* kn = kp + (size_t)(t + 1) * 64 * kstep;
#pragma unroll
            for (int s = 0; s < 4; ++s) {
                kf[s]     = *(const short8*)(kn + s * 16);
                kf[4 + s] = *(const short8*)(kn + 32 * kstep + s * 16);
            }
        }

        float pm[16];
#pragma unroll
        for (int i = 0; i < 16; ++i) pm[i] = fmaxf(s0[i], s1[i]);
#pragma unroll
        for (int i = 0; i < 8; ++i) pm[i] = fmaxf(pm[i], pm[i + 8]);
#pragma unroll
        for (int i = 0; i < 4; ++i) pm[i] = fmaxf(pm[i], pm[i + 4]);
        float mloc = fmaxf(fmaxf(pm[0], pm[1]), fmaxf(pm[2], pm[3]));
        if (__any(mloc > mw + 8.f)) {
            float mn = mloc;
#pragma unroll
            for (int o = 1; o < 64; o <<= 1) mn = fmaxf(mn, __shfl_xor(mn, o, 64));
            float al = exp2f(mw - mn);
            mw = mn;
            dl *= al;
#pragma unroll
            for (int i = 0; i < 16; ++i) { oacc0[i] *= al; oacc1[i] *= al; }
        }
        float ds = 0.f;
#pragma unroll
        for (int i = 0; i < 16; ++i) { s0[i] = exp2f(s0[i] - mw); ds += s0[i]; }
#pragma unroll
        for (int i = 0; i < 16; ++i) { s1[i] = exp2f(s1[i] - mw); ds += s1[i]; }
        ds += __shfl_xor(ds, 32, 64);
        dl += ds;

        if (t + 1 < ntiles) VPACK(curb ^ 1, van, vbn);
        if (t + 2 < ntiles) {
            van = *(const short8*)(vsrc + (size_t)(t + 2) * 64 * kstep);
            vbn = *(const short8*)(vsrc + ((size_t)(t + 2) * 64 + 1) * kstep);
        }

#pragma unroll
        for (int kb2 = 0; kb2 < 2; ++kb2) {
            u32 wd[8];
#pragma unroll
            for (int j = 0; j < 8; ++j) {
                float lo = (kb2 == 0) ? s0[2 * j] : s1[2 * j];
                float hi = (kb2 == 0) ? s0[2 * j + 1] : s1[2 * j + 1];
                asm("v_cvt_pk_bf16_f32 %0, %1, %2" : "=v"(wd[j]) : "v"(lo), "v"(hi));
            }
#pragma unroll
            for (int ks2 = 0; ks2 < 2; ++ks2) {
                i32x2 X = __builtin_amdgcn_permlane32_swap(
                    (int)wd[ks2 * 4 + 0], (int)wd[ks2 * 4 + 2], false, false);
                i32x2 Y = __builtin_amdgcn_permlane32_swap(
                    (int)wd[ks2 * 4 + 1], (int)wd[ks2 * 4 + 3], false, false);
                union { u32 u[4]; short8 s; } pk;
                pk.u[0] = (u32)X[0]; pk.u[1] = (u32)Y[0];
                pk.u[2] = (u32)X[1]; pk.u[3] = (u32)Y[1];
                const int tt = kb2 * 2 + ks2;
#pragma unroll
                for (int hg = 0; hg < 2; ++hg) {
                    int row = hg * 32 + lq;
                    int byteoff = row * 128 + ((lh * 16 + tt * 32) ^ ((row & 7) << 4));
                    short8 vf = *(const short8*)&Vt[curb][byteoff >> 1];
                    if (hg == 0)
                        oacc0 = __builtin_amdgcn_mfma_f32_32x32x16_bf16(pk.s, vf, oacc0, 0, 0, 0);
                    else
                        oacc1 = __builtin_amdgcn_mfma_f32_32x32x16_bf16(pk.s, vf, oacc1, 0, 0, 0);
                }
            }
        }
        lds_barrier();
    }

    if (l < 32) dbuf[wv][lq] = dl;
    u16* ob = (slot == 7) ? tp : obuf + (size_t)slot * S_LEN * DM;
    float* lse_b = lse + (size_t)slot * S_LEN * NHEAD;
    if (l < 32) lse_b[sq_l * NHEAD + head] = mw + log2f(dl);
#pragma unroll
    for (int reg = 0; reg < 16; ++reg) {
        int qloc = (reg & 3) + 8 * (reg >> 2) + 4 * lh;
        float invd = 1.f / dbuf[wv][qloc];
        size_t sq = base + (size_t)r * (q0 + qloc);
        u16* orow = ob + sq * DM + head * 64;
        u32 pk2;
        float v0 = oacc0[reg] * invd, v1 = oacc1[reg] * invd;
        asm("v_cvt_pk_bf16_f32 %0, %1, %2" : "=v"(pk2) : "v"(v0), "v"(v1));
        orow[lq]      = (u16)(pk2 & 0xffff);
        orow[32 + lq] = (u16)(pk2 >> 16);
    }
#undef VPACK
}

// ---- LongNet combine over 8 partials (normalized o, weight exp2(lse-mx)).
// Structural coverage: slot b valid for (s,head) iff (s^head)&(r-1)==0;
// slot7 iff (s&15)==head.  Invalid slots fully skipped.
__global__ __launch_bounds__(192) void combine_kernel(
    const u16* __restrict__ obuf, const float* __restrict__ lse,
    u16* __restrict__ t)
{
    const int s = blockIdx.x;
    const int tid = threadIdx.x;
    const int c0 = tid * 4, head = c0 >> 6;
    const size_t SD = (size_t)S_LEN * DM;
    const size_t SN = (size_t)S_LEN * NHEAD;
    const int sx = s ^ head;
    bool val[8];
    val[0] = val[1] = true;
    val[2] = val[3] = (sx & 1) == 0;
    val[4] = val[5] = (sx & 3) == 0;
    val[6] = (sx & 7) == 0;
    val[7] = (s & 15) == head;
    float lv[8];
#pragma unroll
    for (int b = 0; b < 8; ++b)
        lv[b] = val[b] ? lse[b * SN + (size_t)s * NHEAD + head] : NEGV;
    float mx = lv[0];
#pragma unroll
    for (int b = 1; b < 8; ++b) mx = fmaxf(mx, lv[b]);
    float wsum = 0.f, o0 = 0.f, o1 = 0.f, o2 = 0.f, o3 = 0.f;
#pragma unroll
    for (int b = 0; b < 8; ++b) {
        if (val[b]) {
            float wb = exp2f(lv[b] - mx);
            wsum += wb;
            const u16* src = (b == 7) ? t : obuf + (size_t)b * SD;
            uint2 u = *(const uint2*)(src + (size_t)s * DM + c0);
            o0 += wb * b2f((u16)(u.x & 0xffff));
            o1 += wb * b2f((u16)(u.x >> 16));
            o2 += wb * b2f((u16)(u.y & 0xffff));
            o3 += wb * b2f((u16)(u.y >> 16));
        }
    }
    float inv = 1.f / wsum;
    u32 lo = (u32)f2b(o0 * inv) | ((u32)f2b(o1 * inv) << 16);
    u32 hi = (u32)f2b(o2 * inv) | ((u32)f2b(o3 * inv) << 16);
    ((uint2*)(t + (size_t)s * DM))[tid] = make_uint2(lo, hi);
}

// ---------------------------------------------------------------- layer-3 cls path
__global__ __launch_bounds__(256) void cls_attn_kernel(
    const u16* __restrict__ qb, const u16* __restrict__ kb,
    const u16* __restrict__ vb, float* __restrict__ cpart,
    float* __restrict__ lsep)
{
    __shared__ float q0[64];
    __shared__ float pbuf[128];
    __shared__ float red[8];
    __shared__ float po[256];
    const int blk = blockIdx.x, tid = threadIdx.x;
    int b, head, chunk;
    if (blk < 96)       { b = 0; head = blk >> 3; chunk = blk & 7; }
    else if (blk < 144) { int i = blk - 96;  b = 1; head = (i >> 3) * 2; chunk = i & 7; }
    else if (blk < 168) { int i = blk - 144; b = 2; head = (i >> 3) * 4; chunk = i & 7; }
    else if (blk < 176) { int i = blk - 168; b = 3; head = (i >> 2) * 8; chunk = i & 3; }
    else                { int i = blk - 176; b = 4; head = 0;            chunk = i; }
    const int r = 1 << b;
    if (tid < 64) q0[tid] = b2f(qb[head * 64 + tid]);  // row 0, pre-scaled log2e/8
    __syncthreads();

    float sc = -1e30f;
    if (tid < 128) {
        const int j = chunk * 128 + tid;
        const u16* kp = kb + (size_t)j * r * DM + head * 64;
        float acc = 0.f;
#pragma unroll
        for (int d8 = 0; d8 < 8; ++d8) {
            short8 kv = *(const short8*)(kp + d8 * 8);
#pragma unroll
            for (int jj = 0; jj < 8; ++jj)
                acc += q0[d8 * 8 + jj] * b2f((u16)kv[jj]);
        }
        sc = acc;
    }
    float mxw = sc;
#pragma unroll
    for (int o = 1; o < 64; o <<= 1) mxw = fmaxf(mxw, __shfl_xor(mxw, o, 64));
    if ((tid & 63) == 0) red[tid >> 6] = mxw;
    __syncthreads();
    const float bm = fmaxf(red[0], red[1]);
    float p = 0.f;
    if (tid < 128) { p = exp2f(sc - bm); pbuf[tid] = p; }
    float sw = p;
#pragma unroll
    for (int o = 1; o < 64; o <<= 1) sw += __shfl_xor(sw, o, 64);
    if ((tid & 63) == 0) red[4 + (tid >> 6)] = sw;
    __syncthreads();
    const float dsum = red[4] + red[5];

    const int hd = tid & 63, ch = tid >> 6;
    const u16* vp = vb + (size_t)(chunk * 128 + ch * 32) * r * DM + head * 64 + hd;
    const size_t vstep = (size_t)r * DM;
    float o = 0.f;
#pragma unroll 8
    for (int j = 0; j < 32; ++j)
        o += pbuf[ch * 32 + j] * b2f(vp[(size_t)j * vstep]);
    po[tid] = o;
    __syncthreads();
    if (tid < 64)
        cpart[(size_t)blk * 64 + tid] =
            (po[tid] + po[tid + 64] + po[tid + 128] + po[tid + 192]) / dsum;
    if (tid == 0) lsep[blk] = bm + log2f(dsum);
}

__global__ __launch_bounds__(64) void cls_combine_kernel(
    const float* __restrict__ cpart, const float* __restrict__ lsep,
    u16* __restrict__ t)
{
    const int head = blockIdx.x, tid = threadIdx.x;
#define FORALL_PARTS(EXPR)                                                    \
    for (int c = 0; c < 8; ++c) { int blk = head * 8 + c; EXPR; }             \
    if (!(head & 1)) for (int c = 0; c < 8; ++c) { int blk = 96 + (head >> 1) * 8 + c; EXPR; } \
    if (!(head & 3)) for (int c = 0; c < 8; ++c) { int blk = 144 + (head >> 2) * 8 + c; EXPR; } \
    if (!(head & 7)) for (int c = 0; c < 4; ++c) { int blk = 168 + (head >> 3) * 4 + c; EXPR; } \
    if (head == 0)  for (int c = 0; c < 2; ++c) { int blk = 176 + c; EXPR; }
    float mx = -1e30f;
    FORALL_PARTS(mx = fmaxf(mx, lsep[blk]))
    float ws = 0.f, ov = 0.f;
    FORALL_PARTS({ float wb = exp2f(lsep[blk] - mx); ws += wb;
                   ov += wb * cpart[(size_t)blk * 64 + tid]; })
    t[head * 64 + tid] = f2b(ov / ws);
#undef FORALL_PARTS
}

// row-0 GEMV, 8 threads per output (width-8 shuffle reduce), 32 outputs/block
__global__ __launch_bounds__(256) void row_gemv_kernel(
    const u16* __restrict__ x, const u16* __restrict__ wT,
    const float* __restrict__ bias, const float* __restrict__ res,
    float* __restrict__ outf, u16* __restrict__ outb, int K, int dogelu,
    float scale)
{
    __shared__ float xs[3072];
    const int tid = threadIdx.x;
    for (int i = tid; i < K; i += 256) xs[i] = b2f(x[i]);
    __syncthreads();
    const int n = blockIdx.x * 32 + (tid >> 3);
    const int kp = tid & 7;
    const u16* wrow = wT + (size_t)n * K;
    float acc = 0.f;
    for (int k = kp * 8; k < K; k += 64) {
        short8 wv = *(const short8*)(wrow + k);
#pragma unroll
        for (int j = 0; j < 8; ++j) acc += xs[k + j] * b2f((u16)wv[j]);
    }
    acc += __shfl_down(acc, 4, 8);
    acc += __shfl_down(acc, 2, 8);
    acc += __shfl_down(acc, 1, 8);
    if (kp == 0) {
        float v = (acc + bias[n]) * scale;
        if (dogelu) v = gelu_tanh(v);
        if (res) v += res[n];
        if (outf) outf[n] = v;
        if (outb) outb[n] = f2b(v);
    }
}

// ---------------------------------------------------- final double-LN, row 0
__global__ __launch_bounds__(256) void final_ln_kernel(
    const float* __restrict__ h,
    const float* __restrict__ g1, const float* __restrict__ b1,
    const float* __restrict__ g2, const float* __restrict__ b2,
    float* __restrict__ out)
{
    __shared__ float sbuf[4];
    const int tid = threadIdx.x;
    float x0 = h[tid], x1 = h[tid + 256], x2 = h[tid + 512];
    float m = block_reduce_sum(x0 + x1 + x2, sbuf) * (1.f / DM);
    float d0 = x0 - m, d1 = x1 - m, d2 = x2 - m;
    float var = block_reduce_sum(d0 * d0 + d1 * d1 + d2 * d2, sbuf) * (1.f / DM);
    float rs = rsqrtf(var + EPS);
    float y0 = d0 * rs * g1[tid]       + b1[tid];
    float y1 = d1 * rs * g1[tid + 256] + b1[tid + 256];
    float y2 = d2 * rs * g1[tid + 512] + b1[tid + 512];
    m = block_reduce_sum(y0 + y1 + y2, sbuf) * (1.f / DM);
    d0 = y0 - m; d1 = y1 - m; d2 = y2 - m;
    var = block_reduce_sum(d0 * d0 + d1 * d1 + d2 * d2, sbuf) * (1.f / DM);
    rs = rsqrtf(var + EPS);
    out[tid]       = d0 * rs * g2[tid]       + b2[tid];
    out[tid + 256] = d1 * rs * g2[tid + 256] + b2[tid + 256];
    out[tid + 512] = d2 * rs * g2[tid + 512] + b2[tid + 512];
}

// ---------------------------------------------------------------- launcher
extern "C" void kernel_launch(void* const* d_in, const int* in_sizes, int n_in,
                              void* d_out, int out_size, void* d_ws, size_t ws_size,
                              hipStream_t stream)
{
    (void)in_sizes; (void)n_in; (void)out_size; (void)ws_size;
    const float* x        = (const float*)d_in[0];
    const float* coords   = (const float*)d_in[1];
    const float* pos_emb  = (const float*)d_in[2];
    const float* cls_tok  = (const float*)d_in[3];
    const float* patch_w  = (const float*)d_in[4];
    const float* patch_b  = (const float*)d_in[5];
    const float* ln1_g    = (const float*)d_in[6];
    const float* ln1_b    = (const float*)d_in[7];
    const float* wq       = (const float*)d_in[8];
    const float* bq       = (const float*)d_in[9];
    const float* wk       = (const float*)d_in[10];
    const float* bk       = (const float*)d_in[11];
    const float* wv       = (const float*)d_in[12];
    const float* bv       = (const float*)d_in[13];
    const float* wo       = (const float*)d_in[14];
    const float* bo       = (const float*)d_in[15];
    const float* ln2_g    = (const float*)d_in[16];
    const float* ln2_b    = (const float*)d_in[17];
    const float* w1       = (const float*)d_in[18];
    const float* b1       = (const float*)d_in[19];
    const float* w2       = (const float*)d_in[20];
    const float* b2       = (const float*)d_in[21];
    const float* enc_g    = (const float*)d_in[22];
    const float* enc_b    = (const float*)d_in[23];
    const float* norm_g   = (const float*)d_in[24];
    const float* norm_b   = (const float*)d_in[25];
    float* out = (float*)d_out;

    const size_t SD = (size_t)S_LEN * DM;
    const size_t DD = (size_t)DM * DM;
    const size_t DF = (size_t)DM * FFND;
    const size_t SN = (size_t)S_LEN * NHEAD;

    char* p = (char*)d_ws;
    float* h   = (float*)p;              p += SD * 4;
    u16* t     = (u16*)p;                p += SD * 2;
    u16* qb    = (u16*)p;                p += SD * 2;
    u16* kb    = (u16*)p;                p += SD * 2;
    u16* vb    = (u16*)p;                p += SD * 2;
    float* lse = (float*)p;              p += 8 * SN * 4;
    u16* obuf  = (u16*)p;                p += 7 * SD * 2;  // slot 7 == t
    u16* ffn   = obuf;                   // aliases obuf (dead during FFN)
    u16* xb    = obuf;                   // aliases obuf (used only pre-layer0)
    u16* pwT   = (u16*)p;                p += (size_t)DIN * DM * 2;
    u16* wTdd  = (u16*)p;                p += 4 * DD * 2;
    u16* w1T   = (u16*)p;                p += DF * 2;
    u16* w2T   = (u16*)p;                p += DF * 2;
    // layer-3 cls partials reuse the (then-idle) lse buffer
    float* cpart = lse;                  // 178*64 floats
    float* lsep  = lse + 178 * 64;       // 178 floats

    cvt_bf16_kernel<<<2048, 256, 0, stream>>>(x, xb, (L_LEN * DIN) / 4);
    transpose_cvt<<<dim3(DM / 64, DIN / 64, 1), 256, 0, stream>>>(
        patch_w, patch_w, patch_w, patch_w, pwT, DIN, DM);
    // patch embed with fused pos-embed add (rows 1..4095)
    gemm_patch_kernel<<<dim3(DM / 64, 64), 256, 0, stream>>>(
        xb, pwT, patch_b, coords, pos_emb, h + DM, L_LEN, DM, DIN);
    posadd_cls_kernel<<<1, 256, 0, stream>>>(h, pos_emb, cls_tok);

    for (int l = 0; l < 4; ++l) {
        const size_t lDD = (size_t)l * DD;
        const size_t lDF = (size_t)l * DF;
        prep_weights<<<1728, 256, 0, stream>>>(
            wq + lDD, wk + lDD, wv + lDD, wo + lDD, w1 + lDF, w2 + lDF,
            wTdd, w1T, w2T);

        ln_kernel<<<S_LEN, 192, 0, stream>>>(h, t, ln1_g + l * DM, ln1_b + l * DM);

        if (l < 3) {
            qkv_kernel<<<dim3(6, 32, 3), 256, 0, stream>>>(
                t, wTdd, wTdd + DD, wTdd + 2 * DD,
                bq + l * DM, bk + l * DM, bv + l * DM, qb, kb, vb, 0);
            attn_kernel<<<1416, 256, 0, stream>>>(qb, kb, vb, obuf, t, lse);
            combine_kernel<<<S_LEN, 192, 0, stream>>>(obuf, lse, t);
            gemm6464_kernel<<<dim3(12, 64), 256, 0, stream>>>(
                t, wTdd + 3 * DD, bo + l * DM, h, h, nullptr, S_LEN, DM, DM, 1.f, 0);
            ln_kernel<<<S_LEN, 192, 0, stream>>>(h, t, ln2_g + l * DM, ln2_b + l * DM);
            gemm128_kernel<<<dim3(24, 32), 256, 0, stream>>>(
                t, w1T, b1 + (size_t)l * FFND, nullptr, nullptr, ffn,
                S_LEN, FFND, DM, 1.f, 1);
            gemm6464_kernel<<<dim3(12, 64), 256, 0, stream>>>(
                ffn, w2T, b2 + l * DM, h, h, nullptr, S_LEN, DM, FFND, 1.f, 0);
        } else {
            // Last layer: only the cls row (s=0) is consumed downstream.
            // K,V needed in full (branch 0 attends over all keys); Q only row 0.
            qkv_kernel<<<dim3(6, 32, 2), 256, 0, stream>>>(
                t, wTdd, wTdd + DD, wTdd + 2 * DD,
                bq + l * DM, bk + l * DM, bv + l * DM, qb, kb, vb, 1);
            row_gemv_kernel<<<24, 256, 0, stream>>>(
                t, wTdd, bq + l * DM, nullptr, nullptr, qb, DM, 0,
                0.125f * 1.4426950408889634f);
            cls_attn_kernel<<<178, 256, 0, stream>>>(qb, kb, vb, cpart, lsep);
            cls_combine_kernel<<<NHEAD, 64, 0, stream>>>(cpart, lsep, t);
            row_gemv_kernel<<<24, 256, 0, stream>>>(
                t, wTdd + 3 * DD, bo + l * DM, h, h, nullptr, DM, 0, 1.f);
            ln_kernel<<<1, 192, 0, stream>>>(h, t, ln2_g + l * DM, ln2_b + l * DM);
            row_gemv_kernel<<<96, 256, 0, stream>>>(
                t, w1T, b1 + (size_t)l * FFND, nullptr, nullptr, ffn, DM, 1, 1.f);
            row_gemv_kernel<<<24, 256, 0, stream>>>(
                ffn, w2T, b2 + l * DM, h, h, nullptr, FFND, 0, 1.f);
        }
    }
    final_ln_kernel<<<1, 256, 0, stream>>>(h, enc_g, enc_b, norm_g, norm_b, out);
}

// Round 17
// 897.634 us; speedup vs baseline: 1.0791x; 1.0258x over previous
//
#include <hip/hip_runtime.h>
#include <hip/hip_bf16.h>
#include <math.h>
#include <stdint.h>

#define S_LEN 4096
#define L_LEN 4095
#define DIN   1536
#define DM    768
#define NHEAD 12
#define HDIM  64
#define FFND  3072
#define NEGV  (-1e9f)
#define EPS   1e-5f

typedef unsigned short u16;
typedef unsigned int   u32;
typedef short short8 __attribute__((ext_vector_type(8)));
typedef float f32x4 __attribute__((ext_vector_type(4)));
typedef float f32x16 __attribute__((ext_vector_type(16)));
typedef int i32x2 __attribute__((ext_vector_type(2)));

// ---------------------------------------------------------------- helpers
__device__ __forceinline__ u16 f2b(float f) {
    union { float f; u32 u; } x; x.f = f;
    u32 r = (x.u + 0x7FFF + ((x.u >> 16) & 1)) >> 16;
    return (u16)r;
}
__device__ __forceinline__ float b2f(u16 v) {
    union { u32 u; float f; } x; x.u = ((u32)v) << 16;
    return x.f;
}
__device__ __forceinline__ float gelu_tanh(float x) {
    float x3 = x * x * x;
    return 0.5f * x * (1.f + tanhf(0.7978845608f * (x + 0.044715f * x3)));
}
__device__ __forceinline__ float block_reduce_sum(float v, float* sbuf) {
#pragma unroll
    for (int o = 32; o > 0; o >>= 1) v += __shfl_down(v, o, 64);
    __syncthreads();
    if ((threadIdx.x & 63) == 0) sbuf[threadIdx.x >> 6] = v;
    __syncthreads();
    return sbuf[0] + sbuf[1] + sbuf[2] + sbuf[3];
}
__device__ __forceinline__ void gload16(const void* g, void* l) {
    __builtin_amdgcn_global_load_lds((const __attribute__((address_space(1))) void*)g,
                                     (__attribute__((address_space(3))) void*)l,
                                     16, 0, 0);
}
// barrier draining only LDS ops; global register prefetches stay in flight
__device__ __forceinline__ void lds_barrier() {
    asm volatile("s_waitcnt lgkmcnt(0)" ::: "memory");
    __builtin_amdgcn_s_barrier();
    __builtin_amdgcn_sched_barrier(0);
}

// ---------------------------------------------------------------- GEMM (bf16 MFMA, B^T layout)
// POS=1: add pos_embed[pos(coords[row])] in the epilogue (patch embed fusion)
template <int BM, int BN, int POS = 0>
__device__ __forceinline__ void gemm_bt(
    const u16* __restrict__ A, const u16* __restrict__ Bt,
    const float* __restrict__ bias, const float* __restrict__ res,
    float* __restrict__ outf, u16* __restrict__ outb,
    int M, int N, int K, float scale, int dogelu, int bx, int by,
    const float* __restrict__ coords = nullptr,
    const float* __restrict__ pe = nullptr)
{
    constexpr int MI = BM / 32;
    constexpr int NI = BN / 32;
    constexpr int AI = BM / 32;
    constexpr int BI = BN / 32;
    __shared__ u16 As[BM * 64];
    __shared__ u16 Bs[BN * 64];
    const int tid = threadIdx.x, wv = tid >> 6, l = tid & 63;
    const int bm = by * BM, bn = bx * BN;
    const int wm = wv >> 1, wn = wv & 1;

    f32x4 acc[MI][NI];
#pragma unroll
    for (int i = 0; i < MI; ++i)
#pragma unroll
        for (int j = 0; j < NI; ++j) acc[i][j] = (f32x4){0.f, 0.f, 0.f, 0.f};

    for (int k0 = 0; k0 < K; k0 += 64) {
#pragma unroll
        for (int i = 0; i < AI; ++i) {
            int row = (wv * AI + i) * 8 + (l >> 3);
            int col = ((l & 7) ^ (row & 7)) * 8;
            int grow = bm + row; if (grow > M - 1) grow = M - 1;
            gload16(A + (size_t)grow * K + k0 + col, &As[(wv * AI + i) * 512]);
        }
#pragma unroll
        for (int i = 0; i < BI; ++i) {
            int row = (wv * BI + i) * 8 + (l >> 3);
            int col = ((l & 7) ^ (row & 7)) * 8;
            gload16(Bt + (size_t)(bn + row) * K + k0 + col, &Bs[(wv * BI + i) * 512]);
        }
        __syncthreads();
#pragma unroll
        for (int kc = 0; kc < 2; ++kc) {
            short8 a[MI], b[NI];
#pragma unroll
            for (int mi = 0; mi < MI; ++mi) {
                int row = wm * (BM / 2) + mi * 16 + (l & 15);
                int off = ((l >> 4) * 16 + kc * 64) ^ ((row & 7) << 4);
                a[mi] = *(const short8*)&As[(row * 128 + off) >> 1];
            }
#pragma unroll
            for (int ni = 0; ni < NI; ++ni) {
                int row = wn * (BN / 2) + ni * 16 + (l & 15);
                int off = ((l >> 4) * 16 + kc * 64) ^ ((row & 7) << 4);
                b[ni] = *(const short8*)&Bs[(row * 128 + off) >> 1];
            }
#pragma unroll
            for (int mi = 0; mi < MI; ++mi)
#pragma unroll
                for (int ni = 0; ni < NI; ++ni)
                    acc[mi][ni] = __builtin_amdgcn_mfma_f32_16x16x32_bf16(
                        a[mi], b[ni], acc[mi][ni], 0, 0, 0);
        }
        __syncthreads();
    }
#pragma unroll
    for (int mi = 0; mi < MI; ++mi) {
#pragma unroll
        for (int rg = 0; rg < 4; ++rg) {
            int row = bm + wm * (BM / 2) + mi * 16 + (l >> 4) * 4 + rg;
            if (row >= M) continue;
            int posidx = 0;
            if constexpr (POS) {
                float c0 = floorf(coords[(size_t)row * 2 + 0] * (1.f / 256.f));
                float c1 = floorf(coords[(size_t)row * 2 + 1] * (1.f / 256.f));
                posidx = (int)(c0 * 128.f + c1) + 1;
            }
#pragma unroll
            for (int ni = 0; ni < NI; ++ni) {
                int col = bn + wn * (BN / 2) + ni * 16 + (l & 15);
                float v = (acc[mi][ni][rg] + bias[col]) * scale;
                if (dogelu) v = gelu_tanh(v);
                if (res) v += res[(size_t)row * N + col];
                if constexpr (POS) v += pe[(size_t)posidx * N + col];
                if (outf) outf[(size_t)row * N + col] = v;
                if (outb) outb[(size_t)row * N + col] = f2b(v);
            }
        }
    }
}

__global__ __launch_bounds__(256) void gemm128_kernel(
    const u16* __restrict__ A, const u16* __restrict__ Bt,
    const float* __restrict__ bias, const float* __restrict__ res,
    float* __restrict__ outf, u16* __restrict__ outb,
    int M, int N, int K, float scale, int dogelu)
{
    gemm_bt<128, 128>(A, Bt, bias, res, outf, outb, M, N, K, scale, dogelu,
                      blockIdx.x, blockIdx.y);
}
__global__ __launch_bounds__(256) void gemm6464_kernel(
    const u16* __restrict__ A, const u16* __restrict__ Bt,
    const float* __restrict__ bias, const float* __restrict__ res,
    float* __restrict__ outf, u16* __restrict__ outb,
    int M, int N, int K, float scale, int dogelu)
{
    gemm_bt<64, 64>(A, Bt, bias, res, outf, outb, M, N, K, scale, dogelu,
                    blockIdx.x, blockIdx.y);
}
// patch embed GEMM with fused pos-embed add (rows 1..4095 of h)
__global__ __launch_bounds__(256) void gemm_patch_kernel(
    const u16* __restrict__ A, const u16* __restrict__ Bt,
    const float* __restrict__ bias, const float* __restrict__ coords,
    const float* __restrict__ pe, float* __restrict__ outf,
    int M, int N, int K)
{
    gemm_bt<64, 64, 1>(A, Bt, bias, nullptr, outf, nullptr, M, N, K, 1.f, 0,
                       blockIdx.x, blockIdx.y, coords, pe);
}
__global__ __launch_bounds__(256) void qkv_kernel(
    const u16* __restrict__ t,
    const u16* __restrict__ wqT, const u16* __restrict__ wkT, const u16* __restrict__ wvT,
    const float* __restrict__ bq, const float* __restrict__ bk, const float* __restrict__ bv,
    u16* __restrict__ q, u16* __restrict__ k, u16* __restrict__ v, int zbase)
{
    int z = blockIdx.z + zbase;
    const u16* B = (z == 0) ? wqT : (z == 1) ? wkT : wvT;
    const float* bias = (z == 0) ? bq : (z == 1) ? bk : bv;
    u16* C = (z == 0) ? q : (z == 1) ? k : v;
    // Q additionally scaled by HD^-0.5 * log2(e) so softmax can use exp2
    float scale = (z == 0) ? 0.125f * 1.4426950408889634f : 1.0f;
    gemm_bt<128, 128>(t, B, bias, nullptr, nullptr, C, S_LEN, DM, DM, scale, 0,
                      blockIdx.x, blockIdx.y);
}

// ---------------------------------------------------------- transpose+convert
__global__ __launch_bounds__(256) void transpose_cvt(
    const float* __restrict__ s0, const float* __restrict__ s1,
    const float* __restrict__ s2, const float* __restrict__ s3,
    u16* __restrict__ dst, int K, int N)
{
    int z = blockIdx.z;
    const float* src = (z == 0) ? s0 : (z == 1) ? s1 : (z == 2) ? s2 : s3;
    u16* d = dst + (size_t)z * K * N;
    __shared__ float tile[64][65];
    const int t = threadIdx.x;
    const int tk = blockIdx.y * 64, tn = blockIdx.x * 64;
    const int r0 = t >> 4, c0 = (t & 15) * 4;
#pragma unroll
    for (int i = 0; i < 4; ++i) {
        const float* sp = &src[(size_t)(tk + r0 + i * 16) * N + tn + c0];
        tile[r0 + i * 16][c0 + 0] = sp[0];
        tile[r0 + i * 16][c0 + 1] = sp[1];
        tile[r0 + i * 16][c0 + 2] = sp[2];
        tile[r0 + i * 16][c0 + 3] = sp[3];
    }
    __syncthreads();
#pragma unroll
    for (int i = 0; i < 4; ++i) {
        int nr = r0 + i * 16;
        u32 lo = (u32)f2b(tile[c0 + 0][nr]) | ((u32)f2b(tile[c0 + 1][nr]) << 16);
        u32 hi = (u32)f2b(tile[c0 + 2][nr]) | ((u32)f2b(tile[c0 + 3][nr]) << 16);
        *(uint2*)&d[(size_t)(tn + nr) * K + tk + c0] = make_uint2(lo, hi);
    }
}

// merged per-layer weight transpose
__global__ __launch_bounds__(256) void prep_weights(
    const float* __restrict__ wq, const float* __restrict__ wk,
    const float* __restrict__ wv, const float* __restrict__ wo,
    const float* __restrict__ w1, const float* __restrict__ w2,
    u16* __restrict__ wTdd, u16* __restrict__ w1T, u16* __restrict__ w2T)
{
    __shared__ float tile[64][65];
    const int id = blockIdx.x;
    const float* src; u16* dst; int K, N, tk64, tn64;
    if (id < 576) {
        int z = id / 144, rm = id % 144;
        src = (z == 0) ? wq : (z == 1) ? wk : (z == 2) ? wv : wo;
        dst = wTdd + (size_t)z * DM * DM;
        K = DM; N = DM; tk64 = rm / 12; tn64 = rm % 12;
    } else if (id < 1152) {
        int rm = id - 576;
        src = w1; dst = w1T; K = DM; N = FFND; tk64 = rm / 48; tn64 = rm % 48;
    } else {
        int rm = id - 1152;
        src = w2; dst = w2T; K = FFND; N = DM; tk64 = rm / 12; tn64 = rm % 12;
    }
    const int t = threadIdx.x;
    const int tk = tk64 * 64, tn = tn64 * 64;
    const int r0 = t >> 4, c0 = (t & 15) * 4;
#pragma unroll
    for (int i = 0; i < 4; ++i) {
        const float* sp = &src[(size_t)(tk + r0 + i * 16) * N + tn + c0];
        tile[r0 + i * 16][c0 + 0] = sp[0];
        tile[r0 + i * 16][c0 + 1] = sp[1];
        tile[r0 + i * 16][c0 + 2] = sp[2];
        tile[r0 + i * 16][c0 + 3] = sp[3];
    }
    __syncthreads();
#pragma unroll
    for (int i = 0; i < 4; ++i) {
        int nr = r0 + i * 16;
        u32 lo = (u32)f2b(tile[c0 + 0][nr]) | ((u32)f2b(tile[c0 + 1][nr]) << 16);
        u32 hi = (u32)f2b(tile[c0 + 2][nr]) | ((u32)f2b(tile[c0 + 3][nr]) << 16);
        *(uint2*)&dst[(size_t)(tn + nr) * K + tk + c0] = make_uint2(lo, hi);
    }
}

__global__ __launch_bounds__(256) void cvt_bf16_kernel(
    const float* __restrict__ x, u16* __restrict__ xb, int n4)
{
    int stride = gridDim.x * 256;
    for (int i = blockIdx.x * 256 + threadIdx.x; i < n4; i += stride) {
        float4 v = ((const float4*)x)[i];
        u32 lo = (u32)f2b(v.x) | ((u32)f2b(v.y) << 16);
        u32 hi = (u32)f2b(v.z) | ((u32)f2b(v.w) << 16);
        ((uint2*)xb)[i] = make_uint2(lo, hi);
    }
}

// ---------------------------------------------------------------- LayerNorm
__global__ __launch_bounds__(192) void ln_kernel(
    const float* __restrict__ in, u16* __restrict__ out,
    const float* __restrict__ g, const float* __restrict__ b)
{
    __shared__ float sA[3], sB[3];
    const int s = blockIdx.x, tid = threadIdx.x;
    float4 x = ((const float4*)(in + (size_t)s * DM))[tid];
    float sum = x.x + x.y + x.z + x.w;
#pragma unroll
    for (int o = 32; o > 0; o >>= 1) sum += __shfl_down(sum, o, 64);
    if ((tid & 63) == 0) sA[tid >> 6] = sum;
    __syncthreads();
    float m = (sA[0] + sA[1] + sA[2]) * (1.f / DM);
    float dx = x.x - m, dy = x.y - m, dz = x.z - m, dw = x.w - m;
    float vs = dx * dx + dy * dy + dz * dz + dw * dw;
#pragma unroll
    for (int o = 32; o > 0; o >>= 1) vs += __shfl_down(vs, o, 64);
    if ((tid & 63) == 0) sB[tid >> 6] = vs;
    __syncthreads();
    float rs = rsqrtf((sB[0] + sB[1] + sB[2]) * (1.f / DM) + EPS);
    float4 gv = ((const float4*)g)[tid];
    float4 bv = ((const float4*)b)[tid];
    u32 lo = (u32)f2b(dx * rs * gv.x + bv.x) | ((u32)f2b(dy * rs * gv.y + bv.y) << 16);
    u32 hi = (u32)f2b(dz * rs * gv.z + bv.z) | ((u32)f2b(dw * rs * gv.w + bv.w) << 16);
    ((uint2*)(out + (size_t)s * DM))[tid] = make_uint2(lo, hi);
}

// ------------------------------------------------- cls row: h[0] = cls + pe[0]
__global__ __launch_bounds__(256) void posadd_cls_kernel(
    float* __restrict__ h, const float* __restrict__ pe,
    const float* __restrict__ cls)
{
    const int tid = threadIdx.x;
    for (int c = tid; c < DM; c += 256) h[c] = cls[c] + pe[c];
}

// ---------------------------------------------------------------- attention (layers 0..2)
// Swapped-QK flash attention, pipelined, ONE partial per branch (5 slots):
//   slot b = branch b (full key span; ntiles 16/16/16/8/4).
// Max-tracking with defer-THR=8.  XCD-aware block swizzle: grid 744 = 8*93.
__global__ __launch_bounds__(256, 3) void attn_kernel(
    const u16* __restrict__ qb, const u16* __restrict__ kbuf, const u16* __restrict__ vb,
    u16* __restrict__ obuf, u16* __restrict__ tp, float* __restrict__ lse)
{
    __shared__ u16 Vt[2][64 * 64];   // [buf][hd][key] swizzled
    __shared__ float dbuf[4][32];

    const int tid = threadIdx.x, wv = tid >> 6, l = tid & 63;
    const int lq = l & 31, lh = l >> 5;
    const int bid = (blockIdx.x & 7) * 93 + (blockIdx.x >> 3);
    int b, qtile, head, seg = 0;
    if (bid < 384) {
        b = 0; int i = bid; qtile = i & 7;
        int rest = i >> 3; head = rest % 12; seg = rest / 12;
    } else if (bid < 576) {
        b = 1; int i = bid - 384; qtile = i & 7;
        int rest = i >> 3; head = rest % 12; seg = rest / 12;
    } else if (bid < 672) {
        b = 2; int i = bid - 576; qtile = i & 7; head = i >> 3;
    } else if (bid < 720) {
        b = 3; int i = bid - 672; qtile = i & 3; head = i >> 2;
    } else {
        b = 4; int i = bid - 720; qtile = i & 1; head = i >> 1;
    }
    const int r = 1 << b;
    const int w = 1024 << b;
    const int ntiles = (b < 3) ? 16 : (b == 3 ? 8 : 4);
    const size_t base = (size_t)seg * w + (head & (r - 1));
    const int q0 = qtile * 128 + wv * 32;
    const size_t kstep = (size_t)r * DM;

    const size_t sq_l = base + (size_t)r * (q0 + lq);
    const u16* qp = qb + sq_l * DM + head * 64 + lh * 8;
    short8 qf[4];
#pragma unroll
    for (int s = 0; s < 4; ++s) qf[s] = *(const short8*)(qp + s * 16);

    const u16* kp = kbuf + (base + (size_t)r * lq) * DM + head * 64 + lh * 8;
    const int c = tid & 7, pp = tid >> 3;
    const u16* vsrc = vb + (base + (size_t)r * (2 * pp)) * DM + head * 64 + c * 8;

#define VPACK(dstbuf, A8, B8) do {                                          \
    _Pragma("unroll") for (int j = 0; j < 8; ++j) {                         \
        int i_ = (j + c) & 7; int hd_ = c * 8 + i_;                         \
        u32 val_ = (u32)(u16)(A8)[i_] | ((u32)(u16)(B8)[i_] << 16);         \
        int byte_ = hd_ * 128 + ((pp * 4) ^ (i_ << 4));                     \
        *(u32*)&Vt[dstbuf][byte_ >> 1] = val_; } } while (0)

    f32x16 oacc0 = {0.f,0.f,0.f,0.f,0.f,0.f,0.f,0.f,0.f,0.f,0.f,0.f,0.f,0.f,0.f,0.f};
    f32x16 oacc1 = oacc0;
    float mw = -INFINITY, dl = 0.f;

    short8 van = *(const short8*)vsrc;
    short8 vbn = *(const short8*)(vsrc + kstep);
    VPACK(0, van, vbn);
    van = *(const short8*)(vsrc + 64 * kstep);
    vbn = *(const short8*)(vsrc + 65 * kstep);
    short8 kf[8];
#pragma unroll
    for (int s = 0; s < 4; ++s) {
        kf[s]     = *(const short8*)(kp + s * 16);
        kf[4 + s] = *(const short8*)(kp + 32 * kstep + s * 16);
    }
    lds_barrier();

    for (int t = 0; t < ntiles; ++t) {
        const int curb = t & 1;
        f32x16 s0 = {0.f,0.f,0.f,0.f,0.f,0.f,0.f,0.f,0.f,0.f,0.f,0.f,0.f,0.f,0.f,0.f};
        f32x16 s1 = s0;
#pragma unroll
        for (int s = 0; s < 4; ++s)
            s0 = __builtin_amdgcn_mfma_f32_32x32x16_bf16(kf[s], qf[s], s0, 0, 0, 0);
#pragma unroll
        for (int s = 0; s < 4; ++s)
            s1 = __builtin_amdgcn_mfma_f32_32x32x16_bf16(kf[4 + s], qf[s], s1, 0, 0, 0);

        if (t + 1 < ntiles) {
            const u16* kn = kp + (size_t)(t + 1) * 64 * kstep;
#pragma unroll
            for (int s = 0; s < 4; ++s) {
                kf[s]     = *(const short8*)(kn + s * 16);
                kf[4 + s] = *(const short8*)(kn + 32 * kstep + s * 16);
            }
        }

        float pm[16];
#pragma unroll
        for (int i = 0; i < 16; ++i) pm[i] = fmaxf(s0[i], s1[i]);
#pragma unroll
        for (int i = 0; i < 8; ++i) pm[i] = fmaxf(pm[i], pm[i + 8]);
#pragma unroll
        for (int i = 0; i < 4; ++i) pm[i] = fmaxf(pm[i], pm[i + 4]);
        float mloc = fmaxf(fmaxf(pm[0], pm[1]), fmaxf(pm[2], pm[3]));
        if (__any(mloc > mw + 8.f)) {
            float mn = mloc;
#pragma unroll
            for (int o = 1; o < 64; o <<= 1) mn = fmaxf(mn, __shfl_xor(mn, o, 64));
            float al = exp2f(mw - mn);
            mw = mn;
            dl *= al;
#pragma unroll
            for (int i = 0; i < 16; ++i) { oacc0[i] *= al; oacc1[i] *= al; }
        }
        float ds = 0.f;
#pragma unroll
        for (int i = 0; i < 16; ++i) { s0[i] = exp2f(s0[i] - mw); ds += s0[i]; }
#pragma unroll
        for (int i = 0; i < 16; ++i) { s1[i] = exp2f(s1[i] - mw); ds += s1[i]; }
        ds += __shfl_xor(ds, 32, 64);
        dl += ds;

        if (t + 1 < ntiles) VPACK(curb ^ 1, van, vbn);
        if (t + 2 < ntiles) {
            van = *(const short8*)(vsrc + (size_t)(t + 2) * 64 * kstep);
            vbn = *(const short8*)(vsrc + ((size_t)(t + 2) * 64 + 1) * kstep);
        }

#pragma unroll
        for (int kb2 = 0; kb2 < 2; ++kb2) {
            u32 wd[8];
#pragma unroll
            for (int j = 0; j < 8; ++j) {
                float lo = (kb2 == 0) ? s0[2 * j] : s1[2 * j];
                float hi = (kb2 == 0) ? s0[2 * j + 1] : s1[2 * j + 1];
                asm("v_cvt_pk_bf16_f32 %0, %1, %2" : "=v"(wd[j]) : "v"(lo), "v"(hi));
            }
#pragma unroll
            for (int ks2 = 0; ks2 < 2; ++ks2) {
                i32x2 X = __builtin_amdgcn_permlane32_swap(
                    (int)wd[ks2 * 4 + 0], (int)wd[ks2 * 4 + 2], false, false);
                i32x2 Y = __builtin_amdgcn_permlane32_swap(
                    (int)wd[ks2 * 4 + 1], (int)wd[ks2 * 4 + 3], false, false);
                union { u32 u[4]; short8 s; } pk;
                pk.u[0] = (u32)X[0]; pk.u[1] = (u32)Y[0];
                pk.u[2] = (u32)X[1]; pk.u[3] = (u32)Y[1];
                const int tt = kb2 * 2 + ks2;
#pragma unroll
                for (int hg = 0; hg < 2; ++hg) {
                    int row = hg * 32 + lq;
                    int byteoff = row * 128 + ((lh * 16 + tt * 32) ^ ((row & 7) << 4));
                    short8 vf = *(const short8*)&Vt[curb][byteoff >> 1];
                    if (hg == 0)
                        oacc0 = __builtin_amdgcn_mfma_f32_32x32x16_bf16(pk.s, vf, oacc0, 0, 0, 0);
                    else
                        oacc1 = __builtin_amdgcn_mfma_f32_32x32x16_bf16(pk.s, vf, oacc1, 0, 0, 0);
                }
            }
        }
        lds_barrier();
    }

    if (l < 32) dbuf[wv][lq] = dl;
    u16* ob = (b == 4) ? tp : obuf + (size_t)b * S_LEN * DM;
    float* lse_b = lse + (size_t)b * S_LEN * NHEAD;
    if (l < 32) lse_b[sq_l * NHEAD + head] = mw + log2f(dl);
#pragma unroll
    for (int reg = 0; reg < 16; ++reg) {
        int qloc = (reg & 3) + 8 * (reg >> 2) + 4 * lh;
        float invd = 1.f / dbuf[wv][qloc];
        size_t sq = base + (size_t)r * (q0 + qloc);
        u16* orow = ob + sq * DM + head * 64;
        u32 pk2;
        float v0 = oacc0[reg] * invd, v1 = oacc1[reg] * invd;
        asm("v_cvt_pk_bf16_f32 %0, %1, %2" : "=v"(pk2) : "v"(v0), "v"(v1));
        orow[lq]      = (u16)(pk2 & 0xffff);
        orow[32 + lq] = (u16)(pk2 >> 16);
    }
#undef VPACK
}

// ---- LongNet combine over 5 branch partials (normalized o, exp2(lse-mx)).
// Structural coverage: branch b valid for (s,head) iff (s^head)&(r-1)==0;
// branch 4 iff (s&15)==head.  Invalid slots fully skipped.
__global__ __launch_bounds__(192) void combine_kernel(
    const u16* __restrict__ obuf, const float* __restrict__ lse,
    u16* __restrict__ t)
{
    const int s = blockIdx.x;
    const int tid = threadIdx.x;
    const int c0 = tid * 4, head = c0 >> 6;
    const size_t SD = (size_t)S_LEN * DM;
    const size_t SN = (size_t)S_LEN * NHEAD;
    const int sx = s ^ head;
    bool val[5];
    val[0] = true;
    val[1] = (sx & 1) == 0;
    val[2] = (sx & 3) == 0;
    val[3] = (sx & 7) == 0;
    val[4] = (s & 15) == head;
    float lv[5];
#pragma unroll
    for (int b = 0; b < 5; ++b)
        lv[b] = val[b] ? lse[b * SN + (size_t)s * NHEAD + head] : NEGV;
    float mx = lv[0];
#pragma unroll
    for (int b = 1; b < 5; ++b) mx = fmaxf(mx, lv[b]);
    float wsum = 0.f, o0 = 0.f, o1 = 0.f, o2 = 0.f, o3 = 0.f;
#pragma unroll
    for (int b = 0; b < 5; ++b) {
        if (val[b]) {
            float wb = exp2f(lv[b] - mx);
            wsum += wb;
            const u16* src = (b == 4) ? t : obuf + (size_t)b * SD;
            uint2 u = *(const uint2*)(src + (size_t)s * DM + c0);
            o0 += wb * b2f((u16)(u.x & 0xffff));
            o1 += wb * b2f((u16)(u.x >> 16));
            o2 += wb * b2f((u16)(u.y & 0xffff));
            o3 += wb * b2f((u16)(u.y >> 16));
        }
    }
    float inv = 1.f / wsum;
    u32 lo = (u32)f2b(o0 * inv) | ((u32)f2b(o1 * inv) << 16);
    u32 hi = (u32)f2b(o2 * inv) | ((u32)f2b(o3 * inv) << 16);
    ((uint2*)(t + (size_t)s * DM))[tid] = make_uint2(lo, hi);
}

// ---------------------------------------------------------------- layer-3 cls path
__global__ __launch_bounds__(256) void cls_attn_kernel(
    const u16* __restrict__ qb, const u16* __restrict__ kb,
    const u16* __restrict__ vb, float* __restrict__ cpart,
    float* __restrict__ lsep)
{
    __shared__ float q0[64];
    __shared__ float pbuf[128];
    __shared__ float red[8];
    __shared__ float po[256];
    const int blk = blockIdx.x, tid = threadIdx.x;
    int b, head, chunk;
    if (blk < 96)       { b = 0; head = blk >> 3; chunk = blk & 7; }
    else if (blk < 144) { int i = blk - 96;  b = 1; head = (i >> 3) * 2; chunk = i & 7; }
    else if (blk < 168) { int i = blk - 144; b = 2; head = (i >> 3) * 4; chunk = i & 7; }
    else if (blk < 176) { int i = blk - 168; b = 3; head = (i >> 2) * 8; chunk = i & 3; }
    else                { int i = blk - 176; b = 4; head = 0;            chunk = i; }
    const int r = 1 << b;
    if (tid < 64) q0[tid] = b2f(qb[head * 64 + tid]);  // row 0, pre-scaled log2e/8
    __syncthreads();

    float sc = -1e30f;
    if (tid < 128) {
        const int j = chunk * 128 + tid;
        const u16* kp = kb + (size_t)j * r * DM + head * 64;
        float acc = 0.f;
#pragma unroll
        for (int d8 = 0; d8 < 8; ++d8) {
            short8 kv = *(const short8*)(kp + d8 * 8);
#pragma unroll
            for (int jj = 0; jj < 8; ++jj)
                acc += q0[d8 * 8 + jj] * b2f((u16)kv[jj]);
        }
        sc = acc;
    }
    float mxw = sc;
#pragma unroll
    for (int o = 1; o < 64; o <<= 1) mxw = fmaxf(mxw, __shfl_xor(mxw, o, 64));
    if ((tid & 63) == 0) red[tid >> 6] = mxw;
    __syncthreads();
    const float bm = fmaxf(red[0], red[1]);
    float p = 0.f;
    if (tid < 128) { p = exp2f(sc - bm); pbuf[tid] = p; }
    float sw = p;
#pragma unroll
    for (int o = 1; o < 64; o <<= 1) sw += __shfl_xor(sw, o, 64);
    if ((tid & 63) == 0) red[4 + (tid >> 6)] = sw;
    __syncthreads();
    const float dsum = red[4] + red[5];

    const int hd = tid & 63, ch = tid >> 6;
    const u16* vp = vb + (size_t)(chunk * 128 + ch * 32) * r * DM + head * 64 + hd;
    const size_t vstep = (size_t)r * DM;
    float o = 0.f;
#pragma unroll 8
    for (int j = 0; j < 32; ++j)
        o += pbuf[ch * 32 + j] * b2f(vp[(size_t)j * vstep]);
    po[tid] = o;
    __syncthreads();
    if (tid < 64)
        cpart[(size_t)blk * 64 + tid] =
            (po[tid] + po[tid + 64] + po[tid + 128] + po[tid + 192]) / dsum;
    if (tid == 0) lsep[blk] = bm + log2f(dsum);
}

__global__ __launch_bounds__(64) void cls_combine_kernel(
    const float* __restrict__ cpart, const float* __restrict__ lsep,
    u16* __restrict__ t)
{
    const int head = blockIdx.x, tid = threadIdx.x;
#define FORALL_PARTS(EXPR)                                                    \
    for (int c = 0; c < 8; ++c) { int blk = head * 8 + c; EXPR; }             \
    if (!(head & 1)) for (int c = 0; c < 8; ++c) { int blk = 96 + (head >> 1) * 8 + c; EXPR; } \
    if (!(head & 3)) for (int c = 0; c < 8; ++c) { int blk = 144 + (head >> 2) * 8 + c; EXPR; } \
    if (!(head & 7)) for (int c = 0; c < 4; ++c) { int blk = 168 + (head >> 3) * 4 + c; EXPR; } \
    if (head == 0)  for (int c = 0; c < 2; ++c) { int blk = 176 + c; EXPR; }
    float mx = -1e30f;
    FORALL_PARTS(mx = fmaxf(mx, lsep[blk]))
    float ws = 0.f, ov = 0.f;
    FORALL_PARTS({ float wb = exp2f(lsep[blk] - mx); ws += wb;
                   ov += wb * cpart[(size_t)blk * 64 + tid]; })
    t[head * 64 + tid] = f2b(ov / ws);
#undef FORALL_PARTS
}

// row-0 GEMV, 8 threads per output (width-8 shuffle reduce), 32 outputs/block
__global__ __launch_bounds__(256) void row_gemv_kernel(
    const u16* __restrict__ x, const u16* __restrict__ wT,
    const float* __restrict__ bias, const float* __restrict__ res,
    float* __restrict__ outf, u16* __restrict__ outb, int K, int dogelu,
    float scale)
{
    __shared__ float xs[3072];
    const int tid = threadIdx.x;
    for (int i = tid; i < K; i += 256) xs[i] = b2f(x[i]);
    __syncthreads();
    const int n = blockIdx.x * 32 + (tid >> 3);
    const int kp = tid & 7;
    const u16* wrow = wT + (size_t)n * K;
    float acc = 0.f;
    for (int k = kp * 8; k < K; k += 64) {
        short8 wv = *(const short8*)(wrow + k);
#pragma unroll
        for (int j = 0; j < 8; ++j) acc += xs[k + j] * b2f((u16)wv[j]);
    }
    acc += __shfl_down(acc, 4, 8);
    acc += __shfl_down(acc, 2, 8);
    acc += __shfl_down(acc, 1, 8);
    if (kp == 0) {
        float v = (acc + bias[n]) * scale;
        if (dogelu) v = gelu_tanh(v);
        if (res) v += res[n];
        if (outf) outf[n] = v;
        if (outb) outb[n] = f2b(v);
    }
}

// ---------------------------------------------------- final double-LN, row 0
__global__ __launch_bounds__(256) void final_ln_kernel(
    const float* __restrict__ h,
    const float* __restrict__ g1, const float* __restrict__ b1,
    const float* __restrict__ g2, const float* __restrict__ b2,
    float* __restrict__ out)
{
    __shared__ float sbuf[4];
    const int tid = threadIdx.x;
    float x0 = h[tid], x1 = h[tid + 256], x2 = h[tid + 512];
    float m = block_reduce_sum(x0 + x1 + x2, sbuf) * (1.f / DM);
    float d0 = x0 - m, d1 = x1 - m, d2 = x2 - m;
    float var = block_reduce_sum(d0 * d0 + d1 * d1 + d2 * d2, sbuf) * (1.f / DM);
    float rs = rsqrtf(var + EPS);
    float y0 = d0 * rs * g1[tid]       + b1[tid];
    float y1 = d1 * rs * g1[tid + 256] + b1[tid + 256];
    float y2 = d2 * rs * g1[tid + 512] + b1[tid + 512];
    m = block_reduce_sum(y0 + y1 + y2, sbuf) * (1.f / DM);
    d0 = y0 - m; d1 = y1 - m; d2 = y2 - m;
    var = block_reduce_sum(d0 * d0 + d1 * d1 + d2 * d2, sbuf) * (1.f / DM);
    rs = rsqrtf(var + EPS);
    out[tid]       = d0 * rs * g2[tid]       + b2[tid];
    out[tid + 256] = d1 * rs * g2[tid + 256] + b2[tid + 256];
    out[tid + 512] = d2 * rs * g2[tid + 512] + b2[tid + 512];
}

// ---------------------------------------------------------------- launcher
extern "C" void kernel_launch(void* const* d_in, const int* in_sizes, int n_in,
                              void* d_out, int out_size, void* d_ws, size_t ws_size,
                              hipStream_t stream)
{
    (void)in_sizes; (void)n_in; (void)out_size; (void)ws_size;
    const float* x        = (const float*)d_in[0];
    const float* coords   = (const float*)d_in[1];
    const float* pos_emb  = (const float*)d_in[2];
    const float* cls_tok  = (const float*)d_in[3];
    const float* patch_w  = (const float*)d_in[4];
    const float* patch_b  = (const float*)d_in[5];
    const float* ln1_g    = (const float*)d_in[6];
    const float* ln1_b    = (const float*)d_in[7];
    const float* wq       = (const float*)d_in[8];
    const float* bq       = (const float*)d_in[9];
    const float* wk       = (const float*)d_in[10];
    const float* bk       = (const float*)d_in[11];
    const float* wv       = (const float*)d_in[12];
    const float* bv       = (const float*)d_in[13];
    const float* wo       = (const float*)d_in[14];
    const float* bo       = (const float*)d_in[15];
    const float* ln2_g    = (const float*)d_in[16];
    const float* ln2_b    = (const float*)d_in[17];
    const float* w1       = (const float*)d_in[18];
    const float* b1       = (const float*)d_in[19];
    const float* w2       = (const float*)d_in[20];
    const float* b2       = (const float*)d_in[21];
    const float* enc_g    = (const float*)d_in[22];
    const float* enc_b    = (const float*)d_in[23];
    const float* norm_g   = (const float*)d_in[24];
    const float* norm_b   = (const float*)d_in[25];
    float* out = (float*)d_out;

    const size_t SD = (size_t)S_LEN * DM;
    const size_t DD = (size_t)DM * DM;
    const size_t DF = (size_t)DM * FFND;
    const size_t SN = (size_t)S_LEN * NHEAD;

    char* p = (char*)d_ws;
    float* h   = (float*)p;              p += SD * 4;
    u16* t     = (u16*)p;                p += SD * 2;
    u16* qb    = (u16*)p;                p += SD * 2;
    u16* kb    = (u16*)p;                p += SD * 2;
    u16* vb    = (u16*)p;                p += SD * 2;
    float* lse = (float*)p;              p += 5 * SN * 4;
    u16* obuf  = (u16*)p;                p += 4 * SD * 2;  // slot 4 == t
    u16* ffn   = obuf;                   // aliases obuf (dead during FFN)
    u16* xb    = obuf;                   // aliases obuf (used only pre-layer0)
    u16* pwT   = (u16*)p;                p += (size_t)DIN * DM * 2;
    u16* wTdd  = (u16*)p;                p += 4 * DD * 2;
    u16* w1T   = (u16*)p;                p += DF * 2;
    u16* w2T   = (u16*)p;                p += DF * 2;
    // layer-3 cls partials reuse the (then-idle) lse buffer
    float* cpart = lse;                  // 178*64 floats
    float* lsep  = lse + 178 * 64;       // 178 floats

    cvt_bf16_kernel<<<2048, 256, 0, stream>>>(x, xb, (L_LEN * DIN) / 4);
    transpose_cvt<<<dim3(DM / 64, DIN / 64, 1), 256, 0, stream>>>(
        patch_w, patch_w, patch_w, patch_w, pwT, DIN, DM);
    // patch embed with fused pos-embed add (rows 1..4095)
    gemm_patch_kernel<<<dim3(DM / 64, 64), 256, 0, stream>>>(
        xb, pwT, patch_b, coords, pos_emb, h + DM, L_LEN, DM, DIN);
    posadd_cls_kernel<<<1, 256, 0, stream>>>(h, pos_emb, cls_tok);

    for (int l = 0; l < 4; ++l) {
        const size_t lDD = (size_t)l * DD;
        const size_t lDF = (size_t)l * DF;
        prep_weights<<<1728, 256, 0, stream>>>(
            wq + lDD, wk + lDD, wv + lDD, wo + lDD, w1 + lDF, w2 + lDF,
            wTdd, w1T, w2T);

        ln_kernel<<<S_LEN, 192, 0, stream>>>(h, t, ln1_g + l * DM, ln1_b + l * DM);

        if (l < 3) {
            qkv_kernel<<<dim3(6, 32, 3), 256, 0, stream>>>(
                t, wTdd, wTdd + DD, wTdd + 2 * DD,
                bq + l * DM, bk + l * DM, bv + l * DM, qb, kb, vb, 0);
            attn_kernel<<<744, 256, 0, stream>>>(qb, kb, vb, obuf, t, lse);
            combine_kernel<<<S_LEN, 192, 0, stream>>>(obuf, lse, t);
            gemm6464_kernel<<<dim3(12, 64), 256, 0, stream>>>(
                t, wTdd + 3 * DD, bo + l * DM, h, h, nullptr, S_LEN, DM, DM, 1.f, 0);
            ln_kernel<<<S_LEN, 192, 0, stream>>>(h, t, ln2_g + l * DM, ln2_b + l * DM);
            gemm128_kernel<<<dim3(24, 32), 256, 0, stream>>>(
                t, w1T, b1 + (size_t)l * FFND, nullptr, nullptr, ffn,
                S_LEN, FFND, DM, 1.f, 1);
            gemm6464_kernel<<<dim3(12, 64), 256, 0, stream>>>(
                ffn, w2T, b2 + l * DM, h, h, nullptr, S_LEN, DM, FFND, 1.f, 0);
        } else {
            // Last layer: only the cls row (s=0) is consumed downstream.
            // K,V needed in full (branch 0 attends over all keys); Q only row 0.
            qkv_kernel<<<dim3(6, 32, 2), 256, 0, stream>>>(
                t, wTdd, wTdd + DD, wTdd + 2 * DD,
                bq + l * DM, bk + l * DM, bv + l * DM, qb, kb, vb, 1);
            row_gemv_kernel<<<24, 256, 0, stream>>>(
                t, wTdd, bq + l * DM, nullptr, nullptr, qb, DM, 0,
                0.125f * 1.4426950408889634f);
            cls_attn_kernel<<<178, 256, 0, stream>>>(qb, kb, vb, cpart, lsep);
            cls_combine_kernel<<<NHEAD, 64, 0, stream>>>(cpart, lsep, t);
            row_gemv_kernel<<<24, 256, 0, stream>>>(
                t, wTdd + 3 * DD, bo + l * DM, h, h, nullptr, DM, 0, 1.f);
            ln_kernel<<<1, 192, 0, stream>>>(h, t, ln2_g + l * DM, ln2_b + l * DM);
            row_gemv_kernel<<<96, 256, 0, stream>>>(
                t, w1T, b1 + (size_t)l * FFND, nullptr, nullptr, ffn, DM, 1, 1.f);
            row_gemv_kernel<<<24, 256, 0, stream>>>(
                ffn, w2T, b2 + l * DM, h, h, nullptr, FFND, 0, 1.f);
        }
    }
    final_ln_kernel<<<1, 256, 0, stream>>>(h, enc_g, enc_b, norm_g, norm_b, out);
}

// Round 18
// 889.341 us; speedup vs baseline: 1.0892x; 1.0093x over previous
//
#include <hip/hip_runtime.h>
#include <hip/hip_bf16.h>
#include <math.h>
#include <stdint.h>

#define S_LEN 4096
#define L_LEN 4095
#define DIN   1536
#define DM    768
#define NHEAD 12
#define HDIM  64
#define FFND  3072
#define NEGV  (-1e9f)
#define EPS   1e-5f

typedef unsigned short u16;
typedef unsigned int   u32;
typedef short short8 __attribute__((ext_vector_type(8)));
typedef float f32x4 __attribute__((ext_vector_type(4)));
typedef float f32x16 __attribute__((ext_vector_type(16)));
typedef int i32x2 __attribute__((ext_vector_type(2)));

// ---------------------------------------------------------------- helpers
__device__ __forceinline__ u16 f2b(float f) {
    union { float f; u32 u; } x; x.f = f;
    u32 r = (x.u + 0x7FFF + ((x.u >> 16) & 1)) >> 16;
    return (u16)r;
}
__device__ __forceinline__ float b2f(u16 v) {
    union { u32 u; float f; } x; x.u = ((u32)v) << 16;
    return x.f;
}
__device__ __forceinline__ float gelu_tanh(float x) {
    float x3 = x * x * x;
    return 0.5f * x * (1.f + tanhf(0.7978845608f * (x + 0.044715f * x3)));
}
__device__ __forceinline__ float block_reduce_sum(float v, float* sbuf) {
#pragma unroll
    for (int o = 32; o > 0; o >>= 1) v += __shfl_down(v, o, 64);
    __syncthreads();
    if ((threadIdx.x & 63) == 0) sbuf[threadIdx.x >> 6] = v;
    __syncthreads();
    return sbuf[0] + sbuf[1] + sbuf[2] + sbuf[3];
}
__device__ __forceinline__ void gload16(const void* g, void* l) {
    __builtin_amdgcn_global_load_lds((const __attribute__((address_space(1))) void*)g,
                                     (__attribute__((address_space(3))) void*)l,
                                     16, 0, 0);
}
// barrier draining only LDS ops; global register prefetches stay in flight
__device__ __forceinline__ void lds_barrier() {
    asm volatile("s_waitcnt lgkmcnt(0)" ::: "memory");
    __builtin_amdgcn_s_barrier();
    __builtin_amdgcn_sched_barrier(0);
}

// ---------------------------------------------------------------- GEMM (bf16 MFMA, B^T layout)
// POS=1: add pos_embed[pos(coords[row])] in the epilogue (patch embed fusion)
template <int BM, int BN, int POS = 0>
__device__ __forceinline__ void gemm_bt(
    const u16* __restrict__ A, const u16* __restrict__ Bt,
    const float* __restrict__ bias, const float* __restrict__ res,
    float* __restrict__ outf, u16* __restrict__ outb,
    int M, int N, int K, float scale, int dogelu, int bx, int by,
    const float* __restrict__ coords = nullptr,
    const float* __restrict__ pe = nullptr)
{
    constexpr int MI = BM / 32;
    constexpr int NI = BN / 32;
    constexpr int AI = BM / 32;
    constexpr int BI = BN / 32;
    __shared__ u16 As[BM * 64];
    __shared__ u16 Bs[BN * 64];
    const int tid = threadIdx.x, wv = tid >> 6, l = tid & 63;
    const int bm = by * BM, bn = bx * BN;
    const int wm = wv >> 1, wn = wv & 1;

    f32x4 acc[MI][NI];
#pragma unroll
    for (int i = 0; i < MI; ++i)
#pragma unroll
        for (int j = 0; j < NI; ++j) acc[i][j] = (f32x4){0.f, 0.f, 0.f, 0.f};

    for (int k0 = 0; k0 < K; k0 += 64) {
#pragma unroll
        for (int i = 0; i < AI; ++i) {
            int row = (wv * AI + i) * 8 + (l >> 3);
            int col = ((l & 7) ^ (row & 7)) * 8;
            int grow = bm + row; if (grow > M - 1) grow = M - 1;
            gload16(A + (size_t)grow * K + k0 + col, &As[(wv * AI + i) * 512]);
        }
#pragma unroll
        for (int i = 0; i < BI; ++i) {
            int row = (wv * BI + i) * 8 + (l >> 3);
            int col = ((l & 7) ^ (row & 7)) * 8;
            gload16(Bt + (size_t)(bn + row) * K + k0 + col, &Bs[(wv * BI + i) * 512]);
        }
        __syncthreads();
#pragma unroll
        for (int kc = 0; kc < 2; ++kc) {
            short8 a[MI], b[NI];
#pragma unroll
            for (int mi = 0; mi < MI; ++mi) {
                int row = wm * (BM / 2) + mi * 16 + (l & 15);
                int off = ((l >> 4) * 16 + kc * 64) ^ ((row & 7) << 4);
                a[mi] = *(const short8*)&As[(row * 128 + off) >> 1];
            }
#pragma unroll
            for (int ni = 0; ni < NI; ++ni) {
                int row = wn * (BN / 2) + ni * 16 + (l & 15);
                int off = ((l >> 4) * 16 + kc * 64) ^ ((row & 7) << 4);
                b[ni] = *(const short8*)&Bs[(row * 128 + off) >> 1];
            }
#pragma unroll
            for (int mi = 0; mi < MI; ++mi)
#pragma unroll
                for (int ni = 0; ni < NI; ++ni)
                    acc[mi][ni] = __builtin_amdgcn_mfma_f32_16x16x32_bf16(
                        a[mi], b[ni], acc[mi][ni], 0, 0, 0);
        }
        __syncthreads();
    }
#pragma unroll
    for (int mi = 0; mi < MI; ++mi) {
#pragma unroll
        for (int rg = 0; rg < 4; ++rg) {
            int row = bm + wm * (BM / 2) + mi * 16 + (l >> 4) * 4 + rg;
            if (row >= M) continue;
            int posidx = 0;
            if constexpr (POS) {
                float c0 = floorf(coords[(size_t)row * 2 + 0] * (1.f / 256.f));
                float c1 = floorf(coords[(size_t)row * 2 + 1] * (1.f / 256.f));
                posidx = (int)(c0 * 128.f + c1) + 1;
            }
#pragma unroll
            for (int ni = 0; ni < NI; ++ni) {
                int col = bn + wn * (BN / 2) + ni * 16 + (l & 15);
                float v = (acc[mi][ni][rg] + bias[col]) * scale;
                if (dogelu) v = gelu_tanh(v);
                if (res) v += res[(size_t)row * N + col];
                if constexpr (POS) v += pe[(size_t)posidx * N + col];
                if (outf) outf[(size_t)row * N + col] = v;
                if (outb) outb[(size_t)row * N + col] = f2b(v);
            }
        }
    }
}

__global__ __launch_bounds__(256) void gemm128_kernel(
    const u16* __restrict__ A, const u16* __restrict__ Bt,
    const float* __restrict__ bias, const float* __restrict__ res,
    float* __restrict__ outf, u16* __restrict__ outb,
    int M, int N, int K, float scale, int dogelu)
{
    gemm_bt<128, 128>(A, Bt, bias, res, outf, outb, M, N, K, scale, dogelu,
                      blockIdx.x, blockIdx.y);
}
__global__ __launch_bounds__(256) void gemm6464_kernel(
    const u16* __restrict__ A, const u16* __restrict__ Bt,
    const float* __restrict__ bias, const float* __restrict__ res,
    float* __restrict__ outf, u16* __restrict__ outb,
    int M, int N, int K, float scale, int dogelu)
{
    gemm_bt<64, 64>(A, Bt, bias, res, outf, outb, M, N, K, scale, dogelu,
                    blockIdx.x, blockIdx.y);
}
// patch embed GEMM with fused pos-embed add (rows 1..4095 of h)
__global__ __launch_bounds__(256) void gemm_patch_kernel(
    const u16* __restrict__ A, const u16* __restrict__ Bt,
    const float* __restrict__ bias, const float* __restrict__ coords,
    const float* __restrict__ pe, float* __restrict__ outf,
    int M, int N, int K)
{
    gemm_bt<64, 64, 1>(A, Bt, bias, nullptr, outf, nullptr, M, N, K, 1.f, 0,
                       blockIdx.x, blockIdx.y, coords, pe);
}
__global__ __launch_bounds__(256) void qkv_kernel(
    const u16* __restrict__ t,
    const u16* __restrict__ wqT, const u16* __restrict__ wkT, const u16* __restrict__ wvT,
    const float* __restrict__ bq, const float* __restrict__ bk, const float* __restrict__ bv,
    u16* __restrict__ q, u16* __restrict__ k, u16* __restrict__ v, int zbase)
{
    int z = blockIdx.z + zbase;
    const u16* B = (z == 0) ? wqT : (z == 1) ? wkT : wvT;
    const float* bias = (z == 0) ? bq : (z == 1) ? bk : bv;
    u16* C = (z == 0) ? q : (z == 1) ? k : v;
    // Q additionally scaled by HD^-0.5 * log2(e) so softmax can use exp2
    float scale = (z == 0) ? 0.125f * 1.4426950408889634f : 1.0f;
    gemm_bt<128, 128>(t, B, bias, nullptr, nullptr, C, S_LEN, DM, DM, scale, 0,
                      blockIdx.x, blockIdx.y);
}

// ---------------------------------------------------------- transpose+convert
__global__ __launch_bounds__(256) void transpose_cvt(
    const float* __restrict__ s0, const float* __restrict__ s1,
    const float* __restrict__ s2, const float* __restrict__ s3,
    u16* __restrict__ dst, int K, int N)
{
    int z = blockIdx.z;
    const float* src = (z == 0) ? s0 : (z == 1) ? s1 : (z == 2) ? s2 : s3;
    u16* d = dst + (size_t)z * K * N;
    __shared__ float tile[64][65];
    const int t = threadIdx.x;
    const int tk = blockIdx.y * 64, tn = blockIdx.x * 64;
    const int r0 = t >> 4, c0 = (t & 15) * 4;
#pragma unroll
    for (int i = 0; i < 4; ++i) {
        const float* sp = &src[(size_t)(tk + r0 + i * 16) * N + tn + c0];
        tile[r0 + i * 16][c0 + 0] = sp[0];
        tile[r0 + i * 16][c0 + 1] = sp[1];
        tile[r0 + i * 16][c0 + 2] = sp[2];
        tile[r0 + i * 16][c0 + 3] = sp[3];
    }
    __syncthreads();
#pragma unroll
    for (int i = 0; i < 4; ++i) {
        int nr = r0 + i * 16;
        u32 lo = (u32)f2b(tile[c0 + 0][nr]) | ((u32)f2b(tile[c0 + 1][nr]) << 16);
        u32 hi = (u32)f2b(tile[c0 + 2][nr]) | ((u32)f2b(tile[c0 + 3][nr]) << 16);
        *(uint2*)&d[(size_t)(tn + nr) * K + tk + c0] = make_uint2(lo, hi);
    }
}

// merged per-layer weight transpose
__global__ __launch_bounds__(256) void prep_weights(
    const float* __restrict__ wq, const float* __restrict__ wk,
    const float* __restrict__ wv, const float* __restrict__ wo,
    const float* __restrict__ w1, const float* __restrict__ w2,
    u16* __restrict__ wTdd, u16* __restrict__ w1T, u16* __restrict__ w2T)
{
    __shared__ float tile[64][65];
    const int id = blockIdx.x;
    const float* src; u16* dst; int K, N, tk64, tn64;
    if (id < 576) {
        int z = id / 144, rm = id % 144;
        src = (z == 0) ? wq : (z == 1) ? wk : (z == 2) ? wv : wo;
        dst = wTdd + (size_t)z * DM * DM;
        K = DM; N = DM; tk64 = rm / 12; tn64 = rm % 12;
    } else if (id < 1152) {
        int rm = id - 576;
        src = w1; dst = w1T; K = DM; N = FFND; tk64 = rm / 48; tn64 = rm % 48;
    } else {
        int rm = id - 1152;
        src = w2; dst = w2T; K = FFND; N = DM; tk64 = rm / 12; tn64 = rm % 12;
    }
    const int t = threadIdx.x;
    const int tk = tk64 * 64, tn = tn64 * 64;
    const int r0 = t >> 4, c0 = (t & 15) * 4;
#pragma unroll
    for (int i = 0; i < 4; ++i) {
        const float* sp = &src[(size_t)(tk + r0 + i * 16) * N + tn + c0];
        tile[r0 + i * 16][c0 + 0] = sp[0];
        tile[r0 + i * 16][c0 + 1] = sp[1];
        tile[r0 + i * 16][c0 + 2] = sp[2];
        tile[r0 + i * 16][c0 + 3] = sp[3];
    }
    __syncthreads();
#pragma unroll
    for (int i = 0; i < 4; ++i) {
        int nr = r0 + i * 16;
        u32 lo = (u32)f2b(tile[c0 + 0][nr]) | ((u32)f2b(tile[c0 + 1][nr]) << 16);
        u32 hi = (u32)f2b(tile[c0 + 2][nr]) | ((u32)f2b(tile[c0 + 3][nr]) << 16);
        *(uint2*)&dst[(size_t)(tn + nr) * K + tk + c0] = make_uint2(lo, hi);
    }
}

__global__ __launch_bounds__(256) void cvt_bf16_kernel(
    const float* __restrict__ x, u16* __restrict__ xb, int n4)
{
    int stride = gridDim.x * 256;
    for (int i = blockIdx.x * 256 + threadIdx.x; i < n4; i += stride) {
        float4 v = ((const float4*)x)[i];
        u32 lo = (u32)f2b(v.x) | ((u32)f2b(v.y) << 16);
        u32 hi = (u32)f2b(v.z) | ((u32)f2b(v.w) << 16);
        ((uint2*)xb)[i] = make_uint2(lo, hi);
    }
}

// ---------------------------------------------------------------- LayerNorm
__global__ __launch_bounds__(192) void ln_kernel(
    const float* __restrict__ in, u16* __restrict__ out,
    const float* __restrict__ g, const float* __restrict__ b)
{
    __shared__ float sA[3], sB[3];
    const int s = blockIdx.x, tid = threadIdx.x;
    float4 x = ((const float4*)(in + (size_t)s * DM))[tid];
    float sum = x.x + x.y + x.z + x.w;
#pragma unroll
    for (int o = 32; o > 0; o >>= 1) sum += __shfl_down(sum, o, 64);
    if ((tid & 63) == 0) sA[tid >> 6] = sum;
    __syncthreads();
    float m = (sA[0] + sA[1] + sA[2]) * (1.f / DM);
    float dx = x.x - m, dy = x.y - m, dz = x.z - m, dw = x.w - m;
    float vs = dx * dx + dy * dy + dz * dz + dw * dw;
#pragma unroll
    for (int o = 32; o > 0; o >>= 1) vs += __shfl_down(vs, o, 64);
    if ((tid & 63) == 0) sB[tid >> 6] = vs;
    __syncthreads();
    float rs = rsqrtf((sB[0] + sB[1] + sB[2]) * (1.f / DM) + EPS);
    float4 gv = ((const float4*)g)[tid];
    float4 bv = ((const float4*)b)[tid];
    u32 lo = (u32)f2b(dx * rs * gv.x + bv.x) | ((u32)f2b(dy * rs * gv.y + bv.y) << 16);
    u32 hi = (u32)f2b(dz * rs * gv.z + bv.z) | ((u32)f2b(dw * rs * gv.w + bv.w) << 16);
    ((uint2*)(out + (size_t)s * DM))[tid] = make_uint2(lo, hi);
}

// ------------------------------------------------- cls row: h[0] = cls + pe[0]
__global__ __launch_bounds__(256) void posadd_cls_kernel(
    float* __restrict__ h, const float* __restrict__ pe,
    const float* __restrict__ cls)
{
    const int tid = threadIdx.x;
    for (int c = tid; c < DM; c += 256) h[c] = cls[c] + pe[c];
}

// ---------------------------------------------------------------- attention (layers 0..2)
// Swapped-QK flash attention, pipelined, ONE partial per branch (5 slots):
//   slot b = branch b (full key span; ntiles 16/16/16/8/4).
// Max-tracking with defer-THR=8.  XCD-aware block swizzle: grid 744 = 8*93.
// s_setprio(1) around MFMA clusters (T5): 2 independent blocks/CU at
// drifting phases -> scheduler favors MFMA-phase waves.
__global__ __launch_bounds__(256, 3) void attn_kernel(
    const u16* __restrict__ qb, const u16* __restrict__ kbuf, const u16* __restrict__ vb,
    u16* __restrict__ obuf, u16* __restrict__ tp, float* __restrict__ lse)
{
    __shared__ u16 Vt[2][64 * 64];   // [buf][hd][key] swizzled
    __shared__ float dbuf[4][32];

    const int tid = threadIdx.x, wv = tid >> 6, l = tid & 63;
    const int lq = l & 31, lh = l >> 5;
    const int bid = (blockIdx.x & 7) * 93 + (blockIdx.x >> 3);
    int b, qtile, head, seg = 0;
    if (bid < 384) {
        b = 0; int i = bid; qtile = i & 7;
        int rest = i >> 3; head = rest % 12; seg = rest / 12;
    } else if (bid < 576) {
        b = 1; int i = bid - 384; qtile = i & 7;
        int rest = i >> 3; head = rest % 12; seg = rest / 12;
    } else if (bid < 672) {
        b = 2; int i = bid - 576; qtile = i & 7; head = i >> 3;
    } else if (bid < 720) {
        b = 3; int i = bid - 672; qtile = i & 3; head = i >> 2;
    } else {
        b = 4; int i = bid - 720; qtile = i & 1; head = i >> 1;
    }
    const int r = 1 << b;
    const int w = 1024 << b;
    const int ntiles = (b < 3) ? 16 : (b == 3 ? 8 : 4);
    const size_t base = (size_t)seg * w + (head & (r - 1));
    const int q0 = qtile * 128 + wv * 32;
    const size_t kstep = (size_t)r * DM;

    const size_t sq_l = base + (size_t)r * (q0 + lq);
    const u16* qp = qb + sq_l * DM + head * 64 + lh * 8;
    short8 qf[4];
#pragma unroll
    for (int s = 0; s < 4; ++s) qf[s] = *(const short8*)(qp + s * 16);

    const u16* kp = kbuf + (base + (size_t)r * lq) * DM + head * 64 + lh * 8;
    const int c = tid & 7, pp = tid >> 3;
    const u16* vsrc = vb + (base + (size_t)r * (2 * pp)) * DM + head * 64 + c * 8;

#define VPACK(dstbuf, A8, B8) do {                                          \
    _Pragma("unroll") for (int j = 0; j < 8; ++j) {                         \
        int i_ = (j + c) & 7; int hd_ = c * 8 + i_;                         \
        u32 val_ = (u32)(u16)(A8)[i_] | ((u32)(u16)(B8)[i_] << 16);         \
        int byte_ = hd_ * 128 + ((pp * 4) ^ (i_ << 4));                     \
        *(u32*)&Vt[dstbuf][byte_ >> 1] = val_; } } while (0)

    f32x16 oacc0 = {0.f,0.f,0.f,0.f,0.f,0.f,0.f,0.f,0.f,0.f,0.f,0.f,0.f,0.f,0.f,0.f};
    f32x16 oacc1 = oacc0;
    float mw = -INFINITY, dl = 0.f;

    short8 van = *(const short8*)vsrc;
    short8 vbn = *(const short8*)(vsrc + kstep);
    VPACK(0, van, vbn);
    van = *(const short8*)(vsrc + 64 * kstep);
    vbn = *(const short8*)(vsrc + 65 * kstep);
    short8 kf[8];
#pragma unroll
    for (int s = 0; s < 4; ++s) {
        kf[s]     = *(const short8*)(kp + s * 16);
        kf[4 + s] = *(const short8*)(kp + 32 * kstep + s * 16);
    }
    lds_barrier();

    for (int t = 0; t < ntiles; ++t) {
        const int curb = t & 1;
        f32x16 s0 = {0.f,0.f,0.f,0.f,0.f,0.f,0.f,0.f,0.f,0.f,0.f,0.f,0.f,0.f,0.f,0.f};
        f32x16 s1 = s0;
        __builtin_amdgcn_s_setprio(1);
#pragma unroll
        for (int s = 0; s < 4; ++s)
            s0 = __builtin_amdgcn_mfma_f32_32x32x16_bf16(kf[s], qf[s], s0, 0, 0, 0);
#pragma unroll
        for (int s = 0; s < 4; ++s)
            s1 = __builtin_amdgcn_mfma_f32_32x32x16_bf16(kf[4 + s], qf[s], s1, 0, 0, 0);
        __builtin_amdgcn_s_setprio(0);

        if (t + 1 < ntiles) {
            const u16* kn = kp + (size_t)(t + 1) * 64 * kstep;
#pragma unroll
            for (int s = 0; s < 4; ++s) {
                kf[s]     = *(const short8*)(kn + s * 16);
                kf[4 + s] = *(const short8*)(kn + 32 * kstep + s * 16);
            }
        }

        float pm[16];
#pragma unroll
        for (int i = 0; i < 16; ++i) pm[i] = fmaxf(s0[i], s1[i]);
#pragma unroll
        for (int i = 0; i < 8; ++i) pm[i] = fmaxf(pm[i], pm[i + 8]);
#pragma unroll
        for (int i = 0; i < 4; ++i) pm[i] = fmaxf(pm[i], pm[i + 4]);
        float mloc = fmaxf(fmaxf(pm[0], pm[1]), fmaxf(pm[2], pm[3]));
        if (__any(mloc > mw + 8.f)) {
            float mn = mloc;
#pragma unroll
            for (int o = 1; o < 64; o <<= 1) mn = fmaxf(mn, __shfl_xor(mn, o, 64));
            float al = exp2f(mw - mn);
            mw = mn;
            dl *= al;
#pragma unroll
            for (int i = 0; i < 16; ++i) { oacc0[i] *= al; oacc1[i] *= al; }
        }
        float ds = 0.f;
#pragma unroll
        for (int i = 0; i < 16; ++i) { s0[i] = exp2f(s0[i] - mw); ds += s0[i]; }
#pragma unroll
        for (int i = 0; i < 16; ++i) { s1[i] = exp2f(s1[i] - mw); ds += s1[i]; }
        ds += __shfl_xor(ds, 32, 64);
        dl += ds;

        if (t + 1 < ntiles) VPACK(curb ^ 1, van, vbn);
        if (t + 2 < ntiles) {
            van = *(const short8*)(vsrc + (size_t)(t + 2) * 64 * kstep);
            vbn = *(const short8*)(vsrc + ((size_t)(t + 2) * 64 + 1) * kstep);
        }

        __builtin_amdgcn_s_setprio(1);
#pragma unroll
        for (int kb2 = 0; kb2 < 2; ++kb2) {
            u32 wd[8];
#pragma unroll
            for (int j = 0; j < 8; ++j) {
                float lo = (kb2 == 0) ? s0[2 * j] : s1[2 * j];
                float hi = (kb2 == 0) ? s0[2 * j + 1] : s1[2 * j + 1];
                asm("v_cvt_pk_bf16_f32 %0, %1, %2" : "=v"(wd[j]) : "v"(lo), "v"(hi));
            }
#pragma unroll
            for (int ks2 = 0; ks2 < 2; ++ks2) {
                i32x2 X = __builtin_amdgcn_permlane32_swap(
                    (int)wd[ks2 * 4 + 0], (int)wd[ks2 * 4 + 2], false, false);
                i32x2 Y = __builtin_amdgcn_permlane32_swap(
                    (int)wd[ks2 * 4 + 1], (int)wd[ks2 * 4 + 3], false, false);
                union { u32 u[4]; short8 s; } pk;
                pk.u[0] = (u32)X[0]; pk.u[1] = (u32)Y[0];
                pk.u[2] = (u32)X[1]; pk.u[3] = (u32)Y[1];
                const int tt = kb2 * 2 + ks2;
#pragma unroll
                for (int hg = 0; hg < 2; ++hg) {
                    int row = hg * 32 + lq;
                    int byteoff = row * 128 + ((lh * 16 + tt * 32) ^ ((row & 7) << 4));
                    short8 vf = *(const short8*)&Vt[curb][byteoff >> 1];
                    if (hg == 0)
                        oacc0 = __builtin_amdgcn_mfma_f32_32x32x16_bf16(pk.s, vf, oacc0, 0, 0, 0);
                    else
                        oacc1 = __builtin_amdgcn_mfma_f32_32x32x16_bf16(pk.s, vf, oacc1, 0, 0, 0);
                }
            }
        }
        __builtin_amdgcn_s_setprio(0);
        lds_barrier();
    }

    if (l < 32) dbuf[wv][lq] = dl;
    u16* ob = (b == 4) ? tp : obuf + (size_t)b * S_LEN * DM;
    float* lse_b = lse + (size_t)b * S_LEN * NHEAD;
    if (l < 32) lse_b[sq_l * NHEAD + head] = mw + log2f(dl);
#pragma unroll
    for (int reg = 0; reg < 16; ++reg) {
        int qloc = (reg & 3) + 8 * (reg >> 2) + 4 * lh;
        float invd = 1.f / dbuf[wv][qloc];
        size_t sq = base + (size_t)r * (q0 + qloc);
        u16* orow = ob + sq * DM + head * 64;
        u32 pk2;
        float v0 = oacc0[reg] * invd, v1 = oacc1[reg] * invd;
        asm("v_cvt_pk_bf16_f32 %0, %1, %2" : "=v"(pk2) : "v"(v0), "v"(v1));
        orow[lq]      = (u16)(pk2 & 0xffff);
        orow[32 + lq] = (u16)(pk2 >> 16);
    }
#undef VPACK
}

// ---- LongNet combine over 5 branch partials (normalized o, exp2(lse-mx)).
// Structural coverage: branch b valid for (s,head) iff (s^head)&(r-1)==0;
// branch 4 iff (s&15)==head.  Invalid slots fully skipped.
__global__ __launch_bounds__(192) void combine_kernel(
    const u16* __restrict__ obuf, const float* __restrict__ lse,
    u16* __restrict__ t)
{
    const int s = blockIdx.x;
    const int tid = threadIdx.x;
    const int c0 = tid * 4, head = c0 >> 6;
    const size_t SD = (size_t)S_LEN * DM;
    const size_t SN = (size_t)S_LEN * NHEAD;
    const int sx = s ^ head;
    bool val[5];
    val[0] = true;
    val[1] = (sx & 1) == 0;
    val[2] = (sx & 3) == 0;
    val[3] = (sx & 7) == 0;
    val[4] = (s & 15) == head;
    float lv[5];
#pragma unroll
    for (int b = 0; b < 5; ++b)
        lv[b] = val[b] ? lse[b * SN + (size_t)s * NHEAD + head] : NEGV;
    float mx = lv[0];
#pragma unroll
    for (int b = 1; b < 5; ++b) mx = fmaxf(mx, lv[b]);
    float wsum = 0.f, o0 = 0.f, o1 = 0.f, o2 = 0.f, o3 = 0.f;
#pragma unroll
    for (int b = 0; b < 5; ++b) {
        if (val[b]) {
            float wb = exp2f(lv[b] - mx);
            wsum += wb;
            const u16* src = (b == 4) ? t : obuf + (size_t)b * SD;
            uint2 u = *(const uint2*)(src + (size_t)s * DM + c0);
            o0 += wb * b2f((u16)(u.x & 0xffff));
            o1 += wb * b2f((u16)(u.x >> 16));
            o2 += wb * b2f((u16)(u.y & 0xffff));
            o3 += wb * b2f((u16)(u.y >> 16));
        }
    }
    float inv = 1.f / wsum;
    u32 lo = (u32)f2b(o0 * inv) | ((u32)f2b(o1 * inv) << 16);
    u32 hi = (u32)f2b(o2 * inv) | ((u32)f2b(o3 * inv) << 16);
    ((uint2*)(t + (size_t)s * DM))[tid] = make_uint2(lo, hi);
}

// ---------------------------------------------------------------- layer-3 cls path
__global__ __launch_bounds__(256) void cls_attn_kernel(
    const u16* __restrict__ qb, const u16* __restrict__ kb,
    const u16* __restrict__ vb, float* __restrict__ cpart,
    float* __restrict__ lsep)
{
    __shared__ float q0[64];
    __shared__ float pbuf[128];
    __shared__ float red[8];
    __shared__ float po[256];
    const int blk = blockIdx.x, tid = threadIdx.x;
    int b, head, chunk;
    if (blk < 96)       { b = 0; head = blk >> 3; chunk = blk & 7; }
    else if (blk < 144) { int i = blk - 96;  b = 1; head = (i >> 3) * 2; chunk = i & 7; }
    else if (blk < 168) { int i = blk - 144; b = 2; head = (i >> 3) * 4; chunk = i & 7; }
    else if (blk < 176) { int i = blk - 168; b = 3; head = (i >> 2) * 8; chunk = i & 3; }
    else                { int i = blk - 176; b = 4; head = 0;            chunk = i; }
    const int r = 1 << b;
    if (tid < 64) q0[tid] = b2f(qb[head * 64 + tid]);  // row 0, pre-scaled log2e/8
    __syncthreads();

    float sc = -1e30f;
    if (tid < 128) {
        const int j = chunk * 128 + tid;
        const u16* kp = kb + (size_t)j * r * DM + head * 64;
        float acc = 0.f;
#pragma unroll
        for (int d8 = 0; d8 < 8; ++d8) {
            short8 kv = *(const short8*)(kp + d8 * 8);
#pragma unroll
            for (int jj = 0; jj < 8; ++jj)
                acc += q0[d8 * 8 + jj] * b2f((u16)kv[jj]);
        }
        sc = acc;
    }
    float mxw = sc;
#pragma unroll
    for (int o = 1; o < 64; o <<= 1) mxw = fmaxf(mxw, __shfl_xor(mxw, o, 64));
    if ((tid & 63) == 0) red[tid >> 6] = mxw;
    __syncthreads();
    const float bm = fmaxf(red[0], red[1]);
    float p = 0.f;
    if (tid < 128) { p = exp2f(sc - bm); pbuf[tid] = p; }
    float sw = p;
#pragma unroll
    for (int o = 1; o < 64; o <<= 1) sw += __shfl_xor(sw, o, 64);
    if ((tid & 63) == 0) red[4 + (tid >> 6)] = sw;
    __syncthreads();
    const float dsum = red[4] + red[5];

    const int hd = tid & 63, ch = tid >> 6;
    const u16* vp = vb + (size_t)(chunk * 128 + ch * 32) * r * DM + head * 64 + hd;
    const size_t vstep = (size_t)r * DM;
    float o = 0.f;
#pragma unroll 8
    for (int j = 0; j < 32; ++j)
        o += pbuf[ch * 32 + j] * b2f(vp[(size_t)j * vstep]);
    po[tid] = o;
    __syncthreads();
    if (tid < 64)
        cpart[(size_t)blk * 64 + tid] =
            (po[tid] + po[tid + 64] + po[tid + 128] + po[tid + 192]) / dsum;
    if (tid == 0) lsep[blk] = bm + log2f(dsum);
}

__global__ __launch_bounds__(64) void cls_combine_kernel(
    const float* __restrict__ cpart, const float* __restrict__ lsep,
    u16* __restrict__ t)
{
    const int head = blockIdx.x, tid = threadIdx.x;
#define FORALL_PARTS(EXPR)                                                    \
    for (int c = 0; c < 8; ++c) { int blk = head * 8 + c; EXPR; }             \
    if (!(head & 1)) for (int c = 0; c < 8; ++c) { int blk = 96 + (head >> 1) * 8 + c; EXPR; } \
    if (!(head & 3)) for (int c = 0; c < 8; ++c) { int blk = 144 + (head >> 2) * 8 + c; EXPR; } \
    if (!(head & 7)) for (int c = 0; c < 4; ++c) { int blk = 168 + (head >> 3) * 4 + c; EXPR; } \
    if (head == 0)  for (int c = 0; c < 2; ++c) { int blk = 176 + c; EXPR; }
    float mx = -1e30f;
    FORALL_PARTS(mx = fmaxf(mx, lsep[blk]))
    float ws = 0.f, ov = 0.f;
    FORALL_PARTS({ float wb = exp2f(lsep[blk] - mx); ws += wb;
                   ov += wb * cpart[(size_t)blk * 64 + tid]; })
    t[head * 64 + tid] = f2b(ov / ws);
#undef FORALL_PARTS
}

// row-0 GEMV, 8 threads per output (width-8 shuffle reduce), 32 outputs/block
__global__ __launch_bounds__(256) void row_gemv_kernel(
    const u16* __restrict__ x, const u16* __restrict__ wT,
    const float* __restrict__ bias, const float* __restrict__ res,
    float* __restrict__ outf, u16* __restrict__ outb, int K, int dogelu,
    float scale)
{
    __shared__ float xs[3072];
    const int tid = threadIdx.x;
    for (int i = tid; i < K; i += 256) xs[i] = b2f(x[i]);
    __syncthreads();
    const int n = blockIdx.x * 32 + (tid >> 3);
    const int kp = tid & 7;
    const u16* wrow = wT + (size_t)n * K;
    float acc = 0.f;
    for (int k = kp * 8; k < K; k += 64) {
        short8 wv = *(const short8*)(wrow + k);
#pragma unroll
        for (int j = 0; j < 8; ++j) acc += xs[k + j] * b2f((u16)wv[j]);
    }
    acc += __shfl_down(acc, 4, 8);
    acc += __shfl_down(acc, 2, 8);
    acc += __shfl_down(acc, 1, 8);
    if (kp == 0) {
        float v = (acc + bias[n]) * scale;
        if (dogelu) v = gelu_tanh(v);
        if (res) v += res[n];
        if (outf) outf[n] = v;
        if (outb) outb[n] = f2b(v);
    }
}

// ---------------------------------------------------- final double-LN, row 0
__global__ __launch_bounds__(256) void final_ln_kernel(
    const float* __restrict__ h,
    const float* __restrict__ g1, const float* __restrict__ b1,
    const float* __restrict__ g2, const float* __restrict__ b2,
    float* __restrict__ out)
{
    __shared__ float sbuf[4];
    const int tid = threadIdx.x;
    float x0 = h[tid], x1 = h[tid + 256], x2 = h[tid + 512];
    float m = block_reduce_sum(x0 + x1 + x2, sbuf) * (1.f / DM);
    float d0 = x0 - m, d1 = x1 - m, d2 = x2 - m;
    float var = block_reduce_sum(d0 * d0 + d1 * d1 + d2 * d2, sbuf) * (1.f / DM);
    float rs = rsqrtf(var + EPS);
    float y0 = d0 * rs * g1[tid]       + b1[tid];
    float y1 = d1 * rs * g1[tid + 256] + b1[tid + 256];
    float y2 = d2 * rs * g1[tid + 512] + b1[tid + 512];
    m = block_reduce_sum(y0 + y1 + y2, sbuf) * (1.f / DM);
    d0 = y0 - m; d1 = y1 - m; d2 = y2 - m;
    var = block_reduce_sum(d0 * d0 + d1 * d1 + d2 * d2, sbuf) * (1.f / DM);
    rs = rsqrtf(var + EPS);
    out[tid]       = d0 * rs * g2[tid]       + b2[tid];
    out[tid + 256] = d1 * rs * g2[tid + 256] + b2[tid + 256];
    out[tid + 512] = d2 * rs * g2[tid + 512] + b2[tid + 512];
}

// ---------------------------------------------------------------- launcher
extern "C" void kernel_launch(void* const* d_in, const int* in_sizes, int n_in,
                              void* d_out, int out_size, void* d_ws, size_t ws_size,
                              hipStream_t stream)
{
    (void)in_sizes; (void)n_in; (void)out_size; (void)ws_size;
    const float* x        = (const float*)d_in[0];
    const float* coords   = (const float*)d_in[1];
    const float* pos_emb  = (const float*)d_in[2];
    const float* cls_tok  = (const float*)d_in[3];
    const float* patch_w  = (const float*)d_in[4];
    const float* patch_b  = (const float*)d_in[5];
    const float* ln1_g    = (const float*)d_in[6];
    const float* ln1_b    = (const float*)d_in[7];
    const float* wq       = (const float*)d_in[8];
    const float* bq       = (const float*)d_in[9];
    const float* wk       = (const float*)d_in[10];
    const float* bk       = (const float*)d_in[11];
    const float* wv       = (const float*)d_in[12];
    const float* bv       = (const float*)d_in[13];
    const float* wo       = (const float*)d_in[14];
    const float* bo       = (const float*)d_in[15];
    const float* ln2_g    = (const float*)d_in[16];
    const float* ln2_b    = (const float*)d_in[17];
    const float* w1       = (const float*)d_in[18];
    const float* b1       = (const float*)d_in[19];
    const float* w2       = (const float*)d_in[20];
    const float* b2       = (const float*)d_in[21];
    const float* enc_g    = (const float*)d_in[22];
    const float* enc_b    = (const float*)d_in[23];
    const float* norm_g   = (const float*)d_in[24];
    const float* norm_b   = (const float*)d_in[25];
    float* out = (float*)d_out;

    const size_t SD = (size_t)S_LEN * DM;
    const size_t DD = (size_t)DM * DM;
    const size_t DF = (size_t)DM * FFND;
    const size_t SN = (size_t)S_LEN * NHEAD;

    char* p = (char*)d_ws;
    float* h   = (float*)p;              p += SD * 4;
    u16* t     = (u16*)p;                p += SD * 2;
    u16* qb    = (u16*)p;                p += SD * 2;
    u16* kb    = (u16*)p;                p += SD * 2;
    u16* vb    = (u16*)p;                p += SD * 2;
    float* lse = (float*)p;              p += 5 * SN * 4;
    u16* obuf  = (u16*)p;                p += 4 * SD * 2;  // slot 4 == t
    u16* ffn   = obuf;                   // aliases obuf (dead during FFN)
    u16* xb    = obuf;                   // aliases obuf (used only pre-layer0)
    u16* pwT   = (u16*)p;                p += (size_t)DIN * DM * 2;
    u16* wTdd  = (u16*)p;                p += 4 * DD * 2;
    u16* w1T   = (u16*)p;                p += DF * 2;
    u16* w2T   = (u16*)p;                p += DF * 2;
    // layer-3 cls partials reuse the (then-idle) lse buffer
    float* cpart = lse;                  // 178*64 floats
    float* lsep  = lse + 178 * 64;       // 178 floats

    cvt_bf16_kernel<<<2048, 256, 0, stream>>>(x, xb, (L_LEN * DIN) / 4);
    transpose_cvt<<<dim3(DM / 64, DIN / 64, 1), 256, 0, stream>>>(
        patch_w, patch_w, patch_w, patch_w, pwT, DIN, DM);
    // patch embed with fused pos-embed add (rows 1..4095)
    gemm_patch_kernel<<<dim3(DM / 64, 64), 256, 0, stream>>>(
        xb, pwT, patch_b, coords, pos_emb, h + DM, L_LEN, DM, DIN);
    posadd_cls_kernel<<<1, 256, 0, stream>>>(h, pos_emb, cls_tok);

    for (int l = 0; l < 4; ++l) {
        const size_t lDD = (size_t)l * DD;
        const size_t lDF = (size_t)l * DF;
        prep_weights<<<1728, 256, 0, stream>>>(
            wq + lDD, wk + lDD, wv + lDD, wo + lDD, w1 + lDF, w2 + lDF,
            wTdd, w1T, w2T);

        ln_kernel<<<S_LEN, 192, 0, stream>>>(h, t, ln1_g + l * DM, ln1_b + l * DM);

        if (l < 3) {
            qkv_kernel<<<dim3(6, 32, 3), 256, 0, stream>>>(
                t, wTdd, wTdd + DD, wTdd + 2 * DD,
                bq + l * DM, bk + l * DM, bv + l * DM, qb, kb, vb, 0);
            attn_kernel<<<744, 256, 0, stream>>>(qb, kb, vb, obuf, t, lse);
            combine_kernel<<<S_LEN, 192, 0, stream>>>(obuf, lse, t);
            gemm6464_kernel<<<dim3(12, 64), 256, 0, stream>>>(
                t, wTdd + 3 * DD, bo + l * DM, h, h, nullptr, S_LEN, DM, DM, 1.f, 0);
            ln_kernel<<<S_LEN, 192, 0, stream>>>(h, t, ln2_g + l * DM, ln2_b + l * DM);
            gemm128_kernel<<<dim3(24, 32), 256, 0, stream>>>(
                t, w1T, b1 + (size_t)l * FFND, nullptr, nullptr, ffn,
                S_LEN, FFND, DM, 1.f, 1);
            gemm6464_kernel<<<dim3(12, 64), 256, 0, stream>>>(
                ffn, w2T, b2 + l * DM, h, h, nullptr, S_LEN, DM, FFND, 1.f, 0);
        } else {
            // Last layer: only the cls row (s=0) is consumed downstream.
            // K,V needed in full (branch 0 attends over all keys); Q only row 0.
            qkv_kernel<<<dim3(6, 32, 2), 256, 0, stream>>>(
                t, wTdd, wTdd + DD, wTdd + 2 * DD,
                bq + l * DM, bk + l * DM, bv + l * DM, qb, kb, vb, 1);
            row_gemv_kernel<<<24, 256, 0, stream>>>(
                t, wTdd, bq + l * DM, nullptr, nullptr, qb, DM, 0,
                0.125f * 1.4426950408889634f);
            cls_attn_kernel<<<178, 256, 0, stream>>>(qb, kb, vb, cpart, lsep);
            cls_combine_kernel<<<NHEAD, 64, 0, stream>>>(cpart, lsep, t);
            row_gemv_kernel<<<24, 256, 0, stream>>>(
                t, wTdd + 3 * DD, bo + l * DM, h, h, nullptr, DM, 0, 1.f);
            ln_kernel<<<1, 192, 0, stream>>>(h, t, ln2_g + l * DM, ln2_b + l * DM);
            row_gemv_kernel<<<96, 256, 0, stream>>>(
                t, w1T, b1 + (size_t)l * FFND, nullptr, nullptr, ffn, DM, 1, 1.f);
            row_gemv_kernel<<<24, 256, 0, stream>>>(
                ffn, w2T, b2 + l * DM, h, h, nullptr, FFND, 0, 1.f);
        }
    }
    final_ln_kernel<<<1, 256, 0, stream>>>(h, enc_g, enc_b, norm_g, norm_b, out);
}